// Round 7
// baseline (871.939 us; speedup 1.0000x reference)
//
#include <hip/hip_runtime.h>
#include <math.h>

// Problem constants
#define BATCH 8
#define SEQ 512
#define HID 768
#define NHEAD 12
#define KVHEAD 4
#define HDIM 64
#define NEXP 8
#define TOPK 2
#define IEXP 1536
#define NTOK (BATCH * SEQ)     // 4096
#define NSLOT (NTOK * TOPK)    // 8192
#define REP (NHEAD / KVHEAD)   // 3

typedef unsigned short u16;
typedef float f32x4 __attribute__((ext_vector_type(4)));
typedef __bf16 bf16x8 __attribute__((ext_vector_type(8)));
typedef unsigned short u16x8 __attribute__((ext_vector_type(8)));

__device__ __forceinline__ u16 f2bf(float f) {
    unsigned u = __float_as_uint(f);
    u += 0x7fffu + ((u >> 16) & 1u);   // RNE
    return (u16)(u >> 16);
}
__device__ __forceinline__ float bf2f(u16 h) {
    return __uint_as_float(((unsigned)h) << 16);
}

__device__ __forceinline__ void gload16(const void* g, void* l) {
    __builtin_amdgcn_global_load_lds(
        (const __attribute__((address_space(1))) void*)g,
        (__attribute__((address_space(3))) void*)l, 16, 0, 0);
}

// split 8 fp32 -> hi/lo bf16
__device__ __forceinline__ void cvt8(float4 a, float4 b, u16x8& hi, u16x8& lo) {
    float x[8] = {a.x, a.y, a.z, a.w, b.x, b.y, b.z, b.w};
#pragma unroll
    for (int i = 0; i < 8; ++i) {
        u16 h = f2bf(x[i]);
        hi[i] = h;
        lo[i] = f2bf(x[i] - bf2f(h));
    }
}

// swizzled element offset in a row-major [R][64] bf16 LDS tile (stride 128B):
// XOR the 16B-chunk index with (row&7) -> 2-way max bank aliasing (free).
#define SW(row, col) (((row) << 6) + ((col) ^ (((row) & 7) << 3)))

// ---------------------------------------------------------------------------
// fp32 -> bf16 hi/lo split convert (weights)
// ---------------------------------------------------------------------------
__global__ __launch_bounds__(256)
void cvt_split(const float* __restrict__ x, u16* __restrict__ yh,
               u16* __restrict__ yl, int n) {
    int i = (blockIdx.x * 256 + threadIdx.x) * 4;
    if (i >= n) return;
    float4 v = *(const float4*)(x + i);
    float a[4] = {v.x, v.y, v.z, v.w};
    ushort4 h, lo;
    u16 t;
    t = f2bf(a[0]); h.x = t; lo.x = f2bf(a[0] - bf2f(t));
    t = f2bf(a[1]); h.y = t; lo.y = f2bf(a[1] - bf2f(t));
    t = f2bf(a[2]); h.z = t; lo.z = f2bf(a[2] - bf2f(t));
    t = f2bf(a[3]); h.w = t; lo.w = f2bf(a[3] - bf2f(t));
    *(ushort4*)(yh + i) = h;
    *(ushort4*)(yl + i) = lo;
}

// ---------------------------------------------------------------------------
// per-expert transpose + convert: src[e][R][C] fp32 -> dst[e][C][R] bf16
// ---------------------------------------------------------------------------
__global__ __launch_bounds__(256)
void transpose_cvt(const float* __restrict__ src, u16* __restrict__ dst,
                   int R, int C) {
    const int e = blockIdx.z;
    src += (size_t)e * R * C;
    dst += (size_t)e * R * C;
    __shared__ float t[32][33];
    const int c0 = blockIdx.x << 5, r0 = blockIdx.y << 5;
    const int tx = threadIdx.x, ty = threadIdx.y;
#pragma unroll
    for (int i = 0; i < 4; ++i)
        t[ty * 4 + i][tx] = src[(size_t)(r0 + ty * 4 + i) * C + c0 + tx];
    __syncthreads();
#pragma unroll
    for (int i = 0; i < 4; ++i)
        dst[(size_t)(c0 + ty * 4 + i) * R + r0 + tx] = f2bf(t[tx][ty * 4 + i]);
}

// ---------------------------------------------------------------------------
// RMSNorm: one block per token. fp32 out; optional bf16 copy (for MoE A-side)
// ---------------------------------------------------------------------------
__global__ __launch_bounds__(256)
void rmsnorm_kernel(const float* __restrict__ X, const float* __restrict__ W,
                    float* __restrict__ Y, u16* __restrict__ Ybf) {
    const int t = blockIdx.x;
    const int tid = threadIdx.x;
    const float* x = X + (size_t)t * HID;
    float x0 = x[tid], x1 = x[tid + 256], x2 = x[tid + 512];
    float ss = x0 * x0 + x1 * x1 + x2 * x2;
    for (int m = 1; m < 64; m <<= 1) ss += __shfl_xor(ss, m);
    __shared__ float red[4];
    if ((tid & 63) == 0) red[tid >> 6] = ss;
    __syncthreads();
    float tot = red[0] + red[1] + red[2] + red[3];
    float inv = rsqrtf(tot * (1.0f / HID) + 1e-6f);
    float r0 = x0 * inv * W[tid];
    float r1 = x1 * inv * W[tid + 256];
    float r2 = x2 * inv * W[tid + 512];
    float* y = Y + (size_t)t * HID;
    y[tid] = r0; y[tid + 256] = r1; y[tid + 512] = r2;
    if (Ybf) {
        u16* yb = Ybf + (size_t)t * HID;
        yb[tid] = f2bf(r0); yb[tid + 256] = f2bf(r1); yb[tid + 512] = f2bf(r2);
    }
}

// ---------------------------------------------------------------------------
// Split-precision MFMA NT GEMM for QKV. A fp32 (hi/lo in-kernel),
// Wh/Wl bf16 [1280][768]. 128x128 tile, BK=32. Grid (10, 32).
// acc = ah*bh + al*bh + ah*bl  (ll term ~2^-18, dropped)
// ---------------------------------------------------------------------------
__global__ __launch_bounds__(256)
void qkv_split(const float* __restrict__ X, const u16* __restrict__ Wh,
               const u16* __restrict__ Wl,
               const float* __restrict__ bq, const float* __restrict__ bk,
               const float* __restrict__ bv,
               float* __restrict__ Qo, float* __restrict__ Ko,
               float* __restrict__ Vo) {
    __shared__ __align__(16) u16 Ah[4096], Al[4096], Bh[4096], Bl[4096];
    const int tid = threadIdx.x, l = tid & 63, w = tid >> 6;
    const int wm = w & 1, wn = w >> 1;
    const int m0 = blockIdx.y << 7, n0 = blockIdx.x << 7;
    const int sr = l >> 2, sc8 = (l & 3) << 3;
    const float* gA0 = X + (size_t)(m0 + w * 32 + sr) * HID + sc8;
    const float* gA1 = gA0 + 16 * HID;
    const u16* gBh0 = Wh + (size_t)(n0 + w * 32 + sr) * HID + sc8;
    const u16* gBh1 = gBh0 + 16 * HID;
    const u16* gBl0 = Wl + (size_t)(n0 + w * 32 + sr) * HID + sc8;
    const u16* gBl1 = gBl0 + 16 * HID;
    const int aoff0 = (w * 32 + sr) * 32 + sc8, aoff1 = aoff0 + 512;
    u16* lBh0 = Bh + w * 1024; u16* lBh1 = lBh0 + 512;
    u16* lBl0 = Bl + w * 1024; u16* lBl1 = lBl0 + 512;
    const int fr = l & 15, fc = (l >> 4) << 3;
    f32x4 acc[4][4];
#pragma unroll
    for (int i = 0; i < 4; ++i)
#pragma unroll
        for (int j = 0; j < 4; ++j) acc[i][j] = (f32x4){0.f, 0.f, 0.f, 0.f};
    for (int k0 = 0; k0 < HID; k0 += 32) {
        float4 a00 = *(const float4*)(gA0 + k0);
        float4 a01 = *(const float4*)(gA0 + k0 + 4);
        float4 a10 = *(const float4*)(gA1 + k0);
        float4 a11 = *(const float4*)(gA1 + k0 + 4);
        gload16(gBh0 + k0, lBh0);
        gload16(gBh1 + k0, lBh1);
        gload16(gBl0 + k0, lBl0);
        gload16(gBl1 + k0, lBl1);
        u16x8 h0, l0v, h1, l1v;
        cvt8(a00, a01, h0, l0v);
        cvt8(a10, a11, h1, l1v);
        *(u16x8*)(Ah + aoff0) = h0; *(u16x8*)(Al + aoff0) = l0v;
        *(u16x8*)(Ah + aoff1) = h1; *(u16x8*)(Al + aoff1) = l1v;
        __syncthreads();
        bf16x8 ah[4], al[4], bh[4], bl[4];
#pragma unroll
        for (int i = 0; i < 4; ++i) {
            ah[i] = *(const bf16x8*)(Ah + (wm * 64 + i * 16 + fr) * 32 + fc);
            al[i] = *(const bf16x8*)(Al + (wm * 64 + i * 16 + fr) * 32 + fc);
            bh[i] = *(const bf16x8*)(Bh + (wn * 64 + i * 16 + fr) * 32 + fc);
            bl[i] = *(const bf16x8*)(Bl + (wn * 64 + i * 16 + fr) * 32 + fc);
        }
#pragma unroll
        for (int mf = 0; mf < 4; ++mf)
#pragma unroll
            for (int nf = 0; nf < 4; ++nf) {
                acc[mf][nf] = __builtin_amdgcn_mfma_f32_16x16x32_bf16(
                    ah[mf], bh[nf], acc[mf][nf], 0, 0, 0);
                acc[mf][nf] = __builtin_amdgcn_mfma_f32_16x16x32_bf16(
                    al[mf], bh[nf], acc[mf][nf], 0, 0, 0);
                acc[mf][nf] = __builtin_amdgcn_mfma_f32_16x16x32_bf16(
                    ah[mf], bl[nf], acc[mf][nf], 0, 0, 0);
            }
        __syncthreads();
    }
    float* outp; const float* bp; int ldc, nl;
    if (n0 < 768)       { outp = Qo; bp = bq; ldc = 768; nl = n0; }
    else if (n0 < 1024) { outp = Ko; bp = bk; ldc = 256; nl = n0 - 768; }
    else                { outp = Vo; bp = bv; ldc = 256; nl = n0 - 1024; }
    const int er = (l >> 4) << 2, ec = l & 15;
#pragma unroll
    for (int mf = 0; mf < 4; ++mf)
#pragma unroll
        for (int i = 0; i < 4; ++i) {
            int row = m0 + wm * 64 + mf * 16 + er + i;
#pragma unroll
            for (int nf = 0; nf < 4; ++nf) {
                int col = nl + wn * 64 + nf * 16 + ec;
                outp[(size_t)row * ldc + col] = acc[mf][nf][i] + bp[col];
            }
        }
}

// ---------------------------------------------------------------------------
// Split-precision MFMA NT GEMM with residual: C = A@W^T + resid.
// ---------------------------------------------------------------------------
__global__ __launch_bounds__(256)
void oproj_split(const float* __restrict__ A, const u16* __restrict__ Wh,
                 const u16* __restrict__ Wl, const float* __restrict__ resid,
                 float* __restrict__ C, int M, int N, int K) {
    __shared__ __align__(16) u16 Ah[4096], Al[4096], Bh[4096], Bl[4096];
    const int tid = threadIdx.x, l = tid & 63, w = tid >> 6;
    const int wm = w & 1, wn = w >> 1;
    const int m0 = blockIdx.y << 7, n0 = blockIdx.x << 7;
    const int sr = l >> 2, sc8 = (l & 3) << 3;
    const float* gA0 = A + (size_t)(m0 + w * 32 + sr) * K + sc8;
    const float* gA1 = gA0 + (size_t)16 * K;
    const u16* gBh0 = Wh + (size_t)(n0 + w * 32 + sr) * K + sc8;
    const u16* gBh1 = gBh0 + (size_t)16 * K;
    const u16* gBl0 = Wl + (size_t)(n0 + w * 32 + sr) * K + sc8;
    const u16* gBl1 = gBl0 + (size_t)16 * K;
    const int aoff0 = (w * 32 + sr) * 32 + sc8, aoff1 = aoff0 + 512;
    u16* lBh0 = Bh + w * 1024; u16* lBh1 = lBh0 + 512;
    u16* lBl0 = Bl + w * 1024; u16* lBl1 = lBl0 + 512;
    const int fr = l & 15, fc = (l >> 4) << 3;
    f32x4 acc[4][4];
#pragma unroll
    for (int i = 0; i < 4; ++i)
#pragma unroll
        for (int j = 0; j < 4; ++j) acc[i][j] = (f32x4){0.f, 0.f, 0.f, 0.f};
    for (int k0 = 0; k0 < K; k0 += 32) {
        float4 a00 = *(const float4*)(gA0 + k0);
        float4 a01 = *(const float4*)(gA0 + k0 + 4);
        float4 a10 = *(const float4*)(gA1 + k0);
        float4 a11 = *(const float4*)(gA1 + k0 + 4);
        gload16(gBh0 + k0, lBh0);
        gload16(gBh1 + k0, lBh1);
        gload16(gBl0 + k0, lBl0);
        gload16(gBl1 + k0, lBl1);
        u16x8 h0, l0v, h1, l1v;
        cvt8(a00, a01, h0, l0v);
        cvt8(a10, a11, h1, l1v);
        *(u16x8*)(Ah + aoff0) = h0; *(u16x8*)(Al + aoff0) = l0v;
        *(u16x8*)(Ah + aoff1) = h1; *(u16x8*)(Al + aoff1) = l1v;
        __syncthreads();
        bf16x8 ah[4], al[4], bh[4], bl[4];
#pragma unroll
        for (int i = 0; i < 4; ++i) {
            ah[i] = *(const bf16x8*)(Ah + (wm * 64 + i * 16 + fr) * 32 + fc);
            al[i] = *(const bf16x8*)(Al + (wm * 64 + i * 16 + fr) * 32 + fc);
            bh[i] = *(const bf16x8*)(Bh + (wn * 64 + i * 16 + fr) * 32 + fc);
            bl[i] = *(const bf16x8*)(Bl + (wn * 64 + i * 16 + fr) * 32 + fc);
        }
#pragma unroll
        for (int mf = 0; mf < 4; ++mf)
#pragma unroll
            for (int nf = 0; nf < 4; ++nf) {
                acc[mf][nf] = __builtin_amdgcn_mfma_f32_16x16x32_bf16(
                    ah[mf], bh[nf], acc[mf][nf], 0, 0, 0);
                acc[mf][nf] = __builtin_amdgcn_mfma_f32_16x16x32_bf16(
                    al[mf], bh[nf], acc[mf][nf], 0, 0, 0);
                acc[mf][nf] = __builtin_amdgcn_mfma_f32_16x16x32_bf16(
                    ah[mf], bl[nf], acc[mf][nf], 0, 0, 0);
            }
        __syncthreads();
    }
    const int er = (l >> 4) << 2, ec = l & 15;
#pragma unroll
    for (int mf = 0; mf < 4; ++mf)
#pragma unroll
        for (int i = 0; i < 4; ++i) {
            int row = m0 + wm * 64 + mf * 16 + er + i;
#pragma unroll
            for (int nf = 0; nf < 4; ++nf) {
                int col = n0 + wn * 64 + nf * 16 + ec;
                C[(size_t)row * N + col] =
                    acc[mf][nf][i] + resid[(size_t)row * N + col];
            }
        }
}

// ---------------------------------------------------------------------------
// RoPE in-place on q (12 heads) and k (4 heads) per token
// ---------------------------------------------------------------------------
__global__ __launch_bounds__(256)
void rope_kernel(float* __restrict__ Q, float* __restrict__ Kb,
                 const int* __restrict__ pos_ids) {
    const int t = blockIdx.x;
    const float pos = (float)pos_ids[t];
    const int tid = threadIdx.x;
#pragma unroll
    for (int it = 0; it < 2; ++it) {
        int p = tid + (it << 8);
        int head = p >> 5, i = p & 31;
        float invf = expf(-(float)i * 0.28782313662425572f); // ln(1e4)/32
        float ang = pos * invf;
        float c = cosf(ang), sn = sinf(ang);
        float* base = (head < NHEAD)
            ? (Q + (size_t)t * HID + head * HDIM)
            : (Kb + (size_t)t * (KVHEAD * HDIM) + (head - NHEAD) * HDIM);
        float x1 = base[i], x2 = base[i + 32];
        base[i]      = x1 * c - x2 * sn;
        base[i + 32] = x2 * c + x1 * sn;
    }
}

// ---------------------------------------------------------------------------
// Self attention (causal GQA) via split-precision MFMA, online softmax.
// Block: 256 thr (4 waves) = 32 queries. Tiles of 64 keys.
// ---------------------------------------------------------------------------
__global__ __launch_bounds__(256)
void attn_self_mfma(const float* __restrict__ Q, const float* __restrict__ K,
                    const float* __restrict__ V, float* __restrict__ O) {
    const int qt = blockIdx.x, n = blockIdx.y, b = blockIdx.z;
    const int kv = n / REP;
    const int tid = threadIdx.x, l = tid & 63, w = tid >> 6;
    const int q0 = qt << 5;
    __shared__ __align__(16) u16 Qh[2048], Ql[2048];    // [32][64]
    __shared__ __align__(16) u16 Kh[4096], Kl[4096];    // [64][64]
    __shared__ __align__(16) u16 Vh[4096], Vl[4096];    // transposed [d][key]
    __shared__ float Ps[32][68];
    __shared__ float scal[32];

    // ---- stage Q (hi/lo, swizzled) ----
    {
        int row = tid >> 3, cg = (tid & 7) << 3;
        const float* qg = Q + (size_t)(b * SEQ + q0 + row) * HID + n * HDIM + cg;
        float4 v0 = *(const float4*)qg;
        float4 v1 = *(const float4*)(qg + 4);
        u16x8 h, lo;
        cvt8(v0, v1, h, lo);
        *(u16x8*)(Qh + SW(row, cg)) = h;
        *(u16x8*)(Ql + SW(row, cg)) = lo;
    }
    __syncthreads();

    const int fr = l & 15, fcg = (l >> 4) << 3;
    const int qf16 = (w & 1) << 4;
    const int fp2 = (w >> 1) << 1;      // frag pair base (k or d)
    bf16x8 qfh[2], qfl[2];
#pragma unroll
    for (int dc = 0; dc < 2; ++dc) {
        int off = SW(qf16 + fr, dc * 32 + fcg);
        qfh[dc] = *(const bf16x8*)(Qh + off);
        qfl[dc] = *(const bf16x8*)(Ql + off);
    }

    f32x4 o[2];
    o[0] = (f32x4){0.f, 0.f, 0.f, 0.f};
    o[1] = (f32x4){0.f, 0.f, 0.f, 0.f};
    float m_run = -3.4e38f, l_run = 0.f;
    const int sq = tid >> 3;
    const int skb = (tid & 7) << 3;
    const float scale = 0.125f;
    const int nt = (qt >> 1) + 1;

    for (int t = 0; t < nt; ++t) {
        __syncthreads();
        // ---- stage K tile (hi/lo, swizzled) ----
        {
            int row = tid >> 2, cg = (tid & 3) << 4;
            const float* kg = K + (size_t)(b * SEQ + (t << 6) + row)
                              * (KVHEAD * HDIM) + kv * HDIM + cg;
            float4 k0 = *(const float4*)kg;
            float4 k1 = *(const float4*)(kg + 4);
            float4 k2 = *(const float4*)(kg + 8);
            float4 k3 = *(const float4*)(kg + 12);
            u16x8 h0, l0v, h1, l1v;
            cvt8(k0, k1, h0, l0v);
            cvt8(k2, k3, h1, l1v);
            *(u16x8*)(Kh + SW(row, cg)) = h0;
            *(u16x8*)(Kh + SW(row, cg + 8)) = h1;
            *(u16x8*)(Kl + SW(row, cg)) = l0v;
            *(u16x8*)(Kl + SW(row, cg + 8)) = l1v;
        }
        // ---- stage V tile transposed [d][key] (hi/lo, swizzled) ----
        {
            int kp = (tid & 31) << 1, dc = (tid >> 5) << 3;
            const float* vg0 = V + (size_t)(b * SEQ + (t << 6) + kp)
                               * (KVHEAD * HDIM) + kv * HDIM + dc;
            const float* vg1 = vg0 + KVHEAD * HDIM;
            float4 a0 = *(const float4*)vg0;
            float4 a1 = *(const float4*)(vg0 + 4);
            float4 b0 = *(const float4*)vg1;
            float4 b1 = *(const float4*)(vg1 + 4);
            float va[8] = {a0.x, a0.y, a0.z, a0.w, a1.x, a1.y, a1.z, a1.w};
            float vb[8] = {b0.x, b0.y, b0.z, b0.w, b1.x, b1.y, b1.z, b1.w};
#pragma unroll
            for (int j = 0; j < 8; ++j) {
                u16 h0 = f2bf(va[j]);
                u16 h1 = f2bf(vb[j]);
                u16 p0 = f2bf(va[j] - bf2f(h0));
                u16 p1 = f2bf(vb[j] - bf2f(h1));
                int off = SW(dc + j, kp);
                *(unsigned*)(Vh + off) = (unsigned)h0 | ((unsigned)h1 << 16);
                *(unsigned*)(Vl + off) = (unsigned)p0 | ((unsigned)p1 << 16);
            }
        }
        __syncthreads();
        // ---- S = Q K^T (split MFMA) ----
#pragma unroll
        for (int kk = 0; kk < 2; ++kk) {
            int kf = fp2 + kk;
            bf16x8 kh[2], klv[2];
#pragma unroll
            for (int dc = 0; dc < 2; ++dc) {
                int off = SW(kf * 16 + fr, dc * 32 + fcg);
                kh[dc]  = *(const bf16x8*)(Kh + off);
                klv[dc] = *(const bf16x8*)(Kl + off);
            }
            f32x4 s = (f32x4){0.f, 0.f, 0.f, 0.f};
            s = __builtin_amdgcn_mfma_f32_16x16x32_bf16(qfh[0], kh[0], s, 0, 0, 0);
            s = __builtin_amdgcn_mfma_f32_16x16x32_bf16(qfh[1], kh[1], s, 0, 0, 0);
            s = __builtin_amdgcn_mfma_f32_16x16x32_bf16(qfl[0], kh[0], s, 0, 0, 0);
            s = __builtin_amdgcn_mfma_f32_16x16x32_bf16(qfl[1], kh[1], s, 0, 0, 0);
            s = __builtin_amdgcn_mfma_f32_16x16x32_bf16(qfh[0], klv[0], s, 0, 0, 0);
            s = __builtin_amdgcn_mfma_f32_16x16x32_bf16(qfh[1], klv[1], s, 0, 0, 0);
            int col = kf * 16 + fr;
            int key = (t << 6) + col;
#pragma unroll
            for (int r = 0; r < 4; ++r) {
                int qrow = qf16 + ((l >> 4) << 2) + r;
                Ps[qrow][col] = (key <= q0 + qrow) ? s[r] * scale : -1e9f;
            }
        }
        __syncthreads();
        // ---- online softmax update (8 threads per query) ----
        {
            float4 s0 = *(const float4*)&Ps[sq][skb];
            float4 s1 = *(const float4*)&Ps[sq][skb + 4];
            float sv[8] = {s0.x, s0.y, s0.z, s0.w, s1.x, s1.y, s1.z, s1.w};
            float mx = sv[0];
#pragma unroll
            for (int j = 1; j < 8; ++j) mx = fmaxf(mx, sv[j]);
            for (int x = 1; x < 8; x <<= 1) mx = fmaxf(mx, __shfl_xor(mx, x));
            float mnew = fmaxf(m_run, mx);
            float corr = __expf(m_run - mnew);
            float lsum = 0.f;
#pragma unroll
            for (int j = 0; j < 8; ++j) {
                sv[j] = __expf(sv[j] - mnew);
                lsum += sv[j];
            }
            for (int x = 1; x < 8; x <<= 1) lsum += __shfl_xor(lsum, x);
            l_run = l_run * corr + lsum;
            m_run = mnew;
            *(float4*)&Ps[sq][skb]     = make_float4(sv[0], sv[1], sv[2], sv[3]);
            *(float4*)&Ps[sq][skb + 4] = make_float4(sv[4], sv[5], sv[6], sv[7]);
            if ((tid & 7) == 0) scal[sq] = corr;
        }
        __syncthreads();
        // ---- rescale O, then O += P V (split MFMA) ----
        {
            float4 c4 = *(const float4*)&scal[qf16 + ((l >> 4) << 2)];
            float cr[4] = {c4.x, c4.y, c4.z, c4.w};
#pragma unroll
            for (int dfi = 0; dfi < 2; ++dfi)
#pragma unroll
                for (int r = 0; r < 4; ++r) o[dfi][r] *= cr[r];
            bf16x8 ph[2], pl[2];
#pragma unroll
            for (int kc = 0; kc < 2; ++kc) {
                float4 p0 = *(const float4*)&Ps[qf16 + fr][kc * 32 + fcg];
                float4 p1 = *(const float4*)&Ps[qf16 + fr][kc * 32 + fcg + 4];
                u16x8 hh, ll;
                cvt8(p0, p1, hh, ll);
                ph[kc] = *(bf16x8*)&hh;
                pl[kc] = *(bf16x8*)&ll;
            }
#pragma unroll
            for (int dfi = 0; dfi < 2; ++dfi) {
                int df = fp2 + dfi;
#pragma unroll
                for (int kc = 0; kc < 2; ++kc) {
                    int off = SW(df * 16 + fr, kc * 32 + fcg);
                    bf16x8 vh = *(const bf16x8*)(Vh + off);
                    bf16x8 vl = *(const bf16x8*)(Vl + off);
                    o[dfi] = __builtin_amdgcn_mfma_f32_16x16x32_bf16(
                        ph[kc], vh, o[dfi], 0, 0, 0);
                    o[dfi] = __builtin_amdgcn_mfma_f32_16x16x32_bf16(
                        pl[kc], vh, o[dfi], 0, 0, 0);
                    o[dfi] = __builtin_amdgcn_mfma_f32_16x16x32_bf16(
                        ph[kc], vl, o[dfi], 0, 0, 0);
                }
            }
        }
    }
    __syncthreads();
    if ((tid & 7) == 0) scal[sq] = 1.0f / l_run;
    __syncthreads();
    {
        int qrb = qf16 + ((l >> 4) << 2);
        float4 li4 = *(const float4*)&scal[qrb];
        float li[4] = {li4.x, li4.y, li4.z, li4.w};
#pragma unroll
        for (int dfi = 0; dfi < 2; ++dfi) {
            int df = fp2 + dfi;
            int col = n * HDIM + df * 16 + fr;
#pragma unroll
            for (int r = 0; r < 4; ++r) {
                int row = q0 + qrb + r;
                O[(size_t)(b * SEQ + row) * HID + col] = o[dfi][r] * li[r];
            }
        }
    }
}

// ---------------------------------------------------------------------------
// Group attention: MHA across the 8 channels. One wave per (s, head).
// ---------------------------------------------------------------------------
__global__ __launch_bounds__(64)
void attn_group(const float* __restrict__ Q, const float* __restrict__ K,
                const float* __restrict__ V, const float* __restrict__ gmask,
                float* __restrict__ O) {
    const int n = blockIdx.x % NHEAD;
    const int s = blockIdx.x / NHEAD;
    const int kv = n / REP;
    const int lane = threadIdx.x;
    __shared__ float Qs[8][65], Ks[8][65], Vs[8][65], Ps[64];
    for (int c = 0; c < 8; ++c) {
        Qs[c][lane] = Q[(size_t)(c * SEQ + s) * HID + n * HDIM + lane];
        Ks[c][lane] = K[(size_t)(c * SEQ + s) * (KVHEAD * HDIM) + kv * HDIM + lane];
        Vs[c][lane] = V[(size_t)(c * SEQ + s) * (KVHEAD * HDIM) + kv * HDIM + lane];
    }
    __syncthreads();
    const int qb = lane >> 3, kb = lane & 7;
    float sc = 0;
    for (int d = 0; d < 64; ++d) sc += Qs[qb][d] * Ks[kb][d];
    sc = sc * 0.125f + gmask[(size_t)s * 64 + qb * 8 + kb];
    float m = sc;
    for (int x = 1; x < 8; x <<= 1) m = fmaxf(m, __shfl_xor(m, x));
    float p = __expf(sc - m);
    float l = p;
    for (int x = 1; x < 8; x <<= 1) l += __shfl_xor(l, x);
    Ps[lane] = p / l;
    __syncthreads();
    for (int q2 = 0; q2 < 8; ++q2) {
        float o = 0;
        for (int c = 0; c < 8; ++c) o += Ps[q2 * 8 + c] * Vs[c][lane];
        O[(size_t)(q2 * SEQ + s) * HID + n * HDIM + lane] = o;
    }
}

// ---------------------------------------------------------------------------
// MoE router (fp32)
// ---------------------------------------------------------------------------
__global__ __launch_bounds__(64)
void router_kernel(const float* __restrict__ X, const float* __restrict__ GW,
                   int* __restrict__ counts, int* __restrict__ topi,
                   float* __restrict__ topw, int* __restrict__ posb) {
    const int t = blockIdx.x;
    const int lane = threadIdx.x;
    const int e = lane >> 3, c = lane & 7;
    const float4* x4 = (const float4*)(X + (size_t)t * HID + c * 96);
    const float4* g4 = (const float4*)(GW + (size_t)e * HID + c * 96);
    float p = 0;
#pragma unroll
    for (int i = 0; i < 24; ++i) {
        float4 xv = x4[i], gv = g4[i];
        p += xv.x * gv.x + xv.y * gv.y + xv.z * gv.z + xv.w * gv.w;
    }
    p += __shfl_xor(p, 1);
    p += __shfl_xor(p, 2);
    p += __shfl_xor(p, 4);
    float lg[8];
#pragma unroll
    for (int i = 0; i < 8; ++i) lg[i] = __shfl(p, i * 8);
    float m = lg[0];
#pragma unroll
    for (int i = 1; i < 8; ++i) m = fmaxf(m, lg[i]);
    float s = 0;
#pragma unroll
    for (int i = 0; i < 8; ++i) { lg[i] = expf(lg[i] - m); s += lg[i]; }
    float inv = 1.0f / s;
    int i1 = 0; float b1 = lg[0];
#pragma unroll
    for (int i = 1; i < 8; ++i) if (lg[i] > b1) { b1 = lg[i]; i1 = i; }
    int i2 = -1; float b2 = -1.0f;
#pragma unroll
    for (int i = 0; i < 8; ++i)
        if (i != i1 && lg[i] > b2) { b2 = lg[i]; i2 = i; }
    if (lane == 0) {
        topi[t * 2] = i1; topi[t * 2 + 1] = i2;
        topw[t * 2] = b1 * inv; topw[t * 2 + 1] = b2 * inv;
        posb[t * 2] = atomicAdd(&counts[i1], 1);
        posb[t * 2 + 1] = atomicAdd(&counts[i2], 1);
    }
}

__global__ void scan_kernel(const int* __restrict__ counts, int* __restrict__ offsets) {
    int acc = 0;
    for (int e = 0; e < NEXP; ++e) { offsets[e] = acc; acc += counts[e]; }
}

__global__ __launch_bounds__(256)
void fill_slots(const int* __restrict__ topi, const float* __restrict__ topw,
                const int* __restrict__ posb, const int* __restrict__ offsets,
                int* __restrict__ slot_token, float* __restrict__ slot_w,
                int* __restrict__ token_slot) {
    int t = blockIdx.x * 256 + threadIdx.x;
    if (t >= NTOK) return;
#pragma unroll
    for (int k = 0; k < TOPK; ++k) {
        int e = topi[t * 2 + k];
        int sl = offsets[e] + posb[t * 2 + k];
        slot_token[sl] = t;
        slot_w[sl] = topw[t * 2 + k];
        token_slot[t * 2 + k] = sl;
    }
}

// ---------------------------------------------------------------------------
// MoE gate+up grouped GEMM, single-bf16 A (post-router: flip-free).
// Xb bf16 [NTOK][HID] gathered via slot_token with global_load_lds.
// Wg/Wu bf16 [e][IEXP][HID]. H bf16 out. Grid (m=32, n=12, e=8):
// m fastest so consecutive blocks share the same weight panel (L2 reuse).
// ---------------------------------------------------------------------------
__global__ __launch_bounds__(256)
void moe_gate_up(const u16* __restrict__ Xb, const u16* __restrict__ Wg,
                 const u16* __restrict__ Wu,
                 const int* __restrict__ slot_token,
                 const int* __restrict__ counts,
                 const int* __restrict__ offsets, u16* __restrict__ H) {
    const int e = blockIdx.z;
    const int Ce = counts[e];
    const int m0 = blockIdx.x << 7;
    if (Ce == 0 || m0 >= Ce) return;
    const int n0 = blockIdx.y << 7;
    const int base = offsets[e];
    __shared__ __align__(16) u16 As[4096];
    __shared__ __align__(16) u16 Gs[4096];
    __shared__ __align__(16) u16 Us[4096];
    const int tid = threadIdx.x, l = tid & 63, w = tid >> 6;
    const int wm = w & 1, wn = w >> 1;
    const int sr = l >> 2, sc8 = (l & 3) << 3;
    int r0 = m0 + w * 32 + sr;
    int r1 = r0 + 16;
    int t0 = slot_token[base + min(r0, Ce - 1)];
    int t1 = slot_token[base + min(r1, Ce - 1)];
    const u16* gA0 = Xb + (size_t)t0 * HID + sc8;
    const u16* gA1 = Xb + (size_t)t1 * HID + sc8;
    const u16* Wge = Wg + (size_t)e * IEXP * HID;
    const u16* Wue = Wu + (size_t)e * IEXP * HID;
    const u16* gG0 = Wge + (size_t)(n0 + w * 32 + sr) * HID + sc8;
    const u16* gG1 = gG0 + 16 * HID;
    const u16* gU0 = Wue + (size_t)(n0 + w * 32 + sr) * HID + sc8;
    const u16* gU1 = gU0 + 16 * HID;
    u16* lA0 = As + w * 1024; u16* lA1 = lA0 + 512;
    u16* lG0 = Gs + w * 1024; u16* lG1 = lG0 + 512;
    u16* lU0 = Us + w * 1024; u16* lU1 = lU0 + 512;
    const int fr = l & 15, fc = (l >> 4) << 3;
    f32x4 accg[4][4], accu[4][4];
#pragma unroll
    for (int i = 0; i < 4; ++i)
#pragma unroll
        for (int j = 0; j < 4; ++j) {
            accg[i][j] = (f32x4){0.f, 0.f, 0.f, 0.f};
            accu[i][j] = (f32x4){0.f, 0.f, 0.f, 0.f};
        }
    for (int k0 = 0; k0 < HID; k0 += 32) {
        gload16(gA0 + k0, lA0);
        gload16(gA1 + k0, lA1);
        gload16(gG0 + k0, lG0);
        gload16(gG1 + k0, lG1);
        gload16(gU0 + k0, lU0);
        gload16(gU1 + k0, lU1);
        __syncthreads();
        bf16x8 af[4], gf[4], uf[4];
#pragma unroll
        for (int i = 0; i < 4; ++i) {
            af[i] = *(const bf16x8*)(As + (wm * 64 + i * 16 + fr) * 32 + fc);
            gf[i] = *(const bf16x8*)(Gs + (wn * 64 + i * 16 + fr) * 32 + fc);
            uf[i] = *(const bf16x8*)(Us + (wn * 64 + i * 16 + fr) * 32 + fc);
        }
#pragma unroll
        for (int mf = 0; mf < 4; ++mf)
#pragma unroll
            for (int nf = 0; nf < 4; ++nf) {
                accg[mf][nf] = __builtin_amdgcn_mfma_f32_16x16x32_bf16(
                    af[mf], gf[nf], accg[mf][nf], 0, 0, 0);
                accu[mf][nf] = __builtin_amdgcn_mfma_f32_16x16x32_bf16(
                    af[mf], uf[nf], accu[mf][nf], 0, 0, 0);
            }
        __syncthreads();
    }
    const int er = (l >> 4) << 2, ec = l & 15;
#pragma unroll
    for (int mf = 0; mf < 4; ++mf)
#pragma unroll
        for (int i = 0; i < 4; ++i) {
            int row = m0 + wm * 64 + mf * 16 + er + i;
            if (row >= Ce) continue;
            size_t sl = (size_t)(base + row);
#pragma unroll
            for (int nf = 0; nf < 4; ++nf) {
                int col = n0 + wn * 64 + nf * 16 + ec;
                float g = accg[mf][nf][i];
                float u = accu[mf][nf][i];
                float h = g / (1.0f + __expf(-g)) * u;
                H[sl * IEXP + col] = f2bf(h);
            }
        }
}

// ---------------------------------------------------------------------------
// MoE down grouped GEMM bf16: D[slot][HID] fp32 = slot_w * (H @ Wd^T)
// Wd pre-transposed to [e][HID][IEXP]. Grid (m=32, n=6, e=8), m fastest.
// ---------------------------------------------------------------------------
__global__ __launch_bounds__(256)
void moe_down_bf16(const u16* __restrict__ Hb, const u16* __restrict__ Wd,
                   const float* __restrict__ slot_w,
                   const int* __restrict__ counts,
                   const int* __restrict__ offsets, float* __restrict__ D) {
    const int e = blockIdx.z;
    const int Ce = counts[e];
    const int m0 = blockIdx.x << 7;
    if (Ce == 0 || m0 >= Ce) return;
    const int n0 = blockIdx.y << 7;
    const int base = offsets[e];
    __shared__ __align__(16) u16 As[4096];
    __shared__ __align__(16) u16 Bs[4096];
    const int tid = threadIdx.x, l = tid & 63, w = tid >> 6;
    const int wm = w & 1, wn = w >> 1;
    const int sr = l >> 2, sc = (l & 3) << 3;
    const u16* Ae = Hb + (size_t)base * IEXP;
    int r0 = min(m0 + w * 32 + sr, Ce - 1);
    int r1 = min(m0 + w * 32 + 16 + sr, Ce - 1);
    const u16* gA0 = Ae + (size_t)r0 * IEXP + sc;
    const u16* gA1 = Ae + (size_t)r1 * IEXP + sc;
    const u16* Wde = Wd + (size_t)e * HID * IEXP;
    const u16* gB0 = Wde + (size_t)(n0 + w * 32 + sr) * IEXP + sc;
    const u16* gB1 = gB0 + 16 * IEXP;
    u16* lA0 = As + w * 1024; u16* lA1 = lA0 + 512;
    u16* lB0 = Bs + w * 1024; u16* lB1 = lB0 + 512;
    const int fr = l & 15, fc = (l >> 4) << 3;
    f32x4 acc[4][4];
#pragma unroll
    for (int i = 0; i < 4; ++i)
#pragma unroll
        for (int j = 0; j < 4; ++j) acc[i][j] = (f32x4){0.f, 0.f, 0.f, 0.f};
    for (int k0 = 0; k0 < IEXP; k0 += 32) {
        gload16(gA0 + k0, lA0);
        gload16(gA1 + k0, lA1);
        gload16(gB0 + k0, lB0);
        gload16(gB1 + k0, lB1);
        __syncthreads();
        bf16x8 af[4], bfv[4];
#pragma unroll
        for (int i = 0; i < 4; ++i) {
            af[i]  = *(const bf16x8*)(As + (wm * 64 + i * 16 + fr) * 32 + fc);
            bfv[i] = *(const bf16x8*)(Bs + (wn * 64 + i * 16 + fr) * 32 + fc);
        }
#pragma unroll
        for (int mf = 0; mf < 4; ++mf)
#pragma unroll
            for (int nf = 0; nf < 4; ++nf)
                acc[mf][nf] = __builtin_amdgcn_mfma_f32_16x16x32_bf16(
                    af[mf], bfv[nf], acc[mf][nf], 0, 0, 0);
        __syncthreads();
    }
    const int er = (l >> 4) << 2, ec = l & 15;
#pragma unroll
    for (int mf = 0; mf < 4; ++mf)
#pragma unroll
        for (int i = 0; i < 4; ++i) {
            int row = m0 + wm * 64 + mf * 16 + er + i;
            if (row >= Ce) continue;
            size_t sl = (size_t)(base + row);
            float sw = slot_w[sl];
#pragma unroll
            for (int nf = 0; nf < 4; ++nf) {
                int col = n0 + wn * 64 + nf * 16 + ec;
                D[sl * HID + col] = acc[mf][nf][i] * sw;
            }
        }
}

__global__ __launch_bounds__(256)
void moe_add(float* __restrict__ out, const float* __restrict__ D,
             const int* __restrict__ token_slot) {
    const int t = blockIdx.y;
    const int h = blockIdx.x * 256 + threadIdx.x;
    int s0 = token_slot[t * 2], s1 = token_slot[t * 2 + 1];
    out[(size_t)t * HID + h] += D[(size_t)s0 * HID + h] + D[(size_t)s1 * HID + h];
}

// ---------------------------------------------------------------------------
extern "C" void kernel_launch(void* const* d_in, const int* in_sizes, int n_in,
                              void* d_out, int out_size, void* d_ws, size_t ws_size,
                              hipStream_t stream) {
    const float* hidden = (const float*)d_in[0];
    const float* amask  = (const float*)d_in[1];
    const float* gmask  = (const float*)d_in[2];
    const int*   posids = (const int*)d_in[3];
    const float* ln1 = (const float*)d_in[4];
    const float* ln2 = (const float*)d_in[5];
    const float* ln3 = (const float*)d_in[6];
    const float* sqw = (const float*)d_in[7];  const float* sqb = (const float*)d_in[8];
    const float* skw = (const float*)d_in[9];  const float* skb = (const float*)d_in[10];
    const float* svw = (const float*)d_in[11]; const float* svb = (const float*)d_in[12];
    const float* sow = (const float*)d_in[13];
    const float* gqw = (const float*)d_in[14]; const float* gqb = (const float*)d_in[15];
    const float* gkw = (const float*)d_in[16]; const float* gkb = (const float*)d_in[17];
    const float* gvw = (const float*)d_in[18]; const float* gvb = (const float*)d_in[19];
    const float* gow = (const float*)d_in[20];
    const float* gatew = (const float*)d_in[21];
    const float* wg = (const float*)d_in[22];
    const float* wu = (const float*)d_in[23];
    const float* wd = (const float*)d_in[24];
    float* out = (float*)d_out;
    (void)amask;

    // ---- workspace carve (byte offsets), ~121.8 MB ----
    char* base = (char*)d_ws;
    float* xb     = (float*)(base + 0);
    float* qb     = (float*)(base + 12582912);
    float* kbuf   = (float*)(base + 25165824);
    float* vbuf   = (float*)(base + 29360128);
    float* ab     = (float*)(base + 33554432);
    u16* wqkv_sh  = (u16*)(base + 46137344);
    u16* wqkv_sl  = (u16*)(base + 48103424);
    u16* wo_sh    = (u16*)(base + 50069504);
    u16* wo_sl    = (u16*)(base + 51249152);
    u16* wqkv_gh  = (u16*)(base + 52428800);
    u16* wqkv_gl  = (u16*)(base + 54394880);
    u16* wo_gh    = (u16*)(base + 56360960);
    u16* wo_gl    = (u16*)(base + 57540608);
    u16* wgt      = (u16*)(base + 58720256);
    u16* wut      = (u16*)(base + 77594624);
    u16* wdt      = (u16*)(base + 96468992);
    float* slotw  = (float*)(base + 115343360);
    float* topw   = (float*)(base + 115376128);
    int* counts   = (int*)(base + 115408896);
    int* offsets  = (int*)(base + 115409024);
    int* topi     = (int*)(base + 115409408);
    int* posb     = (int*)(base + 115442176);
    int* slot_token = (int*)(base + 115474944);
    int* token_slot = (int*)(base + 115507712);
    u16* xbf      = (u16*)(base + 115540480);   // 6,291,456 -> 121,831,936
    // MoE-phase overlays (attention activations + attn weights dead by then):
    u16*   Hbuf  = (u16*)  (base + 12582912);   // 25,165,824 B
    float* Dbuf  = (float*)(base + 37748736);   // 25,165,824 B (clobbers attn W + wgt head; both done)

    // ---- weight prep ----
    cvt_split<<<576, 256, 0, stream>>>(sqw, wqkv_sh, wqkv_sl, 589824);
    cvt_split<<<192, 256, 0, stream>>>(skw, wqkv_sh + 589824, wqkv_sl + 589824, 196608);
    cvt_split<<<192, 256, 0, stream>>>(svw, wqkv_sh + 786432, wqkv_sl + 786432, 196608);
    cvt_split<<<576, 256, 0, stream>>>(sow, wo_sh, wo_sl, 589824);
    cvt_split<<<576, 256, 0, stream>>>(gqw, wqkv_gh, wqkv_gl, 589824);
    cvt_split<<<192, 256, 0, stream>>>(gkw, wqkv_gh + 589824, wqkv_gl + 589824, 196608);
    cvt_split<<<192, 256, 0, stream>>>(gvw, wqkv_gh + 786432, wqkv_gl + 786432, 196608);
    cvt_split<<<576, 256, 0, stream>>>(gow, wo_gh, wo_gl, 589824);
    transpose_cvt<<<dim3(48, 24, 8), dim3(32, 8), 0, stream>>>(wg, wgt, HID, IEXP);
    transpose_cvt<<<dim3(48, 24, 8), dim3(32, 8), 0, stream>>>(wu, wut, HID, IEXP);
    transpose_cvt<<<dim3(24, 48, 8), dim3(32, 8), 0, stream>>>(wd, wdt, IEXP, HID);

    // ---- self attention ----
    rmsnorm_kernel<<<NTOK, 256, 0, stream>>>(hidden, ln1, xb, nullptr);
    qkv_split<<<dim3(10, 32), 256, 0, stream>>>(xb, wqkv_sh, wqkv_sl,
                                                sqb, skb, svb, qb, kbuf, vbuf);
    rope_kernel<<<NTOK, 256, 0, stream>>>(qb, kbuf, posids);
    attn_self_mfma<<<dim3(SEQ / 32, NHEAD, BATCH), 256, 0, stream>>>(qb, kbuf, vbuf, ab);
    oproj_split<<<dim3(6, 32), 256, 0, stream>>>(ab, wo_sh, wo_sl, hidden, out,
                                                 NTOK, HID, HID);

    // ---- group attention ----
    rmsnorm_kernel<<<NTOK, 256, 0, stream>>>(out, ln2, xb, nullptr);
    qkv_split<<<dim3(10, 32), 256, 0, stream>>>(xb, wqkv_gh, wqkv_gl,
                                                gqb, gkb, gvb, qb, kbuf, vbuf);
    attn_group<<<SEQ * NHEAD, 64, 0, stream>>>(qb, kbuf, vbuf, gmask, ab);
    oproj_split<<<dim3(6, 32), 256, 0, stream>>>(ab, wo_gh, wo_gl, out, out,
                                                 NTOK, HID, HID);

    // ---- MoE (bf16 MFMA: post-router, flip-free) ----
    rmsnorm_kernel<<<NTOK, 256, 0, stream>>>(out, ln3, xb, xbf);
    hipMemsetAsync(counts, 0, 8 * sizeof(int), stream);
    router_kernel<<<NTOK, 64, 0, stream>>>(xb, gatew, counts, topi, topw, posb);
    scan_kernel<<<1, 1, 0, stream>>>(counts, offsets);
    fill_slots<<<16, 256, 0, stream>>>(topi, topw, posb, offsets,
                                       slot_token, slotw, token_slot);
    moe_gate_up<<<dim3(32, 12, 8), 256, 0, stream>>>(
        xbf, wgt, wut, slot_token, counts, offsets, Hbuf);
    moe_down_bf16<<<dim3(32, 6, 8), 256, 0, stream>>>(
        Hbuf, wdt, slotw, counts, offsets, Dbuf);
    moe_add<<<dim3(3, NTOK), 256, 0, stream>>>(out, Dbuf, token_slot);
}

// Round 8
// 692.413 us; speedup vs baseline: 1.2593x; 1.2593x over previous
//
#include <hip/hip_runtime.h>
#include <math.h>

// Problem constants
#define BATCH 8
#define SEQ 512
#define HID 768
#define NHEAD 12
#define KVHEAD 4
#define HDIM 64
#define NEXP 8
#define TOPK 2
#define IEXP 1536
#define NTOK (BATCH * SEQ)     // 4096
#define NSLOT (NTOK * TOPK)    // 8192
#define REP (NHEAD / KVHEAD)   // 3

typedef unsigned short u16;
typedef float f32x4 __attribute__((ext_vector_type(4)));
typedef __bf16 bf16x8 __attribute__((ext_vector_type(8)));
typedef unsigned short u16x8 __attribute__((ext_vector_type(8)));

__device__ __forceinline__ u16 f2bf(float f) {
    unsigned u = __float_as_uint(f);
    u += 0x7fffu + ((u >> 16) & 1u);   // RNE
    return (u16)(u >> 16);
}
__device__ __forceinline__ float bf2f(u16 h) {
    return __uint_as_float(((unsigned)h) << 16);
}

__device__ __forceinline__ void gload16(const void* g, void* l) {
    __builtin_amdgcn_global_load_lds(
        (const __attribute__((address_space(1))) void*)g,
        (__attribute__((address_space(3))) void*)l, 16, 0, 0);
}

// split 8 fp32 -> hi/lo bf16
__device__ __forceinline__ void cvt8(float4 a, float4 b, u16x8& hi, u16x8& lo) {
    float x[8] = {a.x, a.y, a.z, a.w, b.x, b.y, b.z, b.w};
#pragma unroll
    for (int i = 0; i < 8; ++i) {
        u16 h = f2bf(x[i]);
        hi[i] = h;
        lo[i] = f2bf(x[i] - bf2f(h));
    }
}

// swizzled element offset in a row-major [R][64] bf16 LDS tile (stride 128B):
// XOR the 16B-chunk index with (row&7) -> 2-way max bank aliasing (free).
#define SW(row, col) (((row) << 6) + ((col) ^ (((row) & 7) << 3)))

// ---------------------------------------------------------------------------
// fp32 -> bf16 hi/lo split convert (weights)
// ---------------------------------------------------------------------------
__global__ __launch_bounds__(256)
void cvt_split(const float* __restrict__ x, u16* __restrict__ yh,
               u16* __restrict__ yl, int n) {
    int i = (blockIdx.x * 256 + threadIdx.x) * 4;
    if (i >= n) return;
    float4 v = *(const float4*)(x + i);
    float a[4] = {v.x, v.y, v.z, v.w};
    ushort4 h, lo;
    u16 t;
    t = f2bf(a[0]); h.x = t; lo.x = f2bf(a[0] - bf2f(t));
    t = f2bf(a[1]); h.y = t; lo.y = f2bf(a[1] - bf2f(t));
    t = f2bf(a[2]); h.z = t; lo.z = f2bf(a[2] - bf2f(t));
    t = f2bf(a[3]); h.w = t; lo.w = f2bf(a[3] - bf2f(t));
    *(ushort4*)(yh + i) = h;
    *(ushort4*)(yl + i) = lo;
}

// ---------------------------------------------------------------------------
// per-expert transpose + convert: src[e][R][C] fp32 -> dst[e][C][R] bf16
// ---------------------------------------------------------------------------
__global__ __launch_bounds__(256)
void transpose_cvt(const float* __restrict__ src, u16* __restrict__ dst,
                   int R, int C) {
    const int e = blockIdx.z;
    src += (size_t)e * R * C;
    dst += (size_t)e * R * C;
    __shared__ float t[32][33];
    const int c0 = blockIdx.x << 5, r0 = blockIdx.y << 5;
    const int tx = threadIdx.x, ty = threadIdx.y;
#pragma unroll
    for (int i = 0; i < 4; ++i)
        t[ty * 4 + i][tx] = src[(size_t)(r0 + ty * 4 + i) * C + c0 + tx];
    __syncthreads();
#pragma unroll
    for (int i = 0; i < 4; ++i)
        dst[(size_t)(c0 + ty * 4 + i) * R + r0 + tx] = f2bf(t[tx][ty * 4 + i]);
}

// ---------------------------------------------------------------------------
// RMSNorm: one block per token (fp32 out)
// ---------------------------------------------------------------------------
__global__ __launch_bounds__(256)
void rmsnorm_kernel(const float* __restrict__ X, const float* __restrict__ W,
                    float* __restrict__ Y) {
    const int t = blockIdx.x;
    const int tid = threadIdx.x;
    const float* x = X + (size_t)t * HID;
    float x0 = x[tid], x1 = x[tid + 256], x2 = x[tid + 512];
    float ss = x0 * x0 + x1 * x1 + x2 * x2;
    for (int m = 1; m < 64; m <<= 1) ss += __shfl_xor(ss, m);
    __shared__ float red[4];
    if ((tid & 63) == 0) red[tid >> 6] = ss;
    __syncthreads();
    float tot = red[0] + red[1] + red[2] + red[3];
    float inv = rsqrtf(tot * (1.0f / HID) + 1e-6f);
    float* y = Y + (size_t)t * HID;
    y[tid]       = x0 * inv * W[tid];
    y[tid + 256] = x1 * inv * W[tid + 256];
    y[tid + 512] = x2 * inv * W[tid + 512];
}

// ---------------------------------------------------------------------------
// Split-precision MFMA NT GEMM for QKV. A fp32 (hi/lo in-kernel),
// Wh/Wl bf16 [1280][768]. 128x128 tile, BK=32. Grid (10, 32).
// ---------------------------------------------------------------------------
__global__ __launch_bounds__(256)
void qkv_split(const float* __restrict__ X, const u16* __restrict__ Wh,
               const u16* __restrict__ Wl,
               const float* __restrict__ bq, const float* __restrict__ bk,
               const float* __restrict__ bv,
               float* __restrict__ Qo, float* __restrict__ Ko,
               float* __restrict__ Vo) {
    __shared__ __align__(16) u16 Ah[4096], Al[4096], Bh[4096], Bl[4096];
    const int tid = threadIdx.x, l = tid & 63, w = tid >> 6;
    const int wm = w & 1, wn = w >> 1;
    const int m0 = blockIdx.y << 7, n0 = blockIdx.x << 7;
    const int sr = l >> 2, sc8 = (l & 3) << 3;
    const float* gA0 = X + (size_t)(m0 + w * 32 + sr) * HID + sc8;
    const float* gA1 = gA0 + 16 * HID;
    const u16* gBh0 = Wh + (size_t)(n0 + w * 32 + sr) * HID + sc8;
    const u16* gBh1 = gBh0 + 16 * HID;
    const u16* gBl0 = Wl + (size_t)(n0 + w * 32 + sr) * HID + sc8;
    const u16* gBl1 = gBl0 + 16 * HID;
    const int aoff0 = (w * 32 + sr) * 32 + sc8, aoff1 = aoff0 + 512;
    u16* lBh0 = Bh + w * 1024; u16* lBh1 = lBh0 + 512;
    u16* lBl0 = Bl + w * 1024; u16* lBl1 = lBl0 + 512;
    const int fr = l & 15, fc = (l >> 4) << 3;
    f32x4 acc[4][4];
#pragma unroll
    for (int i = 0; i < 4; ++i)
#pragma unroll
        for (int j = 0; j < 4; ++j) acc[i][j] = (f32x4){0.f, 0.f, 0.f, 0.f};
    for (int k0 = 0; k0 < HID; k0 += 32) {
        float4 a00 = *(const float4*)(gA0 + k0);
        float4 a01 = *(const float4*)(gA0 + k0 + 4);
        float4 a10 = *(const float4*)(gA1 + k0);
        float4 a11 = *(const float4*)(gA1 + k0 + 4);
        gload16(gBh0 + k0, lBh0);
        gload16(gBh1 + k0, lBh1);
        gload16(gBl0 + k0, lBl0);
        gload16(gBl1 + k0, lBl1);
        u16x8 h0, l0v, h1, l1v;
        cvt8(a00, a01, h0, l0v);
        cvt8(a10, a11, h1, l1v);
        *(u16x8*)(Ah + aoff0) = h0; *(u16x8*)(Al + aoff0) = l0v;
        *(u16x8*)(Ah + aoff1) = h1; *(u16x8*)(Al + aoff1) = l1v;
        __syncthreads();
        bf16x8 ah[4], al[4], bh[4], bl[4];
#pragma unroll
        for (int i = 0; i < 4; ++i) {
            ah[i] = *(const bf16x8*)(Ah + (wm * 64 + i * 16 + fr) * 32 + fc);
            al[i] = *(const bf16x8*)(Al + (wm * 64 + i * 16 + fr) * 32 + fc);
            bh[i] = *(const bf16x8*)(Bh + (wn * 64 + i * 16 + fr) * 32 + fc);
            bl[i] = *(const bf16x8*)(Bl + (wn * 64 + i * 16 + fr) * 32 + fc);
        }
#pragma unroll
        for (int mf = 0; mf < 4; ++mf)
#pragma unroll
            for (int nf = 0; nf < 4; ++nf) {
                acc[mf][nf] = __builtin_amdgcn_mfma_f32_16x16x32_bf16(
                    ah[mf], bh[nf], acc[mf][nf], 0, 0, 0);
                acc[mf][nf] = __builtin_amdgcn_mfma_f32_16x16x32_bf16(
                    al[mf], bh[nf], acc[mf][nf], 0, 0, 0);
                acc[mf][nf] = __builtin_amdgcn_mfma_f32_16x16x32_bf16(
                    ah[mf], bl[nf], acc[mf][nf], 0, 0, 0);
            }
        __syncthreads();
    }
    float* outp; const float* bp; int ldc, nl;
    if (n0 < 768)       { outp = Qo; bp = bq; ldc = 768; nl = n0; }
    else if (n0 < 1024) { outp = Ko; bp = bk; ldc = 256; nl = n0 - 768; }
    else                { outp = Vo; bp = bv; ldc = 256; nl = n0 - 1024; }
    const int er = (l >> 4) << 2, ec = l & 15;
#pragma unroll
    for (int mf = 0; mf < 4; ++mf)
#pragma unroll
        for (int i = 0; i < 4; ++i) {
            int row = m0 + wm * 64 + mf * 16 + er + i;
#pragma unroll
            for (int nf = 0; nf < 4; ++nf) {
                int col = nl + wn * 64 + nf * 16 + ec;
                outp[(size_t)row * ldc + col] = acc[mf][nf][i] + bp[col];
            }
        }
}

// ---------------------------------------------------------------------------
// Split-precision MFMA NT GEMM with residual: C = A@W^T + resid.
// ---------------------------------------------------------------------------
__global__ __launch_bounds__(256)
void oproj_split(const float* __restrict__ A, const u16* __restrict__ Wh,
                 const u16* __restrict__ Wl, const float* __restrict__ resid,
                 float* __restrict__ C, int M, int N, int K) {
    __shared__ __align__(16) u16 Ah[4096], Al[4096], Bh[4096], Bl[4096];
    const int tid = threadIdx.x, l = tid & 63, w = tid >> 6;
    const int wm = w & 1, wn = w >> 1;
    const int m0 = blockIdx.y << 7, n0 = blockIdx.x << 7;
    const int sr = l >> 2, sc8 = (l & 3) << 3;
    const float* gA0 = A + (size_t)(m0 + w * 32 + sr) * K + sc8;
    const float* gA1 = gA0 + (size_t)16 * K;
    const u16* gBh0 = Wh + (size_t)(n0 + w * 32 + sr) * K + sc8;
    const u16* gBh1 = gBh0 + (size_t)16 * K;
    const u16* gBl0 = Wl + (size_t)(n0 + w * 32 + sr) * K + sc8;
    const u16* gBl1 = gBl0 + (size_t)16 * K;
    const int aoff0 = (w * 32 + sr) * 32 + sc8, aoff1 = aoff0 + 512;
    u16* lBh0 = Bh + w * 1024; u16* lBh1 = lBh0 + 512;
    u16* lBl0 = Bl + w * 1024; u16* lBl1 = lBl0 + 512;
    const int fr = l & 15, fc = (l >> 4) << 3;
    f32x4 acc[4][4];
#pragma unroll
    for (int i = 0; i < 4; ++i)
#pragma unroll
        for (int j = 0; j < 4; ++j) acc[i][j] = (f32x4){0.f, 0.f, 0.f, 0.f};
    for (int k0 = 0; k0 < K; k0 += 32) {
        float4 a00 = *(const float4*)(gA0 + k0);
        float4 a01 = *(const float4*)(gA0 + k0 + 4);
        float4 a10 = *(const float4*)(gA1 + k0);
        float4 a11 = *(const float4*)(gA1 + k0 + 4);
        gload16(gBh0 + k0, lBh0);
        gload16(gBh1 + k0, lBh1);
        gload16(gBl0 + k0, lBl0);
        gload16(gBl1 + k0, lBl1);
        u16x8 h0, l0v, h1, l1v;
        cvt8(a00, a01, h0, l0v);
        cvt8(a10, a11, h1, l1v);
        *(u16x8*)(Ah + aoff0) = h0; *(u16x8*)(Al + aoff0) = l0v;
        *(u16x8*)(Ah + aoff1) = h1; *(u16x8*)(Al + aoff1) = l1v;
        __syncthreads();
        bf16x8 ah[4], al[4], bh[4], bl[4];
#pragma unroll
        for (int i = 0; i < 4; ++i) {
            ah[i] = *(const bf16x8*)(Ah + (wm * 64 + i * 16 + fr) * 32 + fc);
            al[i] = *(const bf16x8*)(Al + (wm * 64 + i * 16 + fr) * 32 + fc);
            bh[i] = *(const bf16x8*)(Bh + (wn * 64 + i * 16 + fr) * 32 + fc);
            bl[i] = *(const bf16x8*)(Bl + (wn * 64 + i * 16 + fr) * 32 + fc);
        }
#pragma unroll
        for (int mf = 0; mf < 4; ++mf)
#pragma unroll
            for (int nf = 0; nf < 4; ++nf) {
                acc[mf][nf] = __builtin_amdgcn_mfma_f32_16x16x32_bf16(
                    ah[mf], bh[nf], acc[mf][nf], 0, 0, 0);
                acc[mf][nf] = __builtin_amdgcn_mfma_f32_16x16x32_bf16(
                    al[mf], bh[nf], acc[mf][nf], 0, 0, 0);
                acc[mf][nf] = __builtin_amdgcn_mfma_f32_16x16x32_bf16(
                    ah[mf], bl[nf], acc[mf][nf], 0, 0, 0);
            }
        __syncthreads();
    }
    const int er = (l >> 4) << 2, ec = l & 15;
#pragma unroll
    for (int mf = 0; mf < 4; ++mf)
#pragma unroll
        for (int i = 0; i < 4; ++i) {
            int row = m0 + wm * 64 + mf * 16 + er + i;
#pragma unroll
            for (int nf = 0; nf < 4; ++nf) {
                int col = n0 + wn * 64 + nf * 16 + ec;
                C[(size_t)row * N + col] =
                    acc[mf][nf][i] + resid[(size_t)row * N + col];
            }
        }
}

// ---------------------------------------------------------------------------
// RoPE in-place on q (12 heads) and k (4 heads) per token
// ---------------------------------------------------------------------------
__global__ __launch_bounds__(256)
void rope_kernel(float* __restrict__ Q, float* __restrict__ Kb,
                 const int* __restrict__ pos_ids) {
    const int t = blockIdx.x;
    const float pos = (float)pos_ids[t];
    const int tid = threadIdx.x;
#pragma unroll
    for (int it = 0; it < 2; ++it) {
        int p = tid + (it << 8);
        int head = p >> 5, i = p & 31;
        float invf = expf(-(float)i * 0.28782313662425572f); // ln(1e4)/32
        float ang = pos * invf;
        float c = cosf(ang), sn = sinf(ang);
        float* base = (head < NHEAD)
            ? (Q + (size_t)t * HID + head * HDIM)
            : (Kb + (size_t)t * (KVHEAD * HDIM) + (head - NHEAD) * HDIM);
        float x1 = base[i], x2 = base[i + 32];
        base[i]      = x1 * c - x2 * sn;
        base[i + 32] = x2 * c + x1 * sn;
    }
}

// ---------------------------------------------------------------------------
// Self attention (causal GQA) via split-precision MFMA, online softmax.
// Block: 256 thr (4 waves) = 32 queries. Tiles of 64 keys.
// ---------------------------------------------------------------------------
__global__ __launch_bounds__(256)
void attn_self_mfma(const float* __restrict__ Q, const float* __restrict__ K,
                    const float* __restrict__ V, float* __restrict__ O) {
    const int qt = blockIdx.x, n = blockIdx.y, b = blockIdx.z;
    const int kv = n / REP;
    const int tid = threadIdx.x, l = tid & 63, w = tid >> 6;
    const int q0 = qt << 5;
    __shared__ __align__(16) u16 Qh[2048], Ql[2048];    // [32][64]
    __shared__ __align__(16) u16 Kh[4096], Kl[4096];    // [64][64]
    __shared__ __align__(16) u16 Vh[4096], Vl[4096];    // transposed [d][key]
    __shared__ float Ps[32][68];
    __shared__ float scal[32];

    // ---- stage Q (hi/lo, swizzled) ----
    {
        int row = tid >> 3, cg = (tid & 7) << 3;
        const float* qg = Q + (size_t)(b * SEQ + q0 + row) * HID + n * HDIM + cg;
        float4 v0 = *(const float4*)qg;
        float4 v1 = *(const float4*)(qg + 4);
        u16x8 h, lo;
        cvt8(v0, v1, h, lo);
        *(u16x8*)(Qh + SW(row, cg)) = h;
        *(u16x8*)(Ql + SW(row, cg)) = lo;
    }
    __syncthreads();

    const int fr = l & 15, fcg = (l >> 4) << 3;
    const int qf16 = (w & 1) << 4;
    const int fp2 = (w >> 1) << 1;      // frag pair base (k or d)
    bf16x8 qfh[2], qfl[2];
#pragma unroll
    for (int dc = 0; dc < 2; ++dc) {
        int off = SW(qf16 + fr, dc * 32 + fcg);
        qfh[dc] = *(const bf16x8*)(Qh + off);
        qfl[dc] = *(const bf16x8*)(Ql + off);
    }

    f32x4 o[2];
    o[0] = (f32x4){0.f, 0.f, 0.f, 0.f};
    o[1] = (f32x4){0.f, 0.f, 0.f, 0.f};
    float m_run = -3.4e38f, l_run = 0.f;
    const int sq = tid >> 3;
    const int skb = (tid & 7) << 3;
    const float scale = 0.125f;
    const int nt = (qt >> 1) + 1;

    for (int t = 0; t < nt; ++t) {
        __syncthreads();
        // ---- stage K tile (hi/lo, swizzled) ----
        {
            int row = tid >> 2, cg = (tid & 3) << 4;
            const float* kg = K + (size_t)(b * SEQ + (t << 6) + row)
                              * (KVHEAD * HDIM) + kv * HDIM + cg;
            float4 k0 = *(const float4*)kg;
            float4 k1 = *(const float4*)(kg + 4);
            float4 k2 = *(const float4*)(kg + 8);
            float4 k3 = *(const float4*)(kg + 12);
            u16x8 h0, l0v, h1, l1v;
            cvt8(k0, k1, h0, l0v);
            cvt8(k2, k3, h1, l1v);
            *(u16x8*)(Kh + SW(row, cg)) = h0;
            *(u16x8*)(Kh + SW(row, cg + 8)) = h1;
            *(u16x8*)(Kl + SW(row, cg)) = l0v;
            *(u16x8*)(Kl + SW(row, cg + 8)) = l1v;
        }
        // ---- stage V tile transposed [d][key] (hi/lo, swizzled) ----
        {
            int kp = (tid & 31) << 1, dc = (tid >> 5) << 3;
            const float* vg0 = V + (size_t)(b * SEQ + (t << 6) + kp)
                               * (KVHEAD * HDIM) + kv * HDIM + dc;
            const float* vg1 = vg0 + KVHEAD * HDIM;
            float4 a0 = *(const float4*)vg0;
            float4 a1 = *(const float4*)(vg0 + 4);
            float4 b0 = *(const float4*)vg1;
            float4 b1 = *(const float4*)(vg1 + 4);
            float va[8] = {a0.x, a0.y, a0.z, a0.w, a1.x, a1.y, a1.z, a1.w};
            float vb[8] = {b0.x, b0.y, b0.z, b0.w, b1.x, b1.y, b1.z, b1.w};
#pragma unroll
            for (int j = 0; j < 8; ++j) {
                u16 h0 = f2bf(va[j]);
                u16 h1 = f2bf(vb[j]);
                u16 p0 = f2bf(va[j] - bf2f(h0));
                u16 p1 = f2bf(vb[j] - bf2f(h1));
                int off = SW(dc + j, kp);
                *(unsigned*)(Vh + off) = (unsigned)h0 | ((unsigned)h1 << 16);
                *(unsigned*)(Vl + off) = (unsigned)p0 | ((unsigned)p1 << 16);
            }
        }
        __syncthreads();
        // ---- S = Q K^T (split MFMA) ----
#pragma unroll
        for (int kk = 0; kk < 2; ++kk) {
            int kf = fp2 + kk;
            bf16x8 kh[2], klv[2];
#pragma unroll
            for (int dc = 0; dc < 2; ++dc) {
                int off = SW(kf * 16 + fr, dc * 32 + fcg);
                kh[dc]  = *(const bf16x8*)(Kh + off);
                klv[dc] = *(const bf16x8*)(Kl + off);
            }
            f32x4 s = (f32x4){0.f, 0.f, 0.f, 0.f};
            s = __builtin_amdgcn_mfma_f32_16x16x32_bf16(qfh[0], kh[0], s, 0, 0, 0);
            s = __builtin_amdgcn_mfma_f32_16x16x32_bf16(qfh[1], kh[1], s, 0, 0, 0);
            s = __builtin_amdgcn_mfma_f32_16x16x32_bf16(qfl[0], kh[0], s, 0, 0, 0);
            s = __builtin_amdgcn_mfma_f32_16x16x32_bf16(qfl[1], kh[1], s, 0, 0, 0);
            s = __builtin_amdgcn_mfma_f32_16x16x32_bf16(qfh[0], klv[0], s, 0, 0, 0);
            s = __builtin_amdgcn_mfma_f32_16x16x32_bf16(qfh[1], klv[1], s, 0, 0, 0);
            int col = kf * 16 + fr;
            int key = (t << 6) + col;
#pragma unroll
            for (int r = 0; r < 4; ++r) {
                int qrow = qf16 + ((l >> 4) << 2) + r;
                Ps[qrow][col] = (key <= q0 + qrow) ? s[r] * scale : -1e9f;
            }
        }
        __syncthreads();
        // ---- online softmax update (8 threads per query) ----
        {
            float4 s0 = *(const float4*)&Ps[sq][skb];
            float4 s1 = *(const float4*)&Ps[sq][skb + 4];
            float sv[8] = {s0.x, s0.y, s0.z, s0.w, s1.x, s1.y, s1.z, s1.w};
            float mx = sv[0];
#pragma unroll
            for (int j = 1; j < 8; ++j) mx = fmaxf(mx, sv[j]);
            for (int x = 1; x < 8; x <<= 1) mx = fmaxf(mx, __shfl_xor(mx, x));
            float mnew = fmaxf(m_run, mx);
            float corr = __expf(m_run - mnew);
            float lsum = 0.f;
#pragma unroll
            for (int j = 0; j < 8; ++j) {
                sv[j] = __expf(sv[j] - mnew);
                lsum += sv[j];
            }
            for (int x = 1; x < 8; x <<= 1) lsum += __shfl_xor(lsum, x);
            l_run = l_run * corr + lsum;
            m_run = mnew;
            *(float4*)&Ps[sq][skb]     = make_float4(sv[0], sv[1], sv[2], sv[3]);
            *(float4*)&Ps[sq][skb + 4] = make_float4(sv[4], sv[5], sv[6], sv[7]);
            if ((tid & 7) == 0) scal[sq] = corr;
        }
        __syncthreads();
        // ---- rescale O, then O += P V (split MFMA) ----
        {
            float4 c4 = *(const float4*)&scal[qf16 + ((l >> 4) << 2)];
            float cr[4] = {c4.x, c4.y, c4.z, c4.w};
#pragma unroll
            for (int dfi = 0; dfi < 2; ++dfi)
#pragma unroll
                for (int r = 0; r < 4; ++r) o[dfi][r] *= cr[r];
            bf16x8 ph[2], pl[2];
#pragma unroll
            for (int kc = 0; kc < 2; ++kc) {
                float4 p0 = *(const float4*)&Ps[qf16 + fr][kc * 32 + fcg];
                float4 p1 = *(const float4*)&Ps[qf16 + fr][kc * 32 + fcg + 4];
                u16x8 hh, ll;
                cvt8(p0, p1, hh, ll);
                ph[kc] = *(bf16x8*)&hh;
                pl[kc] = *(bf16x8*)&ll;
            }
#pragma unroll
            for (int dfi = 0; dfi < 2; ++dfi) {
                int df = fp2 + dfi;
#pragma unroll
                for (int kc = 0; kc < 2; ++kc) {
                    int off = SW(df * 16 + fr, kc * 32 + fcg);
                    bf16x8 vh = *(const bf16x8*)(Vh + off);
                    bf16x8 vl = *(const bf16x8*)(Vl + off);
                    o[dfi] = __builtin_amdgcn_mfma_f32_16x16x32_bf16(
                        ph[kc], vh, o[dfi], 0, 0, 0);
                    o[dfi] = __builtin_amdgcn_mfma_f32_16x16x32_bf16(
                        pl[kc], vh, o[dfi], 0, 0, 0);
                    o[dfi] = __builtin_amdgcn_mfma_f32_16x16x32_bf16(
                        ph[kc], vl, o[dfi], 0, 0, 0);
                }
            }
        }
    }
    __syncthreads();
    if ((tid & 7) == 0) scal[sq] = 1.0f / l_run;
    __syncthreads();
    {
        int qrb = qf16 + ((l >> 4) << 2);
        float4 li4 = *(const float4*)&scal[qrb];
        float li[4] = {li4.x, li4.y, li4.z, li4.w};
#pragma unroll
        for (int dfi = 0; dfi < 2; ++dfi) {
            int df = fp2 + dfi;
            int col = n * HDIM + df * 16 + fr;
#pragma unroll
            for (int r = 0; r < 4; ++r) {
                int row = q0 + qrb + r;
                O[(size_t)(b * SEQ + row) * HID + col] = o[dfi][r] * li[r];
            }
        }
    }
}

// ---------------------------------------------------------------------------
// Group attention: MHA across the 8 channels. One wave per (s, head).
// ---------------------------------------------------------------------------
__global__ __launch_bounds__(64)
void attn_group(const float* __restrict__ Q, const float* __restrict__ K,
                const float* __restrict__ V, const float* __restrict__ gmask,
                float* __restrict__ O) {
    const int n = blockIdx.x % NHEAD;
    const int s = blockIdx.x / NHEAD;
    const int kv = n / REP;
    const int lane = threadIdx.x;
    __shared__ float Qs[8][65], Ks[8][65], Vs[8][65], Ps[64];
    for (int c = 0; c < 8; ++c) {
        Qs[c][lane] = Q[(size_t)(c * SEQ + s) * HID + n * HDIM + lane];
        Ks[c][lane] = K[(size_t)(c * SEQ + s) * (KVHEAD * HDIM) + kv * HDIM + lane];
        Vs[c][lane] = V[(size_t)(c * SEQ + s) * (KVHEAD * HDIM) + kv * HDIM + lane];
    }
    __syncthreads();
    const int qb = lane >> 3, kb = lane & 7;
    float sc = 0;
    for (int d = 0; d < 64; ++d) sc += Qs[qb][d] * Ks[kb][d];
    sc = sc * 0.125f + gmask[(size_t)s * 64 + qb * 8 + kb];
    float m = sc;
    for (int x = 1; x < 8; x <<= 1) m = fmaxf(m, __shfl_xor(m, x));
    float p = __expf(sc - m);
    float l = p;
    for (int x = 1; x < 8; x <<= 1) l += __shfl_xor(l, x);
    Ps[lane] = p / l;
    __syncthreads();
    for (int q2 = 0; q2 < 8; ++q2) {
        float o = 0;
        for (int c = 0; c < 8; ++c) o += Ps[q2 * 8 + c] * Vs[c][lane];
        O[(size_t)(q2 * SEQ + s) * HID + n * HDIM + lane] = o;
    }
}

// ---------------------------------------------------------------------------
// MoE router (fp32)
// ---------------------------------------------------------------------------
__global__ __launch_bounds__(64)
void router_kernel(const float* __restrict__ X, const float* __restrict__ GW,
                   int* __restrict__ counts, int* __restrict__ topi,
                   float* __restrict__ topw, int* __restrict__ posb) {
    const int t = blockIdx.x;
    const int lane = threadIdx.x;
    const int e = lane >> 3, c = lane & 7;
    const float4* x4 = (const float4*)(X + (size_t)t * HID + c * 96);
    const float4* g4 = (const float4*)(GW + (size_t)e * HID + c * 96);
    float p = 0;
#pragma unroll
    for (int i = 0; i < 24; ++i) {
        float4 xv = x4[i], gv = g4[i];
        p += xv.x * gv.x + xv.y * gv.y + xv.z * gv.z + xv.w * gv.w;
    }
    p += __shfl_xor(p, 1);
    p += __shfl_xor(p, 2);
    p += __shfl_xor(p, 4);
    float lg[8];
#pragma unroll
    for (int i = 0; i < 8; ++i) lg[i] = __shfl(p, i * 8);
    float m = lg[0];
#pragma unroll
    for (int i = 1; i < 8; ++i) m = fmaxf(m, lg[i]);
    float s = 0;
#pragma unroll
    for (int i = 0; i < 8; ++i) { lg[i] = expf(lg[i] - m); s += lg[i]; }
    float inv = 1.0f / s;
    int i1 = 0; float b1 = lg[0];
#pragma unroll
    for (int i = 1; i < 8; ++i) if (lg[i] > b1) { b1 = lg[i]; i1 = i; }
    int i2 = -1; float b2 = -1.0f;
#pragma unroll
    for (int i = 0; i < 8; ++i)
        if (i != i1 && lg[i] > b2) { b2 = lg[i]; i2 = i; }
    if (lane == 0) {
        topi[t * 2] = i1; topi[t * 2 + 1] = i2;
        topw[t * 2] = b1 * inv; topw[t * 2 + 1] = b2 * inv;
        posb[t * 2] = atomicAdd(&counts[i1], 1);
        posb[t * 2 + 1] = atomicAdd(&counts[i2], 1);
    }
}

__global__ void scan_kernel(const int* __restrict__ counts, int* __restrict__ offsets) {
    int acc = 0;
    for (int e = 0; e < NEXP; ++e) { offsets[e] = acc; acc += counts[e]; }
}

__global__ __launch_bounds__(256)
void fill_slots(const int* __restrict__ topi, const float* __restrict__ topw,
                const int* __restrict__ posb, const int* __restrict__ offsets,
                int* __restrict__ slot_token, float* __restrict__ slot_w,
                int* __restrict__ token_slot) {
    int t = blockIdx.x * 256 + threadIdx.x;
    if (t >= NTOK) return;
#pragma unroll
    for (int k = 0; k < TOPK; ++k) {
        int e = topi[t * 2 + k];
        int sl = offsets[e] + posb[t * 2 + k];
        slot_token[sl] = t;
        slot_w[sl] = topw[t * 2 + k];
        token_slot[t * 2 + k] = sl;
    }
}

// ---------------------------------------------------------------------------
// MoE gate+up grouped GEMM. A fp32 gathered + split hi/lo; Wg/Wu bf16
// [e][IEXP][HID]. H bf16 out. 1D grid 3072, XCD-aware decode:
// xcd = bid&7 = expert; j = bid>>3: n = j>>5 (12 panels), m = j&31.
// All readers of one weight panel + one expert's A rows co-reside on one
// XCD so its private L2 serves the re-reads (panel fetched from HBM once).
// ---------------------------------------------------------------------------
__global__ __launch_bounds__(256)
void moe_gate_up(const float* __restrict__ X, const u16* __restrict__ Wg,
                 const u16* __restrict__ Wu,
                 const int* __restrict__ slot_token,
                 const int* __restrict__ counts,
                 const int* __restrict__ offsets, u16* __restrict__ H) {
    const int bid = blockIdx.x;
    const int e = bid & 7;
    const int j = bid >> 3;            // 0..383
    const int n0 = (j >> 5) << 7;      // 12 n-panels
    const int m0 = (j & 31) << 7;      // 32 m-slots
    const int Ce = counts[e];
    if (Ce == 0 || m0 >= Ce) return;
    const int base = offsets[e];
    __shared__ __align__(16) u16 Ah[4096];
    __shared__ __align__(16) u16 Al[4096];
    __shared__ __align__(16) u16 Gs[4096];
    __shared__ __align__(16) u16 Us[4096];
    const int tid = threadIdx.x, l = tid & 63, w = tid >> 6;
    const int wm = w & 1, wn = w >> 1;
    const int sr = l >> 2, sc8 = (l & 3) << 3;
    int r0 = m0 + w * 32 + sr;
    int r1 = r0 + 16;
    int t0 = slot_token[base + min(r0, Ce - 1)];
    int t1 = slot_token[base + min(r1, Ce - 1)];
    const float* gA0 = X + (size_t)t0 * HID + sc8;
    const float* gA1 = X + (size_t)t1 * HID + sc8;
    const u16* Wge = Wg + (size_t)e * IEXP * HID;
    const u16* Wue = Wu + (size_t)e * IEXP * HID;
    const u16* gG0 = Wge + (size_t)(n0 + w * 32 + sr) * HID + sc8;
    const u16* gG1 = gG0 + 16 * HID;
    const u16* gU0 = Wue + (size_t)(n0 + w * 32 + sr) * HID + sc8;
    const u16* gU1 = gU0 + 16 * HID;
    const int aoff0 = (w * 32 + sr) * 32 + sc8, aoff1 = aoff0 + 512;
    u16* lG0 = Gs + w * 1024; u16* lG1 = lG0 + 512;
    u16* lU0 = Us + w * 1024; u16* lU1 = lU0 + 512;
    const int fr = l & 15, fc = (l >> 4) << 3;
    f32x4 accg[4][4], accu[4][4];
#pragma unroll
    for (int i = 0; i < 4; ++i)
#pragma unroll
        for (int jj = 0; jj < 4; ++jj) {
            accg[i][jj] = (f32x4){0.f, 0.f, 0.f, 0.f};
            accu[i][jj] = (f32x4){0.f, 0.f, 0.f, 0.f};
        }
    for (int k0 = 0; k0 < HID; k0 += 32) {
        float4 a00 = *(const float4*)(gA0 + k0);
        float4 a01 = *(const float4*)(gA0 + k0 + 4);
        float4 a10 = *(const float4*)(gA1 + k0);
        float4 a11 = *(const float4*)(gA1 + k0 + 4);
        gload16(gG0 + k0, lG0);
        gload16(gG1 + k0, lG1);
        gload16(gU0 + k0, lU0);
        gload16(gU1 + k0, lU1);
        u16x8 h0, lo0, h1, lo1;
        cvt8(a00, a01, h0, lo0);
        cvt8(a10, a11, h1, lo1);
        *(u16x8*)(Ah + aoff0) = h0; *(u16x8*)(Al + aoff0) = lo0;
        *(u16x8*)(Ah + aoff1) = h1; *(u16x8*)(Al + aoff1) = lo1;
        __syncthreads();
        bf16x8 ah[4], al[4], gf[4], uf[4];
#pragma unroll
        for (int i = 0; i < 4; ++i) {
            ah[i] = *(const bf16x8*)(Ah + (wm * 64 + i * 16 + fr) * 32 + fc);
            al[i] = *(const bf16x8*)(Al + (wm * 64 + i * 16 + fr) * 32 + fc);
            gf[i] = *(const bf16x8*)(Gs + (wn * 64 + i * 16 + fr) * 32 + fc);
            uf[i] = *(const bf16x8*)(Us + (wn * 64 + i * 16 + fr) * 32 + fc);
        }
#pragma unroll
        for (int mf = 0; mf < 4; ++mf)
#pragma unroll
            for (int nf = 0; nf < 4; ++nf) {
                accg[mf][nf] = __builtin_amdgcn_mfma_f32_16x16x32_bf16(
                    ah[mf], gf[nf], accg[mf][nf], 0, 0, 0);
                accg[mf][nf] = __builtin_amdgcn_mfma_f32_16x16x32_bf16(
                    al[mf], gf[nf], accg[mf][nf], 0, 0, 0);
                accu[mf][nf] = __builtin_amdgcn_mfma_f32_16x16x32_bf16(
                    ah[mf], uf[nf], accu[mf][nf], 0, 0, 0);
                accu[mf][nf] = __builtin_amdgcn_mfma_f32_16x16x32_bf16(
                    al[mf], uf[nf], accu[mf][nf], 0, 0, 0);
            }
        __syncthreads();
    }
    const int er = (l >> 4) << 2, ec = l & 15;
#pragma unroll
    for (int mf = 0; mf < 4; ++mf)
#pragma unroll
        for (int i = 0; i < 4; ++i) {
            int row = m0 + wm * 64 + mf * 16 + er + i;
            if (row >= Ce) continue;
            size_t sl = (size_t)(base + row);
#pragma unroll
            for (int nf = 0; nf < 4; ++nf) {
                int col = n0 + wn * 64 + nf * 16 + ec;
                float g = accg[mf][nf][i];
                float u = accu[mf][nf][i];
                float h = g / (1.0f + __expf(-g)) * u;
                H[sl * IEXP + col] = f2bf(h);
            }
        }
}

// ---------------------------------------------------------------------------
// MoE down grouped GEMM bf16: D[slot][HID] fp32 = slot_w * (H @ Wd^T)
// Wd pre-transposed to [e][HID][IEXP]. 1D grid 1536, XCD-aware decode:
// xcd = bid&7 = expert; j = bid>>3: n = j>>5 (6 panels), m = j&31.
// ---------------------------------------------------------------------------
__global__ __launch_bounds__(256)
void moe_down_bf16(const u16* __restrict__ Hb, const u16* __restrict__ Wd,
                   const float* __restrict__ slot_w,
                   const int* __restrict__ counts,
                   const int* __restrict__ offsets, float* __restrict__ D) {
    const int bid = blockIdx.x;
    const int e = bid & 7;
    const int j = bid >> 3;            // 0..191
    const int n0 = (j >> 5) << 7;      // 6 n-panels
    const int m0 = (j & 31) << 7;      // 32 m-slots
    const int Ce = counts[e];
    if (Ce == 0 || m0 >= Ce) return;
    const int base = offsets[e];
    __shared__ __align__(16) u16 As[4096];
    __shared__ __align__(16) u16 Bs[4096];
    const int tid = threadIdx.x, l = tid & 63, w = tid >> 6;
    const int wm = w & 1, wn = w >> 1;
    const int sr = l >> 2, sc = (l & 3) << 3;
    const u16* Ae = Hb + (size_t)base * IEXP;
    int r0 = min(m0 + w * 32 + sr, Ce - 1);
    int r1 = min(m0 + w * 32 + 16 + sr, Ce - 1);
    const u16* gA0 = Ae + (size_t)r0 * IEXP + sc;
    const u16* gA1 = Ae + (size_t)r1 * IEXP + sc;
    const u16* Wde = Wd + (size_t)e * HID * IEXP;
    const u16* gB0 = Wde + (size_t)(n0 + w * 32 + sr) * IEXP + sc;
    const u16* gB1 = gB0 + 16 * IEXP;
    u16* lA0 = As + w * 1024; u16* lA1 = lA0 + 512;
    u16* lB0 = Bs + w * 1024; u16* lB1 = lB0 + 512;
    const int fr = l & 15, fc = (l >> 4) << 3;
    f32x4 acc[4][4];
#pragma unroll
    for (int i = 0; i < 4; ++i)
#pragma unroll
        for (int jj = 0; jj < 4; ++jj) acc[i][jj] = (f32x4){0.f, 0.f, 0.f, 0.f};
    for (int k0 = 0; k0 < IEXP; k0 += 32) {
        gload16(gA0 + k0, lA0);
        gload16(gA1 + k0, lA1);
        gload16(gB0 + k0, lB0);
        gload16(gB1 + k0, lB1);
        __syncthreads();
        bf16x8 af[4], bfv[4];
#pragma unroll
        for (int i = 0; i < 4; ++i) {
            af[i]  = *(const bf16x8*)(As + (wm * 64 + i * 16 + fr) * 32 + fc);
            bfv[i] = *(const bf16x8*)(Bs + (wn * 64 + i * 16 + fr) * 32 + fc);
        }
#pragma unroll
        for (int mf = 0; mf < 4; ++mf)
#pragma unroll
            for (int nf = 0; nf < 4; ++nf)
                acc[mf][nf] = __builtin_amdgcn_mfma_f32_16x16x32_bf16(
                    af[mf], bfv[nf], acc[mf][nf], 0, 0, 0);
        __syncthreads();
    }
    const int er = (l >> 4) << 2, ec = l & 15;
#pragma unroll
    for (int mf = 0; mf < 4; ++mf)
#pragma unroll
        for (int i = 0; i < 4; ++i) {
            int row = m0 + wm * 64 + mf * 16 + er + i;
            if (row >= Ce) continue;
            size_t sl = (size_t)(base + row);
            float sw = slot_w[sl];
#pragma unroll
            for (int nf = 0; nf < 4; ++nf) {
                int col = n0 + wn * 64 + nf * 16 + ec;
                D[sl * HID + col] = acc[mf][nf][i] * sw;
            }
        }
}

__global__ __launch_bounds__(256)
void moe_add(float* __restrict__ out, const float* __restrict__ D,
             const int* __restrict__ token_slot) {
    const int t = blockIdx.y;
    const int h = blockIdx.x * 256 + threadIdx.x;
    int s0 = token_slot[t * 2], s1 = token_slot[t * 2 + 1];
    out[(size_t)t * HID + h] += D[(size_t)s0 * HID + h] + D[(size_t)s1 * HID + h];
}

// ---------------------------------------------------------------------------
extern "C" void kernel_launch(void* const* d_in, const int* in_sizes, int n_in,
                              void* d_out, int out_size, void* d_ws, size_t ws_size,
                              hipStream_t stream) {
    const float* hidden = (const float*)d_in[0];
    const float* amask  = (const float*)d_in[1];
    const float* gmask  = (const float*)d_in[2];
    const int*   posids = (const int*)d_in[3];
    const float* ln1 = (const float*)d_in[4];
    const float* ln2 = (const float*)d_in[5];
    const float* ln3 = (const float*)d_in[6];
    const float* sqw = (const float*)d_in[7];  const float* sqb = (const float*)d_in[8];
    const float* skw = (const float*)d_in[9];  const float* skb = (const float*)d_in[10];
    const float* svw = (const float*)d_in[11]; const float* svb = (const float*)d_in[12];
    const float* sow = (const float*)d_in[13];
    const float* gqw = (const float*)d_in[14]; const float* gqb = (const float*)d_in[15];
    const float* gkw = (const float*)d_in[16]; const float* gkb = (const float*)d_in[17];
    const float* gvw = (const float*)d_in[18]; const float* gvb = (const float*)d_in[19];
    const float* gow = (const float*)d_in[20];
    const float* gatew = (const float*)d_in[21];
    const float* wg = (const float*)d_in[22];
    const float* wu = (const float*)d_in[23];
    const float* wd = (const float*)d_in[24];
    float* out = (float*)d_out;
    (void)amask;

    // ---- workspace carve (byte offsets), ~115.5 MB ----
    char* base = (char*)d_ws;
    float* xb     = (float*)(base + 0);
    float* qb     = (float*)(base + 12582912);
    float* kbuf   = (float*)(base + 25165824);
    float* vbuf   = (float*)(base + 29360128);
    float* ab     = (float*)(base + 33554432);
    u16* wqkv_sh  = (u16*)(base + 46137344);
    u16* wqkv_sl  = (u16*)(base + 48103424);
    u16* wo_sh    = (u16*)(base + 50069504);
    u16* wo_sl    = (u16*)(base + 51249152);
    u16* wqkv_gh  = (u16*)(base + 52428800);
    u16* wqkv_gl  = (u16*)(base + 54394880);
    u16* wo_gh    = (u16*)(base + 56360960);
    u16* wo_gl    = (u16*)(base + 57540608);
    u16* wgt      = (u16*)(base + 58720256);
    u16* wut      = (u16*)(base + 77594624);
    u16* wdt      = (u16*)(base + 96468992);
    float* slotw  = (float*)(base + 115343360);
    float* topw   = (float*)(base + 115376128);
    int* counts   = (int*)(base + 115408896);
    int* offsets  = (int*)(base + 115409024);
    int* topi     = (int*)(base + 115409408);
    int* posb     = (int*)(base + 115442176);
    int* slot_token = (int*)(base + 115474944);
    int* token_slot = (int*)(base + 115507712);
    // MoE-phase overlays (attention activations + attn weights dead by then):
    u16*   Hbuf  = (u16*)  (base + 12582912);   // 25,165,824 B
    float* Dbuf  = (float*)(base + 37748736);   // 25,165,824 B (clobbers attn W + wgt head; both done)

    // ---- weight prep ----
    cvt_split<<<576, 256, 0, stream>>>(sqw, wqkv_sh, wqkv_sl, 589824);
    cvt_split<<<192, 256, 0, stream>>>(skw, wqkv_sh + 589824, wqkv_sl + 589824, 196608);
    cvt_split<<<192, 256, 0, stream>>>(svw, wqkv_sh + 786432, wqkv_sl + 786432, 196608);
    cvt_split<<<576, 256, 0, stream>>>(sow, wo_sh, wo_sl, 589824);
    cvt_split<<<576, 256, 0, stream>>>(gqw, wqkv_gh, wqkv_gl, 589824);
    cvt_split<<<192, 256, 0, stream>>>(gkw, wqkv_gh + 589824, wqkv_gl + 589824, 196608);
    cvt_split<<<192, 256, 0, stream>>>(gvw, wqkv_gh + 786432, wqkv_gl + 786432, 196608);
    cvt_split<<<576, 256, 0, stream>>>(gow, wo_gh, wo_gl, 589824);
    transpose_cvt<<<dim3(48, 24, 8), dim3(32, 8), 0, stream>>>(wg, wgt, HID, IEXP);
    transpose_cvt<<<dim3(48, 24, 8), dim3(32, 8), 0, stream>>>(wu, wut, HID, IEXP);
    transpose_cvt<<<dim3(24, 48, 8), dim3(32, 8), 0, stream>>>(wd, wdt, IEXP, HID);

    // ---- self attention ----
    rmsnorm_kernel<<<NTOK, 256, 0, stream>>>(hidden, ln1, xb);
    qkv_split<<<dim3(10, 32), 256, 0, stream>>>(xb, wqkv_sh, wqkv_sl,
                                                sqb, skb, svb, qb, kbuf, vbuf);
    rope_kernel<<<NTOK, 256, 0, stream>>>(qb, kbuf, posids);
    attn_self_mfma<<<dim3(SEQ / 32, NHEAD, BATCH), 256, 0, stream>>>(qb, kbuf, vbuf, ab);
    oproj_split<<<dim3(6, 32), 256, 0, stream>>>(ab, wo_sh, wo_sl, hidden, out,
                                                 NTOK, HID, HID);

    // ---- group attention ----
    rmsnorm_kernel<<<NTOK, 256, 0, stream>>>(out, ln2, xb);
    qkv_split<<<dim3(10, 32), 256, 0, stream>>>(xb, wqkv_gh, wqkv_gl,
                                                gqb, gkb, gvb, qb, kbuf, vbuf);
    attn_group<<<SEQ * NHEAD, 64, 0, stream>>>(qb, kbuf, vbuf, gmask, ab);
    oproj_split<<<dim3(6, 32), 256, 0, stream>>>(ab, wo_gh, wo_gl, out, out,
                                                 NTOK, HID, HID);

    // ---- MoE (bf16 MFMA: post-router, flip-free; XCD-aware scheduling) ----
    rmsnorm_kernel<<<NTOK, 256, 0, stream>>>(out, ln3, xb);
    hipMemsetAsync(counts, 0, 8 * sizeof(int), stream);
    router_kernel<<<NTOK, 64, 0, stream>>>(xb, gatew, counts, topi, topw, posb);
    scan_kernel<<<1, 1, 0, stream>>>(counts, offsets);
    fill_slots<<<16, 256, 0, stream>>>(topi, topw, posb, offsets,
                                       slot_token, slotw, token_slot);
    moe_gate_up<<<3072, 256, 0, stream>>>(
        xb, wgt, wut, slot_token, counts, offsets, Hbuf);
    moe_down_bf16<<<1536, 256, 0, stream>>>(
        Hbuf, wdt, slotw, counts, offsets, Dbuf);
    moe_add<<<dim3(3, NTOK), 256, 0, stream>>>(out, Dbuf, token_slot);
}

// Round 9
// 614.118 us; speedup vs baseline: 1.4198x; 1.1275x over previous
//
#include <hip/hip_runtime.h>
#include <math.h>

// Problem constants
#define BATCH 8
#define SEQ 512
#define HID 768
#define NHEAD 12
#define KVHEAD 4
#define HDIM 64
#define NEXP 8
#define TOPK 2
#define IEXP 1536
#define NTOK (BATCH * SEQ)     // 4096
#define NSLOT (NTOK * TOPK)    // 8192
#define REP (NHEAD / KVHEAD)   // 3

typedef unsigned short u16;
typedef float f32x4 __attribute__((ext_vector_type(4)));
typedef __bf16 bf16x8 __attribute__((ext_vector_type(8)));
typedef unsigned short u16x8 __attribute__((ext_vector_type(8)));

__device__ __forceinline__ u16 f2bf(float f) {
    unsigned u = __float_as_uint(f);
    u += 0x7fffu + ((u >> 16) & 1u);   // RNE
    return (u16)(u >> 16);
}
__device__ __forceinline__ float bf2f(u16 h) {
    return __uint_as_float(((unsigned)h) << 16);
}

__device__ __forceinline__ void gload16(const void* g, void* l) {
    __builtin_amdgcn_global_load_lds(
        (const __attribute__((address_space(1))) void*)g,
        (__attribute__((address_space(3))) void*)l, 16, 0, 0);
}

// split 8 fp32 -> hi/lo bf16
__device__ __forceinline__ void cvt8(float4 a, float4 b, u16x8& hi, u16x8& lo) {
    float x[8] = {a.x, a.y, a.z, a.w, b.x, b.y, b.z, b.w};
#pragma unroll
    for (int i = 0; i < 8; ++i) {
        u16 h = f2bf(x[i]);
        hi[i] = h;
        lo[i] = f2bf(x[i] - bf2f(h));
    }
}

// swizzled element offset in a row-major [R][64] bf16 LDS tile (stride 128B):
// XOR the 16B-chunk index with (row&7) -> 2-way max bank aliasing (free).
#define SW(row, col) (((row) << 6) + ((col) ^ (((row) & 7) << 3)))

// ---------------------------------------------------------------------------
// fp32 -> bf16 hi/lo split convert (weights)
// ---------------------------------------------------------------------------
__global__ __launch_bounds__(256)
void cvt_split(const float* __restrict__ x, u16* __restrict__ yh,
               u16* __restrict__ yl, int n) {
    int i = (blockIdx.x * 256 + threadIdx.x) * 4;
    if (i >= n) return;
    float4 v = *(const float4*)(x + i);
    float a[4] = {v.x, v.y, v.z, v.w};
    ushort4 h, lo;
    u16 t;
    t = f2bf(a[0]); h.x = t; lo.x = f2bf(a[0] - bf2f(t));
    t = f2bf(a[1]); h.y = t; lo.y = f2bf(a[1] - bf2f(t));
    t = f2bf(a[2]); h.z = t; lo.z = f2bf(a[2] - bf2f(t));
    t = f2bf(a[3]); h.w = t; lo.w = f2bf(a[3] - bf2f(t));
    *(ushort4*)(yh + i) = h;
    *(ushort4*)(yl + i) = lo;
}

// ---------------------------------------------------------------------------
// per-expert transpose + convert: src[e][R][C] fp32 -> dst[e][C][R] bf16
// ---------------------------------------------------------------------------
__global__ __launch_bounds__(256)
void transpose_cvt(const float* __restrict__ src, u16* __restrict__ dst,
                   int R, int C) {
    const int e = blockIdx.z;
    src += (size_t)e * R * C;
    dst += (size_t)e * R * C;
    __shared__ float t[32][33];
    const int c0 = blockIdx.x << 5, r0 = blockIdx.y << 5;
    const int tx = threadIdx.x, ty = threadIdx.y;
#pragma unroll
    for (int i = 0; i < 4; ++i)
        t[ty * 4 + i][tx] = src[(size_t)(r0 + ty * 4 + i) * C + c0 + tx];
    __syncthreads();
#pragma unroll
    for (int i = 0; i < 4; ++i)
        dst[(size_t)(c0 + ty * 4 + i) * R + r0 + tx] = f2bf(t[tx][ty * 4 + i]);
}

// ---------------------------------------------------------------------------
// RMSNorm: one block per token. fp32 out; optional bf16 copy (MoE A-side)
// ---------------------------------------------------------------------------
__global__ __launch_bounds__(256)
void rmsnorm_kernel(const float* __restrict__ X, const float* __restrict__ W,
                    float* __restrict__ Y, u16* __restrict__ Ybf) {
    const int t = blockIdx.x;
    const int tid = threadIdx.x;
    const float* x = X + (size_t)t * HID;
    float x0 = x[tid], x1 = x[tid + 256], x2 = x[tid + 512];
    float ss = x0 * x0 + x1 * x1 + x2 * x2;
    for (int m = 1; m < 64; m <<= 1) ss += __shfl_xor(ss, m);
    __shared__ float red[4];
    if ((tid & 63) == 0) red[tid >> 6] = ss;
    __syncthreads();
    float tot = red[0] + red[1] + red[2] + red[3];
    float inv = rsqrtf(tot * (1.0f / HID) + 1e-6f);
    float r0 = x0 * inv * W[tid];
    float r1 = x1 * inv * W[tid + 256];
    float r2 = x2 * inv * W[tid + 512];
    float* y = Y + (size_t)t * HID;
    y[tid] = r0; y[tid + 256] = r1; y[tid + 512] = r2;
    if (Ybf) {
        u16* yb = Ybf + (size_t)t * HID;
        yb[tid] = f2bf(r0); yb[tid + 256] = f2bf(r1); yb[tid + 512] = f2bf(r2);
    }
}

// ---------------------------------------------------------------------------
// Split-precision MFMA NT GEMM for QKV. A fp32 (hi/lo in-kernel),
// Wh/Wl bf16 [1280][768]. 128x128 tile, BK=32. Grid (10, 32).
// ---------------------------------------------------------------------------
__global__ __launch_bounds__(256)
void qkv_split(const float* __restrict__ X, const u16* __restrict__ Wh,
               const u16* __restrict__ Wl,
               const float* __restrict__ bq, const float* __restrict__ bk,
               const float* __restrict__ bv,
               float* __restrict__ Qo, float* __restrict__ Ko,
               float* __restrict__ Vo) {
    __shared__ __align__(16) u16 Ah[4096], Al[4096], Bh[4096], Bl[4096];
    const int tid = threadIdx.x, l = tid & 63, w = tid >> 6;
    const int wm = w & 1, wn = w >> 1;
    const int m0 = blockIdx.y << 7, n0 = blockIdx.x << 7;
    const int sr = l >> 2, sc8 = (l & 3) << 3;
    const float* gA0 = X + (size_t)(m0 + w * 32 + sr) * HID + sc8;
    const float* gA1 = gA0 + 16 * HID;
    const u16* gBh0 = Wh + (size_t)(n0 + w * 32 + sr) * HID + sc8;
    const u16* gBh1 = gBh0 + 16 * HID;
    const u16* gBl0 = Wl + (size_t)(n0 + w * 32 + sr) * HID + sc8;
    const u16* gBl1 = gBl0 + 16 * HID;
    const int aoff0 = (w * 32 + sr) * 32 + sc8, aoff1 = aoff0 + 512;
    u16* lBh0 = Bh + w * 1024; u16* lBh1 = lBh0 + 512;
    u16* lBl0 = Bl + w * 1024; u16* lBl1 = lBl0 + 512;
    const int fr = l & 15, fc = (l >> 4) << 3;
    f32x4 acc[4][4];
#pragma unroll
    for (int i = 0; i < 4; ++i)
#pragma unroll
        for (int j = 0; j < 4; ++j) acc[i][j] = (f32x4){0.f, 0.f, 0.f, 0.f};
    for (int k0 = 0; k0 < HID; k0 += 32) {
        float4 a00 = *(const float4*)(gA0 + k0);
        float4 a01 = *(const float4*)(gA0 + k0 + 4);
        float4 a10 = *(const float4*)(gA1 + k0);
        float4 a11 = *(const float4*)(gA1 + k0 + 4);
        gload16(gBh0 + k0, lBh0);
        gload16(gBh1 + k0, lBh1);
        gload16(gBl0 + k0, lBl0);
        gload16(gBl1 + k0, lBl1);
        u16x8 h0, l0v, h1, l1v;
        cvt8(a00, a01, h0, l0v);
        cvt8(a10, a11, h1, l1v);
        *(u16x8*)(Ah + aoff0) = h0; *(u16x8*)(Al + aoff0) = l0v;
        *(u16x8*)(Ah + aoff1) = h1; *(u16x8*)(Al + aoff1) = l1v;
        __syncthreads();
        bf16x8 ah[4], al[4], bh[4], bl[4];
#pragma unroll
        for (int i = 0; i < 4; ++i) {
            ah[i] = *(const bf16x8*)(Ah + (wm * 64 + i * 16 + fr) * 32 + fc);
            al[i] = *(const bf16x8*)(Al + (wm * 64 + i * 16 + fr) * 32 + fc);
            bh[i] = *(const bf16x8*)(Bh + (wn * 64 + i * 16 + fr) * 32 + fc);
            bl[i] = *(const bf16x8*)(Bl + (wn * 64 + i * 16 + fr) * 32 + fc);
        }
#pragma unroll
        for (int mf = 0; mf < 4; ++mf)
#pragma unroll
            for (int nf = 0; nf < 4; ++nf) {
                acc[mf][nf] = __builtin_amdgcn_mfma_f32_16x16x32_bf16(
                    ah[mf], bh[nf], acc[mf][nf], 0, 0, 0);
                acc[mf][nf] = __builtin_amdgcn_mfma_f32_16x16x32_bf16(
                    al[mf], bh[nf], acc[mf][nf], 0, 0, 0);
                acc[mf][nf] = __builtin_amdgcn_mfma_f32_16x16x32_bf16(
                    ah[mf], bl[nf], acc[mf][nf], 0, 0, 0);
            }
        __syncthreads();
    }
    float* outp; const float* bp; int ldc, nl;
    if (n0 < 768)       { outp = Qo; bp = bq; ldc = 768; nl = n0; }
    else if (n0 < 1024) { outp = Ko; bp = bk; ldc = 256; nl = n0 - 768; }
    else                { outp = Vo; bp = bv; ldc = 256; nl = n0 - 1024; }
    const int er = (l >> 4) << 2, ec = l & 15;
#pragma unroll
    for (int mf = 0; mf < 4; ++mf)
#pragma unroll
        for (int i = 0; i < 4; ++i) {
            int row = m0 + wm * 64 + mf * 16 + er + i;
#pragma unroll
            for (int nf = 0; nf < 4; ++nf) {
                int col = nl + wn * 64 + nf * 16 + ec;
                outp[(size_t)row * ldc + col] = acc[mf][nf][i] + bp[col];
            }
        }
}

// ---------------------------------------------------------------------------
// Split-precision MFMA NT GEMM with residual: C = A@W^T + resid.
// ---------------------------------------------------------------------------
__global__ __launch_bounds__(256)
void oproj_split(const float* __restrict__ A, const u16* __restrict__ Wh,
                 const u16* __restrict__ Wl, const float* __restrict__ resid,
                 float* __restrict__ C, int M, int N, int K) {
    __shared__ __align__(16) u16 Ah[4096], Al[4096], Bh[4096], Bl[4096];
    const int tid = threadIdx.x, l = tid & 63, w = tid >> 6;
    const int wm = w & 1, wn = w >> 1;
    const int m0 = blockIdx.y << 7, n0 = blockIdx.x << 7;
    const int sr = l >> 2, sc8 = (l & 3) << 3;
    const float* gA0 = A + (size_t)(m0 + w * 32 + sr) * K + sc8;
    const float* gA1 = gA0 + (size_t)16 * K;
    const u16* gBh0 = Wh + (size_t)(n0 + w * 32 + sr) * K + sc8;
    const u16* gBh1 = gBh0 + (size_t)16 * K;
    const u16* gBl0 = Wl + (size_t)(n0 + w * 32 + sr) * K + sc8;
    const u16* gBl1 = gBl0 + (size_t)16 * K;
    const int aoff0 = (w * 32 + sr) * 32 + sc8, aoff1 = aoff0 + 512;
    u16* lBh0 = Bh + w * 1024; u16* lBh1 = lBh0 + 512;
    u16* lBl0 = Bl + w * 1024; u16* lBl1 = lBl0 + 512;
    const int fr = l & 15, fc = (l >> 4) << 3;
    f32x4 acc[4][4];
#pragma unroll
    for (int i = 0; i < 4; ++i)
#pragma unroll
        for (int j = 0; j < 4; ++j) acc[i][j] = (f32x4){0.f, 0.f, 0.f, 0.f};
    for (int k0 = 0; k0 < K; k0 += 32) {
        float4 a00 = *(const float4*)(gA0 + k0);
        float4 a01 = *(const float4*)(gA0 + k0 + 4);
        float4 a10 = *(const float4*)(gA1 + k0);
        float4 a11 = *(const float4*)(gA1 + k0 + 4);
        gload16(gBh0 + k0, lBh0);
        gload16(gBh1 + k0, lBh1);
        gload16(gBl0 + k0, lBl0);
        gload16(gBl1 + k0, lBl1);
        u16x8 h0, l0v, h1, l1v;
        cvt8(a00, a01, h0, l0v);
        cvt8(a10, a11, h1, l1v);
        *(u16x8*)(Ah + aoff0) = h0; *(u16x8*)(Al + aoff0) = l0v;
        *(u16x8*)(Ah + aoff1) = h1; *(u16x8*)(Al + aoff1) = l1v;
        __syncthreads();
        bf16x8 ah[4], al[4], bh[4], bl[4];
#pragma unroll
        for (int i = 0; i < 4; ++i) {
            ah[i] = *(const bf16x8*)(Ah + (wm * 64 + i * 16 + fr) * 32 + fc);
            al[i] = *(const bf16x8*)(Al + (wm * 64 + i * 16 + fr) * 32 + fc);
            bh[i] = *(const bf16x8*)(Bh + (wn * 64 + i * 16 + fr) * 32 + fc);
            bl[i] = *(const bf16x8*)(Bl + (wn * 64 + i * 16 + fr) * 32 + fc);
        }
#pragma unroll
        for (int mf = 0; mf < 4; ++mf)
#pragma unroll
            for (int nf = 0; nf < 4; ++nf) {
                acc[mf][nf] = __builtin_amdgcn_mfma_f32_16x16x32_bf16(
                    ah[mf], bh[nf], acc[mf][nf], 0, 0, 0);
                acc[mf][nf] = __builtin_amdgcn_mfma_f32_16x16x32_bf16(
                    al[mf], bh[nf], acc[mf][nf], 0, 0, 0);
                acc[mf][nf] = __builtin_amdgcn_mfma_f32_16x16x32_bf16(
                    ah[mf], bl[nf], acc[mf][nf], 0, 0, 0);
            }
        __syncthreads();
    }
    const int er = (l >> 4) << 2, ec = l & 15;
#pragma unroll
    for (int mf = 0; mf < 4; ++mf)
#pragma unroll
        for (int i = 0; i < 4; ++i) {
            int row = m0 + wm * 64 + mf * 16 + er + i;
#pragma unroll
            for (int nf = 0; nf < 4; ++nf) {
                int col = n0 + wn * 64 + nf * 16 + ec;
                C[(size_t)row * N + col] =
                    acc[mf][nf][i] + resid[(size_t)row * N + col];
            }
        }
}

// ---------------------------------------------------------------------------
// RoPE in-place on q (12 heads) and k (4 heads) per token
// ---------------------------------------------------------------------------
__global__ __launch_bounds__(256)
void rope_kernel(float* __restrict__ Q, float* __restrict__ Kb,
                 const int* __restrict__ pos_ids) {
    const int t = blockIdx.x;
    const float pos = (float)pos_ids[t];
    const int tid = threadIdx.x;
#pragma unroll
    for (int it = 0; it < 2; ++it) {
        int p = tid + (it << 8);
        int head = p >> 5, i = p & 31;
        float invf = expf(-(float)i * 0.28782313662425572f); // ln(1e4)/32
        float ang = pos * invf;
        float c = cosf(ang), sn = sinf(ang);
        float* base = (head < NHEAD)
            ? (Q + (size_t)t * HID + head * HDIM)
            : (Kb + (size_t)t * (KVHEAD * HDIM) + (head - NHEAD) * HDIM);
        float x1 = base[i], x2 = base[i + 32];
        base[i]      = x1 * c - x2 * sn;
        base[i + 32] = x2 * c + x1 * sn;
    }
}

// ---------------------------------------------------------------------------
// Self attention (causal GQA) via split-precision MFMA, online softmax.
// Block: 256 thr (4 waves) = 32 queries. Tiles of 64 keys.
// ---------------------------------------------------------------------------
__global__ __launch_bounds__(256)
void attn_self_mfma(const float* __restrict__ Q, const float* __restrict__ K,
                    const float* __restrict__ V, float* __restrict__ O) {
    const int qt = blockIdx.x, n = blockIdx.y, b = blockIdx.z;
    const int kv = n / REP;
    const int tid = threadIdx.x, l = tid & 63, w = tid >> 6;
    const int q0 = qt << 5;
    __shared__ __align__(16) u16 Qh[2048], Ql[2048];    // [32][64]
    __shared__ __align__(16) u16 Kh[4096], Kl[4096];    // [64][64]
    __shared__ __align__(16) u16 Vh[4096], Vl[4096];    // transposed [d][key]
    __shared__ float Ps[32][68];
    __shared__ float scal[32];

    // ---- stage Q (hi/lo, swizzled) ----
    {
        int row = tid >> 3, cg = (tid & 7) << 3;
        const float* qg = Q + (size_t)(b * SEQ + q0 + row) * HID + n * HDIM + cg;
        float4 v0 = *(const float4*)qg;
        float4 v1 = *(const float4*)(qg + 4);
        u16x8 h, lo;
        cvt8(v0, v1, h, lo);
        *(u16x8*)(Qh + SW(row, cg)) = h;
        *(u16x8*)(Ql + SW(row, cg)) = lo;
    }
    __syncthreads();

    const int fr = l & 15, fcg = (l >> 4) << 3;
    const int qf16 = (w & 1) << 4;
    const int fp2 = (w >> 1) << 1;      // frag pair base (k or d)
    bf16x8 qfh[2], qfl[2];
#pragma unroll
    for (int dc = 0; dc < 2; ++dc) {
        int off = SW(qf16 + fr, dc * 32 + fcg);
        qfh[dc] = *(const bf16x8*)(Qh + off);
        qfl[dc] = *(const bf16x8*)(Ql + off);
    }

    f32x4 o[2];
    o[0] = (f32x4){0.f, 0.f, 0.f, 0.f};
    o[1] = (f32x4){0.f, 0.f, 0.f, 0.f};
    float m_run = -3.4e38f, l_run = 0.f;
    const int sq = tid >> 3;
    const int skb = (tid & 7) << 3;
    const float scale = 0.125f;
    const int nt = (qt >> 1) + 1;

    for (int t = 0; t < nt; ++t) {
        __syncthreads();
        // ---- stage K tile (hi/lo, swizzled) ----
        {
            int row = tid >> 2, cg = (tid & 3) << 4;
            const float* kg = K + (size_t)(b * SEQ + (t << 6) + row)
                              * (KVHEAD * HDIM) + kv * HDIM + cg;
            float4 k0 = *(const float4*)kg;
            float4 k1 = *(const float4*)(kg + 4);
            float4 k2 = *(const float4*)(kg + 8);
            float4 k3 = *(const float4*)(kg + 12);
            u16x8 h0, l0v, h1, l1v;
            cvt8(k0, k1, h0, l0v);
            cvt8(k2, k3, h1, l1v);
            *(u16x8*)(Kh + SW(row, cg)) = h0;
            *(u16x8*)(Kh + SW(row, cg + 8)) = h1;
            *(u16x8*)(Kl + SW(row, cg)) = l0v;
            *(u16x8*)(Kl + SW(row, cg + 8)) = l1v;
        }
        // ---- stage V tile transposed [d][key] (hi/lo, swizzled) ----
        {
            int kp = (tid & 31) << 1, dc = (tid >> 5) << 3;
            const float* vg0 = V + (size_t)(b * SEQ + (t << 6) + kp)
                               * (KVHEAD * HDIM) + kv * HDIM + dc;
            const float* vg1 = vg0 + KVHEAD * HDIM;
            float4 a0 = *(const float4*)vg0;
            float4 a1 = *(const float4*)(vg0 + 4);
            float4 b0 = *(const float4*)vg1;
            float4 b1 = *(const float4*)(vg1 + 4);
            float va[8] = {a0.x, a0.y, a0.z, a0.w, a1.x, a1.y, a1.z, a1.w};
            float vb[8] = {b0.x, b0.y, b0.z, b0.w, b1.x, b1.y, b1.z, b1.w};
#pragma unroll
            for (int j = 0; j < 8; ++j) {
                u16 h0 = f2bf(va[j]);
                u16 h1 = f2bf(vb[j]);
                u16 p0 = f2bf(va[j] - bf2f(h0));
                u16 p1 = f2bf(vb[j] - bf2f(h1));
                int off = SW(dc + j, kp);
                *(unsigned*)(Vh + off) = (unsigned)h0 | ((unsigned)h1 << 16);
                *(unsigned*)(Vl + off) = (unsigned)p0 | ((unsigned)p1 << 16);
            }
        }
        __syncthreads();
        // ---- S = Q K^T (split MFMA) ----
#pragma unroll
        for (int kk = 0; kk < 2; ++kk) {
            int kf = fp2 + kk;
            bf16x8 kh[2], klv[2];
#pragma unroll
            for (int dc = 0; dc < 2; ++dc) {
                int off = SW(kf * 16 + fr, dc * 32 + fcg);
                kh[dc]  = *(const bf16x8*)(Kh + off);
                klv[dc] = *(const bf16x8*)(Kl + off);
            }
            f32x4 s = (f32x4){0.f, 0.f, 0.f, 0.f};
            s = __builtin_amdgcn_mfma_f32_16x16x32_bf16(qfh[0], kh[0], s, 0, 0, 0);
            s = __builtin_amdgcn_mfma_f32_16x16x32_bf16(qfh[1], kh[1], s, 0, 0, 0);
            s = __builtin_amdgcn_mfma_f32_16x16x32_bf16(qfl[0], kh[0], s, 0, 0, 0);
            s = __builtin_amdgcn_mfma_f32_16x16x32_bf16(qfl[1], kh[1], s, 0, 0, 0);
            s = __builtin_amdgcn_mfma_f32_16x16x32_bf16(qfh[0], klv[0], s, 0, 0, 0);
            s = __builtin_amdgcn_mfma_f32_16x16x32_bf16(qfh[1], klv[1], s, 0, 0, 0);
            int col = kf * 16 + fr;
            int key = (t << 6) + col;
#pragma unroll
            for (int r = 0; r < 4; ++r) {
                int qrow = qf16 + ((l >> 4) << 2) + r;
                Ps[qrow][col] = (key <= q0 + qrow) ? s[r] * scale : -1e9f;
            }
        }
        __syncthreads();
        // ---- online softmax update (8 threads per query) ----
        {
            float4 s0 = *(const float4*)&Ps[sq][skb];
            float4 s1 = *(const float4*)&Ps[sq][skb + 4];
            float sv[8] = {s0.x, s0.y, s0.z, s0.w, s1.x, s1.y, s1.z, s1.w};
            float mx = sv[0];
#pragma unroll
            for (int j = 1; j < 8; ++j) mx = fmaxf(mx, sv[j]);
            for (int x = 1; x < 8; x <<= 1) mx = fmaxf(mx, __shfl_xor(mx, x));
            float mnew = fmaxf(m_run, mx);
            float corr = __expf(m_run - mnew);
            float lsum = 0.f;
#pragma unroll
            for (int j = 0; j < 8; ++j) {
                sv[j] = __expf(sv[j] - mnew);
                lsum += sv[j];
            }
            for (int x = 1; x < 8; x <<= 1) lsum += __shfl_xor(lsum, x);
            l_run = l_run * corr + lsum;
            m_run = mnew;
            *(float4*)&Ps[sq][skb]     = make_float4(sv[0], sv[1], sv[2], sv[3]);
            *(float4*)&Ps[sq][skb + 4] = make_float4(sv[4], sv[5], sv[6], sv[7]);
            if ((tid & 7) == 0) scal[sq] = corr;
        }
        __syncthreads();
        // ---- rescale O, then O += P V (split MFMA) ----
        {
            float4 c4 = *(const float4*)&scal[qf16 + ((l >> 4) << 2)];
            float cr[4] = {c4.x, c4.y, c4.z, c4.w};
#pragma unroll
            for (int dfi = 0; dfi < 2; ++dfi)
#pragma unroll
                for (int r = 0; r < 4; ++r) o[dfi][r] *= cr[r];
            bf16x8 ph[2], pl[2];
#pragma unroll
            for (int kc = 0; kc < 2; ++kc) {
                float4 p0 = *(const float4*)&Ps[qf16 + fr][kc * 32 + fcg];
                float4 p1 = *(const float4*)&Ps[qf16 + fr][kc * 32 + fcg + 4];
                u16x8 hh, ll;
                cvt8(p0, p1, hh, ll);
                ph[kc] = *(bf16x8*)&hh;
                pl[kc] = *(bf16x8*)&ll;
            }
#pragma unroll
            for (int dfi = 0; dfi < 2; ++dfi) {
                int df = fp2 + dfi;
#pragma unroll
                for (int kc = 0; kc < 2; ++kc) {
                    int off = SW(df * 16 + fr, kc * 32 + fcg);
                    bf16x8 vh = *(const bf16x8*)(Vh + off);
                    bf16x8 vl = *(const bf16x8*)(Vl + off);
                    o[dfi] = __builtin_amdgcn_mfma_f32_16x16x32_bf16(
                        ph[kc], vh, o[dfi], 0, 0, 0);
                    o[dfi] = __builtin_amdgcn_mfma_f32_16x16x32_bf16(
                        pl[kc], vh, o[dfi], 0, 0, 0);
                    o[dfi] = __builtin_amdgcn_mfma_f32_16x16x32_bf16(
                        ph[kc], vl, o[dfi], 0, 0, 0);
                }
            }
        }
    }
    __syncthreads();
    if ((tid & 7) == 0) scal[sq] = 1.0f / l_run;
    __syncthreads();
    {
        int qrb = qf16 + ((l >> 4) << 2);
        float4 li4 = *(const float4*)&scal[qrb];
        float li[4] = {li4.x, li4.y, li4.z, li4.w};
#pragma unroll
        for (int dfi = 0; dfi < 2; ++dfi) {
            int df = fp2 + dfi;
            int col = n * HDIM + df * 16 + fr;
#pragma unroll
            for (int r = 0; r < 4; ++r) {
                int row = q0 + qrb + r;
                O[(size_t)(b * SEQ + row) * HID + col] = o[dfi][r] * li[r];
            }
        }
    }
}

// ---------------------------------------------------------------------------
// Group attention: MHA across the 8 channels. One wave per (s, head).
// ---------------------------------------------------------------------------
__global__ __launch_bounds__(64)
void attn_group(const float* __restrict__ Q, const float* __restrict__ K,
                const float* __restrict__ V, const float* __restrict__ gmask,
                float* __restrict__ O) {
    const int n = blockIdx.x % NHEAD;
    const int s = blockIdx.x / NHEAD;
    const int kv = n / REP;
    const int lane = threadIdx.x;
    __shared__ float Qs[8][65], Ks[8][65], Vs[8][65], Ps[64];
    for (int c = 0; c < 8; ++c) {
        Qs[c][lane] = Q[(size_t)(c * SEQ + s) * HID + n * HDIM + lane];
        Ks[c][lane] = K[(size_t)(c * SEQ + s) * (KVHEAD * HDIM) + kv * HDIM + lane];
        Vs[c][lane] = V[(size_t)(c * SEQ + s) * (KVHEAD * HDIM) + kv * HDIM + lane];
    }
    __syncthreads();
    const int qb = lane >> 3, kb = lane & 7;
    float sc = 0;
    for (int d = 0; d < 64; ++d) sc += Qs[qb][d] * Ks[kb][d];
    sc = sc * 0.125f + gmask[(size_t)s * 64 + qb * 8 + kb];
    float m = sc;
    for (int x = 1; x < 8; x <<= 1) m = fmaxf(m, __shfl_xor(m, x));
    float p = __expf(sc - m);
    float l = p;
    for (int x = 1; x < 8; x <<= 1) l += __shfl_xor(l, x);
    Ps[lane] = p / l;
    __syncthreads();
    for (int q2 = 0; q2 < 8; ++q2) {
        float o = 0;
        for (int c = 0; c < 8; ++c) o += Ps[q2 * 8 + c] * Vs[c][lane];
        O[(size_t)(q2 * SEQ + s) * HID + n * HDIM + lane] = o;
    }
}

// ---------------------------------------------------------------------------
// MoE router (fp32)
// ---------------------------------------------------------------------------
__global__ __launch_bounds__(64)
void router_kernel(const float* __restrict__ X, const float* __restrict__ GW,
                   int* __restrict__ counts, int* __restrict__ topi,
                   float* __restrict__ topw, int* __restrict__ posb) {
    const int t = blockIdx.x;
    const int lane = threadIdx.x;
    const int e = lane >> 3, c = lane & 7;
    const float4* x4 = (const float4*)(X + (size_t)t * HID + c * 96);
    const float4* g4 = (const float4*)(GW + (size_t)e * HID + c * 96);
    float p = 0;
#pragma unroll
    for (int i = 0; i < 24; ++i) {
        float4 xv = x4[i], gv = g4[i];
        p += xv.x * gv.x + xv.y * gv.y + xv.z * gv.z + xv.w * gv.w;
    }
    p += __shfl_xor(p, 1);
    p += __shfl_xor(p, 2);
    p += __shfl_xor(p, 4);
    float lg[8];
#pragma unroll
    for (int i = 0; i < 8; ++i) lg[i] = __shfl(p, i * 8);
    float m = lg[0];
#pragma unroll
    for (int i = 1; i < 8; ++i) m = fmaxf(m, lg[i]);
    float s = 0;
#pragma unroll
    for (int i = 0; i < 8; ++i) { lg[i] = expf(lg[i] - m); s += lg[i]; }
    float inv = 1.0f / s;
    int i1 = 0; float b1 = lg[0];
#pragma unroll
    for (int i = 1; i < 8; ++i) if (lg[i] > b1) { b1 = lg[i]; i1 = i; }
    int i2 = -1; float b2 = -1.0f;
#pragma unroll
    for (int i = 0; i < 8; ++i)
        if (i != i1 && lg[i] > b2) { b2 = lg[i]; i2 = i; }
    if (lane == 0) {
        topi[t * 2] = i1; topi[t * 2 + 1] = i2;
        topw[t * 2] = b1 * inv; topw[t * 2 + 1] = b2 * inv;
        posb[t * 2] = atomicAdd(&counts[i1], 1);
        posb[t * 2 + 1] = atomicAdd(&counts[i2], 1);
    }
}

__global__ void scan_kernel(const int* __restrict__ counts, int* __restrict__ offsets) {
    int acc = 0;
    for (int e = 0; e < NEXP; ++e) { offsets[e] = acc; acc += counts[e]; }
}

__global__ __launch_bounds__(256)
void fill_slots(const int* __restrict__ topi, const float* __restrict__ topw,
                const int* __restrict__ posb, const int* __restrict__ offsets,
                int* __restrict__ slot_token, float* __restrict__ slot_w,
                int* __restrict__ token_slot) {
    int t = blockIdx.x * 256 + threadIdx.x;
    if (t >= NTOK) return;
#pragma unroll
    for (int k = 0; k < TOPK; ++k) {
        int e = topi[t * 2 + k];
        int sl = offsets[e] + posb[t * 2 + k];
        slot_token[sl] = t;
        slot_w[sl] = topw[t * 2 + k];
        token_slot[t * 2 + k] = sl;
    }
}

// ---------------------------------------------------------------------------
// MoE gate+up grouped GEMM, single-bf16 A (post-router: flip-free).
// Xb bf16 [NTOK][HID] gathered via slot_token with global_load_lds.
// Wg/Wu bf16 [e][IEXP][HID]. H bf16 out. Grid (n=12, m=32, e=8) — R6's
// proven n-fastest order (best measured 185us; R7/R8 alternatives worse).
// ---------------------------------------------------------------------------
__global__ __launch_bounds__(256)
void moe_gate_up(const u16* __restrict__ Xb, const u16* __restrict__ Wg,
                 const u16* __restrict__ Wu,
                 const int* __restrict__ slot_token,
                 const int* __restrict__ counts,
                 const int* __restrict__ offsets, u16* __restrict__ H) {
    const int e = blockIdx.z;
    const int Ce = counts[e];
    const int m0 = blockIdx.y << 7;
    if (Ce == 0 || m0 >= Ce) return;
    const int n0 = blockIdx.x << 7;
    const int base = offsets[e];
    __shared__ __align__(16) u16 As[4096];
    __shared__ __align__(16) u16 Gs[4096];
    __shared__ __align__(16) u16 Us[4096];
    const int tid = threadIdx.x, l = tid & 63, w = tid >> 6;
    const int wm = w & 1, wn = w >> 1;
    const int sr = l >> 2, sc8 = (l & 3) << 3;
    int r0 = m0 + w * 32 + sr;
    int r1 = r0 + 16;
    int t0 = slot_token[base + min(r0, Ce - 1)];
    int t1 = slot_token[base + min(r1, Ce - 1)];
    const u16* gA0 = Xb + (size_t)t0 * HID + sc8;
    const u16* gA1 = Xb + (size_t)t1 * HID + sc8;
    const u16* Wge = Wg + (size_t)e * IEXP * HID;
    const u16* Wue = Wu + (size_t)e * IEXP * HID;
    const u16* gG0 = Wge + (size_t)(n0 + w * 32 + sr) * HID + sc8;
    const u16* gG1 = gG0 + 16 * HID;
    const u16* gU0 = Wue + (size_t)(n0 + w * 32 + sr) * HID + sc8;
    const u16* gU1 = gU0 + 16 * HID;
    u16* lA0 = As + w * 1024; u16* lA1 = lA0 + 512;
    u16* lG0 = Gs + w * 1024; u16* lG1 = lG0 + 512;
    u16* lU0 = Us + w * 1024; u16* lU1 = lU0 + 512;
    const int fr = l & 15, fc = (l >> 4) << 3;
    f32x4 accg[4][4], accu[4][4];
#pragma unroll
    for (int i = 0; i < 4; ++i)
#pragma unroll
        for (int j = 0; j < 4; ++j) {
            accg[i][j] = (f32x4){0.f, 0.f, 0.f, 0.f};
            accu[i][j] = (f32x4){0.f, 0.f, 0.f, 0.f};
        }
    for (int k0 = 0; k0 < HID; k0 += 32) {
        gload16(gA0 + k0, lA0);
        gload16(gA1 + k0, lA1);
        gload16(gG0 + k0, lG0);
        gload16(gG1 + k0, lG1);
        gload16(gU0 + k0, lU0);
        gload16(gU1 + k0, lU1);
        __syncthreads();
        bf16x8 af[4], gf[4], uf[4];
#pragma unroll
        for (int i = 0; i < 4; ++i) {
            af[i] = *(const bf16x8*)(As + (wm * 64 + i * 16 + fr) * 32 + fc);
            gf[i] = *(const bf16x8*)(Gs + (wn * 64 + i * 16 + fr) * 32 + fc);
            uf[i] = *(const bf16x8*)(Us + (wn * 64 + i * 16 + fr) * 32 + fc);
        }
#pragma unroll
        for (int mf = 0; mf < 4; ++mf)
#pragma unroll
            for (int nf = 0; nf < 4; ++nf) {
                accg[mf][nf] = __builtin_amdgcn_mfma_f32_16x16x32_bf16(
                    af[mf], gf[nf], accg[mf][nf], 0, 0, 0);
                accu[mf][nf] = __builtin_amdgcn_mfma_f32_16x16x32_bf16(
                    af[mf], uf[nf], accu[mf][nf], 0, 0, 0);
            }
        __syncthreads();
    }
    const int er = (l >> 4) << 2, ec = l & 15;
#pragma unroll
    for (int mf = 0; mf < 4; ++mf)
#pragma unroll
        for (int i = 0; i < 4; ++i) {
            int row = m0 + wm * 64 + mf * 16 + er + i;
            if (row >= Ce) continue;
            size_t sl = (size_t)(base + row);
#pragma unroll
            for (int nf = 0; nf < 4; ++nf) {
                int col = n0 + wn * 64 + nf * 16 + ec;
                float g = accg[mf][nf][i];
                float u = accu[mf][nf][i];
                float h = g / (1.0f + __expf(-g)) * u;
                H[sl * IEXP + col] = f2bf(h);
            }
        }
}

// ---------------------------------------------------------------------------
// MoE down grouped GEMM bf16: D[slot][HID] fp32 = slot_w * (H @ Wd^T)
// Wd pre-transposed to [e][HID][IEXP]. Grid (n=6, m=32, e=8) — R6 order.
// ---------------------------------------------------------------------------
__global__ __launch_bounds__(256)
void moe_down_bf16(const u16* __restrict__ Hb, const u16* __restrict__ Wd,
                   const float* __restrict__ slot_w,
                   const int* __restrict__ counts,
                   const int* __restrict__ offsets, float* __restrict__ D) {
    const int e = blockIdx.z;
    const int Ce = counts[e];
    const int m0 = blockIdx.y << 7;
    if (Ce == 0 || m0 >= Ce) return;
    const int n0 = blockIdx.x << 7;
    const int base = offsets[e];
    __shared__ __align__(16) u16 As[4096];
    __shared__ __align__(16) u16 Bs[4096];
    const int tid = threadIdx.x, l = tid & 63, w = tid >> 6;
    const int wm = w & 1, wn = w >> 1;
    const int sr = l >> 2, sc = (l & 3) << 3;
    const u16* Ae = Hb + (size_t)base * IEXP;
    int r0 = min(m0 + w * 32 + sr, Ce - 1);
    int r1 = min(m0 + w * 32 + 16 + sr, Ce - 1);
    const u16* gA0 = Ae + (size_t)r0 * IEXP + sc;
    const u16* gA1 = Ae + (size_t)r1 * IEXP + sc;
    const u16* Wde = Wd + (size_t)e * HID * IEXP;
    const u16* gB0 = Wde + (size_t)(n0 + w * 32 + sr) * IEXP + sc;
    const u16* gB1 = gB0 + 16 * IEXP;
    u16* lA0 = As + w * 1024; u16* lA1 = lA0 + 512;
    u16* lB0 = Bs + w * 1024; u16* lB1 = lB0 + 512;
    const int fr = l & 15, fc = (l >> 4) << 3;
    f32x4 acc[4][4];
#pragma unroll
    for (int i = 0; i < 4; ++i)
#pragma unroll
        for (int j = 0; j < 4; ++j) acc[i][j] = (f32x4){0.f, 0.f, 0.f, 0.f};
    for (int k0 = 0; k0 < IEXP; k0 += 32) {
        gload16(gA0 + k0, lA0);
        gload16(gA1 + k0, lA1);
        gload16(gB0 + k0, lB0);
        gload16(gB1 + k0, lB1);
        __syncthreads();
        bf16x8 af[4], bfv[4];
#pragma unroll
        for (int i = 0; i < 4; ++i) {
            af[i]  = *(const bf16x8*)(As + (wm * 64 + i * 16 + fr) * 32 + fc);
            bfv[i] = *(const bf16x8*)(Bs + (wn * 64 + i * 16 + fr) * 32 + fc);
        }
#pragma unroll
        for (int mf = 0; mf < 4; ++mf)
#pragma unroll
            for (int nf = 0; nf < 4; ++nf)
                acc[mf][nf] = __builtin_amdgcn_mfma_f32_16x16x32_bf16(
                    af[mf], bfv[nf], acc[mf][nf], 0, 0, 0);
        __syncthreads();
    }
    const int er = (l >> 4) << 2, ec = l & 15;
#pragma unroll
    for (int mf = 0; mf < 4; ++mf)
#pragma unroll
        for (int i = 0; i < 4; ++i) {
            int row = m0 + wm * 64 + mf * 16 + er + i;
            if (row >= Ce) continue;
            size_t sl = (size_t)(base + row);
            float sw = slot_w[sl];
#pragma unroll
            for (int nf = 0; nf < 4; ++nf) {
                int col = n0 + wn * 64 + nf * 16 + ec;
                D[sl * HID + col] = acc[mf][nf][i] * sw;
            }
        }
}

__global__ __launch_bounds__(256)
void moe_add(float* __restrict__ out, const float* __restrict__ D,
             const int* __restrict__ token_slot) {
    const int t = blockIdx.y;
    const int h = blockIdx.x * 256 + threadIdx.x;
    int s0 = token_slot[t * 2], s1 = token_slot[t * 2 + 1];
    out[(size_t)t * HID + h] += D[(size_t)s0 * HID + h] + D[(size_t)s1 * HID + h];
}

// ---------------------------------------------------------------------------
extern "C" void kernel_launch(void* const* d_in, const int* in_sizes, int n_in,
                              void* d_out, int out_size, void* d_ws, size_t ws_size,
                              hipStream_t stream) {
    const float* hidden = (const float*)d_in[0];
    const float* amask  = (const float*)d_in[1];
    const float* gmask  = (const float*)d_in[2];
    const int*   posids = (const int*)d_in[3];
    const float* ln1 = (const float*)d_in[4];
    const float* ln2 = (const float*)d_in[5];
    const float* ln3 = (const float*)d_in[6];
    const float* sqw = (const float*)d_in[7];  const float* sqb = (const float*)d_in[8];
    const float* skw = (const float*)d_in[9];  const float* skb = (const float*)d_in[10];
    const float* svw = (const float*)d_in[11]; const float* svb = (const float*)d_in[12];
    const float* sow = (const float*)d_in[13];
    const float* gqw = (const float*)d_in[14]; const float* gqb = (const float*)d_in[15];
    const float* gkw = (const float*)d_in[16]; const float* gkb = (const float*)d_in[17];
    const float* gvw = (const float*)d_in[18]; const float* gvb = (const float*)d_in[19];
    const float* gow = (const float*)d_in[20];
    const float* gatew = (const float*)d_in[21];
    const float* wg = (const float*)d_in[22];
    const float* wu = (const float*)d_in[23];
    const float* wd = (const float*)d_in[24];
    float* out = (float*)d_out;
    (void)amask;

    // ---- workspace carve (byte offsets), ~121.8 MB ----
    char* base = (char*)d_ws;
    float* xb     = (float*)(base + 0);
    float* qb     = (float*)(base + 12582912);
    float* kbuf   = (float*)(base + 25165824);
    float* vbuf   = (float*)(base + 29360128);
    float* ab     = (float*)(base + 33554432);
    u16* wqkv_sh  = (u16*)(base + 46137344);
    u16* wqkv_sl  = (u16*)(base + 48103424);
    u16* wo_sh    = (u16*)(base + 50069504);
    u16* wo_sl    = (u16*)(base + 51249152);
    u16* wqkv_gh  = (u16*)(base + 52428800);
    u16* wqkv_gl  = (u16*)(base + 54394880);
    u16* wo_gh    = (u16*)(base + 56360960);
    u16* wo_gl    = (u16*)(base + 57540608);
    u16* wgt      = (u16*)(base + 58720256);
    u16* wut      = (u16*)(base + 77594624);
    u16* wdt      = (u16*)(base + 96468992);
    float* slotw  = (float*)(base + 115343360);
    float* topw   = (float*)(base + 115376128);
    int* counts   = (int*)(base + 115408896);
    int* offsets  = (int*)(base + 115409024);
    int* topi     = (int*)(base + 115409408);
    int* posb     = (int*)(base + 115442176);
    int* slot_token = (int*)(base + 115474944);
    int* token_slot = (int*)(base + 115507712);
    u16* xbf      = (u16*)(base + 115540480);   // 6,291,456 -> 121,831,936
    // MoE-phase overlays (attention activations + attn weights dead by then):
    u16*   Hbuf  = (u16*)  (base + 12582912);   // 25,165,824 B
    float* Dbuf  = (float*)(base + 37748736);   // 25,165,824 B (clobbers attn W + wgt head; both done)

    // ---- weight prep ----
    cvt_split<<<576, 256, 0, stream>>>(sqw, wqkv_sh, wqkv_sl, 589824);
    cvt_split<<<192, 256, 0, stream>>>(skw, wqkv_sh + 589824, wqkv_sl + 589824, 196608);
    cvt_split<<<192, 256, 0, stream>>>(svw, wqkv_sh + 786432, wqkv_sl + 786432, 196608);
    cvt_split<<<576, 256, 0, stream>>>(sow, wo_sh, wo_sl, 589824);
    cvt_split<<<576, 256, 0, stream>>>(gqw, wqkv_gh, wqkv_gl, 589824);
    cvt_split<<<192, 256, 0, stream>>>(gkw, wqkv_gh + 589824, wqkv_gl + 589824, 196608);
    cvt_split<<<192, 256, 0, stream>>>(gvw, wqkv_gh + 786432, wqkv_gl + 786432, 196608);
    cvt_split<<<576, 256, 0, stream>>>(gow, wo_gh, wo_gl, 589824);
    transpose_cvt<<<dim3(48, 24, 8), dim3(32, 8), 0, stream>>>(wg, wgt, HID, IEXP);
    transpose_cvt<<<dim3(48, 24, 8), dim3(32, 8), 0, stream>>>(wu, wut, HID, IEXP);
    transpose_cvt<<<dim3(24, 48, 8), dim3(32, 8), 0, stream>>>(wd, wdt, IEXP, HID);

    // ---- self attention ----
    rmsnorm_kernel<<<NTOK, 256, 0, stream>>>(hidden, ln1, xb, nullptr);
    qkv_split<<<dim3(10, 32), 256, 0, stream>>>(xb, wqkv_sh, wqkv_sl,
                                                sqb, skb, svb, qb, kbuf, vbuf);
    rope_kernel<<<NTOK, 256, 0, stream>>>(qb, kbuf, posids);
    attn_self_mfma<<<dim3(SEQ / 32, NHEAD, BATCH), 256, 0, stream>>>(qb, kbuf, vbuf, ab);
    oproj_split<<<dim3(6, 32), 256, 0, stream>>>(ab, wo_sh, wo_sl, hidden, out,
                                                 NTOK, HID, HID);

    // ---- group attention ----
    rmsnorm_kernel<<<NTOK, 256, 0, stream>>>(out, ln2, xb, nullptr);
    qkv_split<<<dim3(10, 32), 256, 0, stream>>>(xb, wqkv_gh, wqkv_gl,
                                                gqb, gkb, gvb, qb, kbuf, vbuf);
    attn_group<<<SEQ * NHEAD, 64, 0, stream>>>(qb, kbuf, vbuf, gmask, ab);
    oproj_split<<<dim3(6, 32), 256, 0, stream>>>(ab, wo_gh, wo_gl, out, out,
                                                 NTOK, HID, HID);

    // ---- MoE (bf16 MFMA: post-router, flip-free; R6 grid order) ----
    rmsnorm_kernel<<<NTOK, 256, 0, stream>>>(out, ln3, xb, xbf);
    hipMemsetAsync(counts, 0, 8 * sizeof(int), stream);
    router_kernel<<<NTOK, 64, 0, stream>>>(xb, gatew, counts, topi, topw, posb);
    scan_kernel<<<1, 1, 0, stream>>>(counts, offsets);
    fill_slots<<<16, 256, 0, stream>>>(topi, topw, posb, offsets,
                                       slot_token, slotw, token_slot);
    moe_gate_up<<<dim3(12, 32, 8), 256, 0, stream>>>(
        xbf, wgt, wut, slot_token, counts, offsets, Hbuf);
    moe_down_bf16<<<dim3(6, 32, 8), 256, 0, stream>>>(
        Hbuf, wdt, slotw, counts, offsets, Dbuf);
    moe_add<<<dim3(3, NTOK), 256, 0, stream>>>(out, Dbuf, token_slot);
}

// Round 10
// 599.103 us; speedup vs baseline: 1.4554x; 1.0251x over previous
//
#include <hip/hip_runtime.h>
#include <math.h>

// Problem constants
#define BATCH 8
#define SEQ 512
#define HID 768
#define NHEAD 12
#define KVHEAD 4
#define HDIM 64
#define NEXP 8
#define TOPK 2
#define IEXP 1536
#define NTOK (BATCH * SEQ)     // 4096
#define NSLOT (NTOK * TOPK)    // 8192
#define REP (NHEAD / KVHEAD)   // 3
#define KVD (KVHEAD * HDIM)    // 256

typedef unsigned short u16;
typedef float f32x4 __attribute__((ext_vector_type(4)));
typedef __bf16 bf16x8 __attribute__((ext_vector_type(8)));
typedef unsigned short u16x8 __attribute__((ext_vector_type(8)));

__device__ __forceinline__ u16 f2bf(float f) {
    unsigned u = __float_as_uint(f);
    u += 0x7fffu + ((u >> 16) & 1u);   // RNE
    return (u16)(u >> 16);
}
__device__ __forceinline__ float bf2f(u16 h) {
    return __uint_as_float(((unsigned)h) << 16);
}

__device__ __forceinline__ void gload16(const void* g, void* l) {
    __builtin_amdgcn_global_load_lds(
        (const __attribute__((address_space(1))) void*)g,
        (__attribute__((address_space(3))) void*)l, 16, 0, 0);
}

// split 8 fp32 -> hi/lo bf16
__device__ __forceinline__ void cvt8(float4 a, float4 b, u16x8& hi, u16x8& lo) {
    float x[8] = {a.x, a.y, a.z, a.w, b.x, b.y, b.z, b.w};
#pragma unroll
    for (int i = 0; i < 8; ++i) {
        u16 h = f2bf(x[i]);
        hi[i] = h;
        lo[i] = f2bf(x[i] - bf2f(h));
    }
}

// swizzled element offset in a row-major [R][64] bf16 LDS tile (stride 128B)
#define SW(row, col) (((row) << 6) + ((col) ^ (((row) & 7) << 3)))

// ---------------------------------------------------------------------------
// fp32 -> bf16 hi/lo split convert (weights)
// ---------------------------------------------------------------------------
__global__ __launch_bounds__(256)
void cvt_split(const float* __restrict__ x, u16* __restrict__ yh,
               u16* __restrict__ yl, int n) {
    int i = (blockIdx.x * 256 + threadIdx.x) * 4;
    if (i >= n) return;
    float4 v = *(const float4*)(x + i);
    float a[4] = {v.x, v.y, v.z, v.w};
    ushort4 h, lo;
    u16 t;
    t = f2bf(a[0]); h.x = t; lo.x = f2bf(a[0] - bf2f(t));
    t = f2bf(a[1]); h.y = t; lo.y = f2bf(a[1] - bf2f(t));
    t = f2bf(a[2]); h.z = t; lo.z = f2bf(a[2] - bf2f(t));
    t = f2bf(a[3]); h.w = t; lo.w = f2bf(a[3] - bf2f(t));
    *(ushort4*)(yh + i) = h;
    *(ushort4*)(yl + i) = lo;
}

// ---------------------------------------------------------------------------
// per-expert transpose + convert: src[e][R][C] fp32 -> dst[e][C][R] bf16
// ---------------------------------------------------------------------------
__global__ __launch_bounds__(256)
void transpose_cvt(const float* __restrict__ src, u16* __restrict__ dst,
                   int R, int C) {
    const int e = blockIdx.z;
    src += (size_t)e * R * C;
    dst += (size_t)e * R * C;
    __shared__ float t[32][33];
    const int c0 = blockIdx.x << 5, r0 = blockIdx.y << 5;
    const int tx = threadIdx.x, ty = threadIdx.y;
#pragma unroll
    for (int i = 0; i < 4; ++i)
        t[ty * 4 + i][tx] = src[(size_t)(r0 + ty * 4 + i) * C + c0 + tx];
    __syncthreads();
#pragma unroll
    for (int i = 0; i < 4; ++i)
        dst[(size_t)(c0 + ty * 4 + i) * R + r0 + tx] = f2bf(t[tx][ty * 4 + i]);
}

// ---------------------------------------------------------------------------
// RMSNorm variant 1: hi/lo bf16 out (attention paths)
// ---------------------------------------------------------------------------
__global__ __launch_bounds__(256)
void rmsnorm_split(const float* __restrict__ X, const float* __restrict__ W,
                   u16* __restrict__ Yh, u16* __restrict__ Yl) {
    const int t = blockIdx.x;
    const int tid = threadIdx.x;
    const float* x = X + (size_t)t * HID;
    float x0 = x[tid], x1 = x[tid + 256], x2 = x[tid + 512];
    float ss = x0 * x0 + x1 * x1 + x2 * x2;
    for (int m = 1; m < 64; m <<= 1) ss += __shfl_xor(ss, m);
    __shared__ float red[4];
    if ((tid & 63) == 0) red[tid >> 6] = ss;
    __syncthreads();
    float tot = red[0] + red[1] + red[2] + red[3];
    float inv = rsqrtf(tot * (1.0f / HID) + 1e-6f);
    u16* yh = Yh + (size_t)t * HID;
    u16* yl = Yl + (size_t)t * HID;
#pragma unroll
    for (int j = 0; j < 3; ++j) {
        int idx = tid + j * 256;
        float r = x[idx] * inv * W[idx];
        u16 h = f2bf(r);
        yh[idx] = h;
        yl[idx] = f2bf(r - bf2f(h));
    }
}

// ---------------------------------------------------------------------------
// RMSNorm variant 2: fp32 + single bf16 out (MoE path: router + experts)
// ---------------------------------------------------------------------------
__global__ __launch_bounds__(256)
void rmsnorm_kernel(const float* __restrict__ X, const float* __restrict__ W,
                    float* __restrict__ Y, u16* __restrict__ Ybf) {
    const int t = blockIdx.x;
    const int tid = threadIdx.x;
    const float* x = X + (size_t)t * HID;
    float x0 = x[tid], x1 = x[tid + 256], x2 = x[tid + 512];
    float ss = x0 * x0 + x1 * x1 + x2 * x2;
    for (int m = 1; m < 64; m <<= 1) ss += __shfl_xor(ss, m);
    __shared__ float red[4];
    if ((tid & 63) == 0) red[tid >> 6] = ss;
    __syncthreads();
    float tot = red[0] + red[1] + red[2] + red[3];
    float inv = rsqrtf(tot * (1.0f / HID) + 1e-6f);
    float r0 = x0 * inv * W[tid];
    float r1 = x1 * inv * W[tid + 256];
    float r2 = x2 * inv * W[tid + 512];
    float* y = Y + (size_t)t * HID;
    y[tid] = r0; y[tid + 256] = r1; y[tid + 512] = r2;
    u16* yb = Ybf + (size_t)t * HID;
    yb[tid] = f2bf(r0); yb[tid + 256] = f2bf(r1); yb[tid + 512] = f2bf(r2);
}

// ---------------------------------------------------------------------------
// Split-precision MFMA NT GEMM for QKV. A pre-split hi/lo bf16 (gload_lds),
// Wh/Wl bf16 [1280][768]. Q,K out hi/lo bf16; V out fp32. Grid (10, 32).
// acc = ah*bh + al*bh + ah*bl
// ---------------------------------------------------------------------------
__global__ __launch_bounds__(256)
void qkv_split(const u16* __restrict__ Xh, const u16* __restrict__ Xl,
               const u16* __restrict__ Wh, const u16* __restrict__ Wl,
               const float* __restrict__ bq, const float* __restrict__ bk,
               const float* __restrict__ bv,
               u16* __restrict__ Qh, u16* __restrict__ Ql,
               u16* __restrict__ Kh, u16* __restrict__ Kl,
               float* __restrict__ Vo) {
    __shared__ __align__(16) u16 Ah[4096], Al[4096], Bh[4096], Bl[4096];
    const int tid = threadIdx.x, l = tid & 63, w = tid >> 6;
    const int wm = w & 1, wn = w >> 1;
    const int m0 = blockIdx.y << 7, n0 = blockIdx.x << 7;
    const int sr = l >> 2, sc8 = (l & 3) << 3;
    const u16* gAh0 = Xh + (size_t)(m0 + w * 32 + sr) * HID + sc8;
    const u16* gAh1 = gAh0 + 16 * HID;
    const u16* gAl0 = Xl + (size_t)(m0 + w * 32 + sr) * HID + sc8;
    const u16* gAl1 = gAl0 + 16 * HID;
    const u16* gBh0 = Wh + (size_t)(n0 + w * 32 + sr) * HID + sc8;
    const u16* gBh1 = gBh0 + 16 * HID;
    const u16* gBl0 = Wl + (size_t)(n0 + w * 32 + sr) * HID + sc8;
    const u16* gBl1 = gBl0 + 16 * HID;
    u16* lAh0 = Ah + w * 1024; u16* lAh1 = lAh0 + 512;
    u16* lAl0 = Al + w * 1024; u16* lAl1 = lAl0 + 512;
    u16* lBh0 = Bh + w * 1024; u16* lBh1 = lBh0 + 512;
    u16* lBl0 = Bl + w * 1024; u16* lBl1 = lBl0 + 512;
    const int fr = l & 15, fc = (l >> 4) << 3;
    f32x4 acc[4][4];
#pragma unroll
    for (int i = 0; i < 4; ++i)
#pragma unroll
        for (int j = 0; j < 4; ++j) acc[i][j] = (f32x4){0.f, 0.f, 0.f, 0.f};
    for (int k0 = 0; k0 < HID; k0 += 32) {
        gload16(gAh0 + k0, lAh0);
        gload16(gAh1 + k0, lAh1);
        gload16(gAl0 + k0, lAl0);
        gload16(gAl1 + k0, lAl1);
        gload16(gBh0 + k0, lBh0);
        gload16(gBh1 + k0, lBh1);
        gload16(gBl0 + k0, lBl0);
        gload16(gBl1 + k0, lBl1);
        __syncthreads();
        bf16x8 ah[4], al[4], bh[4], bl[4];
#pragma unroll
        for (int i = 0; i < 4; ++i) {
            ah[i] = *(const bf16x8*)(Ah + (wm * 64 + i * 16 + fr) * 32 + fc);
            al[i] = *(const bf16x8*)(Al + (wm * 64 + i * 16 + fr) * 32 + fc);
            bh[i] = *(const bf16x8*)(Bh + (wn * 64 + i * 16 + fr) * 32 + fc);
            bl[i] = *(const bf16x8*)(Bl + (wn * 64 + i * 16 + fr) * 32 + fc);
        }
#pragma unroll
        for (int mf = 0; mf < 4; ++mf)
#pragma unroll
            for (int nf = 0; nf < 4; ++nf) {
                acc[mf][nf] = __builtin_amdgcn_mfma_f32_16x16x32_bf16(
                    ah[mf], bh[nf], acc[mf][nf], 0, 0, 0);
                acc[mf][nf] = __builtin_amdgcn_mfma_f32_16x16x32_bf16(
                    al[mf], bh[nf], acc[mf][nf], 0, 0, 0);
                acc[mf][nf] = __builtin_amdgcn_mfma_f32_16x16x32_bf16(
                    ah[mf], bl[nf], acc[mf][nf], 0, 0, 0);
            }
        __syncthreads();
    }
    const int er = (l >> 4) << 2, ec = l & 15;
    if (n0 < 1024) {
        u16 *oh, *olo; const float* bp; int ldc, nl;
        if (n0 < 768) { oh = Qh; olo = Ql; bp = bq; ldc = 768; nl = n0; }
        else          { oh = Kh; olo = Kl; bp = bk; ldc = KVD; nl = n0 - 768; }
#pragma unroll
        for (int mf = 0; mf < 4; ++mf)
#pragma unroll
            for (int i = 0; i < 4; ++i) {
                int row = m0 + wm * 64 + mf * 16 + er + i;
#pragma unroll
                for (int nf = 0; nf < 4; ++nf) {
                    int col = nl + wn * 64 + nf * 16 + ec;
                    float v = acc[mf][nf][i] + bp[col];
                    size_t idx = (size_t)row * ldc + col;
                    u16 h = f2bf(v);
                    oh[idx] = h;
                    olo[idx] = f2bf(v - bf2f(h));
                }
            }
    } else {
        int nl = n0 - 1024;
#pragma unroll
        for (int mf = 0; mf < 4; ++mf)
#pragma unroll
            for (int i = 0; i < 4; ++i) {
                int row = m0 + wm * 64 + mf * 16 + er + i;
#pragma unroll
                for (int nf = 0; nf < 4; ++nf) {
                    int col = nl + wn * 64 + nf * 16 + ec;
                    Vo[(size_t)row * KVD + col] = acc[mf][nf][i] + bv[col];
                }
            }
    }
}

// ---------------------------------------------------------------------------
// Split-precision MFMA NT GEMM with residual: C = A@W^T + resid.
// A pre-split hi/lo bf16 (gload_lds). Grid (6, 32).
// ---------------------------------------------------------------------------
__global__ __launch_bounds__(256)
void oproj_split(const u16* __restrict__ Ahg, const u16* __restrict__ Alg,
                 const u16* __restrict__ Wh, const u16* __restrict__ Wl,
                 const float* __restrict__ resid, float* __restrict__ C,
                 int M, int N, int K) {
    __shared__ __align__(16) u16 Ah[4096], Al[4096], Bh[4096], Bl[4096];
    const int tid = threadIdx.x, l = tid & 63, w = tid >> 6;
    const int wm = w & 1, wn = w >> 1;
    const int m0 = blockIdx.y << 7, n0 = blockIdx.x << 7;
    const int sr = l >> 2, sc8 = (l & 3) << 3;
    const u16* gAh0 = Ahg + (size_t)(m0 + w * 32 + sr) * K + sc8;
    const u16* gAh1 = gAh0 + (size_t)16 * K;
    const u16* gAl0 = Alg + (size_t)(m0 + w * 32 + sr) * K + sc8;
    const u16* gAl1 = gAl0 + (size_t)16 * K;
    const u16* gBh0 = Wh + (size_t)(n0 + w * 32 + sr) * K + sc8;
    const u16* gBh1 = gBh0 + (size_t)16 * K;
    const u16* gBl0 = Wl + (size_t)(n0 + w * 32 + sr) * K + sc8;
    const u16* gBl1 = gBl0 + (size_t)16 * K;
    u16* lAh0 = Ah + w * 1024; u16* lAh1 = lAh0 + 512;
    u16* lAl0 = Al + w * 1024; u16* lAl1 = lAl0 + 512;
    u16* lBh0 = Bh + w * 1024; u16* lBh1 = lBh0 + 512;
    u16* lBl0 = Bl + w * 1024; u16* lBl1 = lBl0 + 512;
    const int fr = l & 15, fc = (l >> 4) << 3;
    f32x4 acc[4][4];
#pragma unroll
    for (int i = 0; i < 4; ++i)
#pragma unroll
        for (int j = 0; j < 4; ++j) acc[i][j] = (f32x4){0.f, 0.f, 0.f, 0.f};
    for (int k0 = 0; k0 < K; k0 += 32) {
        gload16(gAh0 + k0, lAh0);
        gload16(gAh1 + k0, lAh1);
        gload16(gAl0 + k0, lAl0);
        gload16(gAl1 + k0, lAl1);
        gload16(gBh0 + k0, lBh0);
        gload16(gBh1 + k0, lBh1);
        gload16(gBl0 + k0, lBl0);
        gload16(gBl1 + k0, lBl1);
        __syncthreads();
        bf16x8 ah[4], al[4], bh[4], bl[4];
#pragma unroll
        for (int i = 0; i < 4; ++i) {
            ah[i] = *(const bf16x8*)(Ah + (wm * 64 + i * 16 + fr) * 32 + fc);
            al[i] = *(const bf16x8*)(Al + (wm * 64 + i * 16 + fr) * 32 + fc);
            bh[i] = *(const bf16x8*)(Bh + (wn * 64 + i * 16 + fr) * 32 + fc);
            bl[i] = *(const bf16x8*)(Bl + (wn * 64 + i * 16 + fr) * 32 + fc);
        }
#pragma unroll
        for (int mf = 0; mf < 4; ++mf)
#pragma unroll
            for (int nf = 0; nf < 4; ++nf) {
                acc[mf][nf] = __builtin_amdgcn_mfma_f32_16x16x32_bf16(
                    ah[mf], bh[nf], acc[mf][nf], 0, 0, 0);
                acc[mf][nf] = __builtin_amdgcn_mfma_f32_16x16x32_bf16(
                    al[mf], bh[nf], acc[mf][nf], 0, 0, 0);
                acc[mf][nf] = __builtin_amdgcn_mfma_f32_16x16x32_bf16(
                    ah[mf], bl[nf], acc[mf][nf], 0, 0, 0);
            }
        __syncthreads();
    }
    const int er = (l >> 4) << 2, ec = l & 15;
#pragma unroll
    for (int mf = 0; mf < 4; ++mf)
#pragma unroll
        for (int i = 0; i < 4; ++i) {
            int row = m0 + wm * 64 + mf * 16 + er + i;
#pragma unroll
            for (int nf = 0; nf < 4; ++nf) {
                int col = n0 + wn * 64 + nf * 16 + ec;
                C[(size_t)row * N + col] =
                    acc[mf][nf][i] + resid[(size_t)row * N + col];
            }
        }
}

// ---------------------------------------------------------------------------
// RoPE on hi/lo split q (12 heads) and k (4 heads) per token
// ---------------------------------------------------------------------------
__global__ __launch_bounds__(256)
void rope_split(u16* __restrict__ Qh, u16* __restrict__ Ql,
                u16* __restrict__ Kh, u16* __restrict__ Kl,
                const int* __restrict__ pos_ids) {
    const int t = blockIdx.x;
    const float pos = (float)pos_ids[t];
    const int tid = threadIdx.x;
#pragma unroll
    for (int it = 0; it < 2; ++it) {
        int p = tid + (it << 8);
        int head = p >> 5, i = p & 31;
        float invf = expf(-(float)i * 0.28782313662425572f); // ln(1e4)/32
        float ang = pos * invf;
        float c = cosf(ang), sn = sinf(ang);
        u16 *ah, *al;
        size_t bofs;
        if (head < NHEAD) { ah = Qh; al = Ql; bofs = (size_t)t * HID + head * HDIM; }
        else { ah = Kh; al = Kl; bofs = (size_t)t * KVD + (head - NHEAD) * HDIM; }
        float x1 = bf2f(ah[bofs + i]) + bf2f(al[bofs + i]);
        float x2 = bf2f(ah[bofs + i + 32]) + bf2f(al[bofs + i + 32]);
        float y1 = x1 * c - x2 * sn;
        float y2 = x2 * c + x1 * sn;
        u16 h1 = f2bf(y1);
        ah[bofs + i] = h1;
        al[bofs + i] = f2bf(y1 - bf2f(h1));
        u16 h2 = f2bf(y2);
        ah[bofs + i + 32] = h2;
        al[bofs + i + 32] = f2bf(y2 - bf2f(h2));
    }
}

// ---------------------------------------------------------------------------
// Self attention (causal GQA), split-precision MFMA, online softmax.
// Q/K pre-split hi/lo (plain u16 copies into swizzled LDS); V fp32 staged
// transposed with in-kernel split. Out: hi/lo bf16. 256 thr = 32 queries.
// ---------------------------------------------------------------------------
__global__ __launch_bounds__(256)
void attn_self_mfma(const u16* __restrict__ Qhg, const u16* __restrict__ Qlg,
                    const u16* __restrict__ Khg, const u16* __restrict__ Klg,
                    const float* __restrict__ V,
                    u16* __restrict__ Oh, u16* __restrict__ Ol) {
    const int qt = blockIdx.x, n = blockIdx.y, b = blockIdx.z;
    const int kv = n / REP;
    const int tid = threadIdx.x, l = tid & 63, w = tid >> 6;
    const int q0 = qt << 5;
    __shared__ __align__(16) u16 sQh[2048], sQl[2048];  // [32][64]
    __shared__ __align__(16) u16 sKh[4096], sKl[4096];  // [64][64]
    __shared__ __align__(16) u16 sVh[4096], sVl[4096];  // transposed [d][key]
    __shared__ float Ps[32][68];
    __shared__ float scal[32];

    // ---- stage Q (copy hi/lo, swizzled) ----
    {
        int row = tid >> 3, cg = (tid & 7) << 3;
        size_t gq = (size_t)(b * SEQ + q0 + row) * HID + n * HDIM + cg;
        *(u16x8*)(sQh + SW(row, cg)) = *(const u16x8*)(Qhg + gq);
        *(u16x8*)(sQl + SW(row, cg)) = *(const u16x8*)(Qlg + gq);
    }
    __syncthreads();

    const int fr = l & 15, fcg = (l >> 4) << 3;
    const int qf16 = (w & 1) << 4;
    const int fp2 = (w >> 1) << 1;
    bf16x8 qfh[2], qfl[2];
#pragma unroll
    for (int dc = 0; dc < 2; ++dc) {
        int off = SW(qf16 + fr, dc * 32 + fcg);
        qfh[dc] = *(const bf16x8*)(sQh + off);
        qfl[dc] = *(const bf16x8*)(sQl + off);
    }

    f32x4 o[2];
    o[0] = (f32x4){0.f, 0.f, 0.f, 0.f};
    o[1] = (f32x4){0.f, 0.f, 0.f, 0.f};
    float m_run = -3.4e38f, l_run = 0.f;
    const int sq = tid >> 3;
    const int skb = (tid & 7) << 3;
    const float scale = 0.125f;
    const int nt = (qt >> 1) + 1;

    for (int t = 0; t < nt; ++t) {
        __syncthreads();
        // ---- stage K tile (copy hi/lo, swizzled) ----
        {
            int row = tid >> 2, cg = (tid & 3) << 4;
            size_t gk = (size_t)(b * SEQ + (t << 6) + row) * KVD + kv * HDIM + cg;
            *(u16x8*)(sKh + SW(row, cg))     = *(const u16x8*)(Khg + gk);
            *(u16x8*)(sKh + SW(row, cg + 8)) = *(const u16x8*)(Khg + gk + 8);
            *(u16x8*)(sKl + SW(row, cg))     = *(const u16x8*)(Klg + gk);
            *(u16x8*)(sKl + SW(row, cg + 8)) = *(const u16x8*)(Klg + gk + 8);
        }
        // ---- stage V tile transposed [d][key] (hi/lo, swizzled) ----
        {
            int kp = (tid & 31) << 1, dc = (tid >> 5) << 3;
            const float* vg0 = V + (size_t)(b * SEQ + (t << 6) + kp) * KVD
                               + kv * HDIM + dc;
            const float* vg1 = vg0 + KVD;
            float4 a0 = *(const float4*)vg0;
            float4 a1 = *(const float4*)(vg0 + 4);
            float4 b0 = *(const float4*)vg1;
            float4 b1 = *(const float4*)(vg1 + 4);
            float va[8] = {a0.x, a0.y, a0.z, a0.w, a1.x, a1.y, a1.z, a1.w};
            float vb[8] = {b0.x, b0.y, b0.z, b0.w, b1.x, b1.y, b1.z, b1.w};
#pragma unroll
            for (int j = 0; j < 8; ++j) {
                u16 h0 = f2bf(va[j]);
                u16 h1 = f2bf(vb[j]);
                u16 p0 = f2bf(va[j] - bf2f(h0));
                u16 p1 = f2bf(vb[j] - bf2f(h1));
                int off = SW(dc + j, kp);
                *(unsigned*)(sVh + off) = (unsigned)h0 | ((unsigned)h1 << 16);
                *(unsigned*)(sVl + off) = (unsigned)p0 | ((unsigned)p1 << 16);
            }
        }
        __syncthreads();
        // ---- S = Q K^T (split MFMA) ----
#pragma unroll
        for (int kk = 0; kk < 2; ++kk) {
            int kf = fp2 + kk;
            bf16x8 kh[2], klv[2];
#pragma unroll
            for (int dc = 0; dc < 2; ++dc) {
                int off = SW(kf * 16 + fr, dc * 32 + fcg);
                kh[dc]  = *(const bf16x8*)(sKh + off);
                klv[dc] = *(const bf16x8*)(sKl + off);
            }
            f32x4 s = (f32x4){0.f, 0.f, 0.f, 0.f};
            s = __builtin_amdgcn_mfma_f32_16x16x32_bf16(qfh[0], kh[0], s, 0, 0, 0);
            s = __builtin_amdgcn_mfma_f32_16x16x32_bf16(qfh[1], kh[1], s, 0, 0, 0);
            s = __builtin_amdgcn_mfma_f32_16x16x32_bf16(qfl[0], kh[0], s, 0, 0, 0);
            s = __builtin_amdgcn_mfma_f32_16x16x32_bf16(qfl[1], kh[1], s, 0, 0, 0);
            s = __builtin_amdgcn_mfma_f32_16x16x32_bf16(qfh[0], klv[0], s, 0, 0, 0);
            s = __builtin_amdgcn_mfma_f32_16x16x32_bf16(qfh[1], klv[1], s, 0, 0, 0);
            int col = kf * 16 + fr;
            int key = (t << 6) + col;
#pragma unroll
            for (int r = 0; r < 4; ++r) {
                int qrow = qf16 + ((l >> 4) << 2) + r;
                Ps[qrow][col] = (key <= q0 + qrow) ? s[r] * scale : -1e9f;
            }
        }
        __syncthreads();
        // ---- online softmax update (8 threads per query) ----
        {
            float4 s0 = *(const float4*)&Ps[sq][skb];
            float4 s1 = *(const float4*)&Ps[sq][skb + 4];
            float sv[8] = {s0.x, s0.y, s0.z, s0.w, s1.x, s1.y, s1.z, s1.w};
            float mx = sv[0];
#pragma unroll
            for (int j = 1; j < 8; ++j) mx = fmaxf(mx, sv[j]);
            for (int x = 1; x < 8; x <<= 1) mx = fmaxf(mx, __shfl_xor(mx, x));
            float mnew = fmaxf(m_run, mx);
            float corr = __expf(m_run - mnew);
            float lsum = 0.f;
#pragma unroll
            for (int j = 0; j < 8; ++j) {
                sv[j] = __expf(sv[j] - mnew);
                lsum += sv[j];
            }
            for (int x = 1; x < 8; x <<= 1) lsum += __shfl_xor(lsum, x);
            l_run = l_run * corr + lsum;
            m_run = mnew;
            *(float4*)&Ps[sq][skb]     = make_float4(sv[0], sv[1], sv[2], sv[3]);
            *(float4*)&Ps[sq][skb + 4] = make_float4(sv[4], sv[5], sv[6], sv[7]);
            if ((tid & 7) == 0) scal[sq] = corr;
        }
        __syncthreads();
        // ---- rescale O, then O += P V (split MFMA) ----
        {
            float4 c4 = *(const float4*)&scal[qf16 + ((l >> 4) << 2)];
            float cr[4] = {c4.x, c4.y, c4.z, c4.w};
#pragma unroll
            for (int dfi = 0; dfi < 2; ++dfi)
#pragma unroll
                for (int r = 0; r < 4; ++r) o[dfi][r] *= cr[r];
            bf16x8 ph[2], pl[2];
#pragma unroll
            for (int kc = 0; kc < 2; ++kc) {
                float4 p0 = *(const float4*)&Ps[qf16 + fr][kc * 32 + fcg];
                float4 p1 = *(const float4*)&Ps[qf16 + fr][kc * 32 + fcg + 4];
                u16x8 hh, ll;
                cvt8(p0, p1, hh, ll);
                ph[kc] = *(bf16x8*)&hh;
                pl[kc] = *(bf16x8*)&ll;
            }
#pragma unroll
            for (int dfi = 0; dfi < 2; ++dfi) {
                int df = fp2 + dfi;
#pragma unroll
                for (int kc = 0; kc < 2; ++kc) {
                    int off = SW(df * 16 + fr, kc * 32 + fcg);
                    bf16x8 vh = *(const bf16x8*)(sVh + off);
                    bf16x8 vl = *(const bf16x8*)(sVl + off);
                    o[dfi] = __builtin_amdgcn_mfma_f32_16x16x32_bf16(
                        ph[kc], vh, o[dfi], 0, 0, 0);
                    o[dfi] = __builtin_amdgcn_mfma_f32_16x16x32_bf16(
                        pl[kc], vh, o[dfi], 0, 0, 0);
                    o[dfi] = __builtin_amdgcn_mfma_f32_16x16x32_bf16(
                        ph[kc], vl, o[dfi], 0, 0, 0);
                }
            }
        }
    }
    __syncthreads();
    if ((tid & 7) == 0) scal[sq] = 1.0f / l_run;
    __syncthreads();
    {
        int qrb = qf16 + ((l >> 4) << 2);
        float4 li4 = *(const float4*)&scal[qrb];
        float li[4] = {li4.x, li4.y, li4.z, li4.w};
#pragma unroll
        for (int dfi = 0; dfi < 2; ++dfi) {
            int df = fp2 + dfi;
            int col = n * HDIM + df * 16 + fr;
#pragma unroll
            for (int r = 0; r < 4; ++r) {
                int row = q0 + qrb + r;
                float val = o[dfi][r] * li[r];
                size_t oidx = (size_t)(b * SEQ + row) * HID + col;
                u16 h = f2bf(val);
                Oh[oidx] = h;
                Ol[oidx] = f2bf(val - bf2f(h));
            }
        }
    }
}

// ---------------------------------------------------------------------------
// Group attention: MHA across the 8 channels. One wave per (s, head).
// Q/K hi/lo in; V fp32; out hi/lo.
// ---------------------------------------------------------------------------
__global__ __launch_bounds__(64)
void attn_group(const u16* __restrict__ Qh, const u16* __restrict__ Ql,
                const u16* __restrict__ Kh, const u16* __restrict__ Kl,
                const float* __restrict__ V, const float* __restrict__ gmask,
                u16* __restrict__ Oh, u16* __restrict__ Ol) {
    const int n = blockIdx.x % NHEAD;
    const int s = blockIdx.x / NHEAD;
    const int kv = n / REP;
    const int lane = threadIdx.x;
    __shared__ float Qs[8][65], Ks[8][65], Vs[8][65], Ps[64];
    for (int c = 0; c < 8; ++c) {
        size_t qi = (size_t)(c * SEQ + s) * HID + n * HDIM + lane;
        size_t ki = (size_t)(c * SEQ + s) * KVD + kv * HDIM + lane;
        Qs[c][lane] = bf2f(Qh[qi]) + bf2f(Ql[qi]);
        Ks[c][lane] = bf2f(Kh[ki]) + bf2f(Kl[ki]);
        Vs[c][lane] = V[ki];
    }
    __syncthreads();
    const int qb = lane >> 3, kb = lane & 7;
    float sc = 0;
    for (int d = 0; d < 64; ++d) sc += Qs[qb][d] * Ks[kb][d];
    sc = sc * 0.125f + gmask[(size_t)s * 64 + qb * 8 + kb];
    float m = sc;
    for (int x = 1; x < 8; x <<= 1) m = fmaxf(m, __shfl_xor(m, x));
    float p = __expf(sc - m);
    float l = p;
    for (int x = 1; x < 8; x <<= 1) l += __shfl_xor(l, x);
    Ps[lane] = p / l;
    __syncthreads();
    for (int q2 = 0; q2 < 8; ++q2) {
        float o = 0;
        for (int c = 0; c < 8; ++c) o += Ps[q2 * 8 + c] * Vs[c][lane];
        size_t oidx = (size_t)(q2 * SEQ + s) * HID + n * HDIM + lane;
        u16 h = f2bf(o);
        Oh[oidx] = h;
        Ol[oidx] = f2bf(o - bf2f(h));
    }
}

// ---------------------------------------------------------------------------
// MoE router (fp32)
// ---------------------------------------------------------------------------
__global__ __launch_bounds__(64)
void router_kernel(const float* __restrict__ X, const float* __restrict__ GW,
                   int* __restrict__ counts, int* __restrict__ topi,
                   float* __restrict__ topw, int* __restrict__ posb) {
    const int t = blockIdx.x;
    const int lane = threadIdx.x;
    const int e = lane >> 3, c = lane & 7;
    const float4* x4 = (const float4*)(X + (size_t)t * HID + c * 96);
    const float4* g4 = (const float4*)(GW + (size_t)e * HID + c * 96);
    float p = 0;
#pragma unroll
    for (int i = 0; i < 24; ++i) {
        float4 xv = x4[i], gv = g4[i];
        p += xv.x * gv.x + xv.y * gv.y + xv.z * gv.z + xv.w * gv.w;
    }
    p += __shfl_xor(p, 1);
    p += __shfl_xor(p, 2);
    p += __shfl_xor(p, 4);
    float lg[8];
#pragma unroll
    for (int i = 0; i < 8; ++i) lg[i] = __shfl(p, i * 8);
    float m = lg[0];
#pragma unroll
    for (int i = 1; i < 8; ++i) m = fmaxf(m, lg[i]);
    float s = 0;
#pragma unroll
    for (int i = 0; i < 8; ++i) { lg[i] = expf(lg[i] - m); s += lg[i]; }
    float inv = 1.0f / s;
    int i1 = 0; float b1 = lg[0];
#pragma unroll
    for (int i = 1; i < 8; ++i) if (lg[i] > b1) { b1 = lg[i]; i1 = i; }
    int i2 = -1; float b2 = -1.0f;
#pragma unroll
    for (int i = 0; i < 8; ++i)
        if (i != i1 && lg[i] > b2) { b2 = lg[i]; i2 = i; }
    if (lane == 0) {
        topi[t * 2] = i1; topi[t * 2 + 1] = i2;
        topw[t * 2] = b1 * inv; topw[t * 2 + 1] = b2 * inv;
        posb[t * 2] = atomicAdd(&counts[i1], 1);
        posb[t * 2 + 1] = atomicAdd(&counts[i2], 1);
    }
}

__global__ void scan_kernel(const int* __restrict__ counts, int* __restrict__ offsets) {
    int acc = 0;
    for (int e = 0; e < NEXP; ++e) { offsets[e] = acc; acc += counts[e]; }
}

__global__ __launch_bounds__(256)
void fill_slots(const int* __restrict__ topi, const float* __restrict__ topw,
                const int* __restrict__ posb, const int* __restrict__ offsets,
                int* __restrict__ slot_token, float* __restrict__ slot_w,
                int* __restrict__ token_slot) {
    int t = blockIdx.x * 256 + threadIdx.x;
    if (t >= NTOK) return;
#pragma unroll
    for (int k = 0; k < TOPK; ++k) {
        int e = topi[t * 2 + k];
        int sl = offsets[e] + posb[t * 2 + k];
        slot_token[sl] = t;
        slot_w[sl] = topw[t * 2 + k];
        token_slot[t * 2 + k] = sl;
    }
}

// ---------------------------------------------------------------------------
// MoE gate+up grouped GEMM, single-bf16 A. Grid (n=12, m=32, e=8) (R6 order).
// ---------------------------------------------------------------------------
__global__ __launch_bounds__(256)
void moe_gate_up(const u16* __restrict__ Xb, const u16* __restrict__ Wg,
                 const u16* __restrict__ Wu,
                 const int* __restrict__ slot_token,
                 const int* __restrict__ counts,
                 const int* __restrict__ offsets, u16* __restrict__ H) {
    const int e = blockIdx.z;
    const int Ce = counts[e];
    const int m0 = blockIdx.y << 7;
    if (Ce == 0 || m0 >= Ce) return;
    const int n0 = blockIdx.x << 7;
    const int base = offsets[e];
    __shared__ __align__(16) u16 As[4096];
    __shared__ __align__(16) u16 Gs[4096];
    __shared__ __align__(16) u16 Us[4096];
    const int tid = threadIdx.x, l = tid & 63, w = tid >> 6;
    const int wm = w & 1, wn = w >> 1;
    const int sr = l >> 2, sc8 = (l & 3) << 3;
    int r0 = m0 + w * 32 + sr;
    int r1 = r0 + 16;
    int t0 = slot_token[base + min(r0, Ce - 1)];
    int t1 = slot_token[base + min(r1, Ce - 1)];
    const u16* gA0 = Xb + (size_t)t0 * HID + sc8;
    const u16* gA1 = Xb + (size_t)t1 * HID + sc8;
    const u16* Wge = Wg + (size_t)e * IEXP * HID;
    const u16* Wue = Wu + (size_t)e * IEXP * HID;
    const u16* gG0 = Wge + (size_t)(n0 + w * 32 + sr) * HID + sc8;
    const u16* gG1 = gG0 + 16 * HID;
    const u16* gU0 = Wue + (size_t)(n0 + w * 32 + sr) * HID + sc8;
    const u16* gU1 = gU0 + 16 * HID;
    u16* lA0 = As + w * 1024; u16* lA1 = lA0 + 512;
    u16* lG0 = Gs + w * 1024; u16* lG1 = lG0 + 512;
    u16* lU0 = Us + w * 1024; u16* lU1 = lU0 + 512;
    const int fr = l & 15, fc = (l >> 4) << 3;
    f32x4 accg[4][4], accu[4][4];
#pragma unroll
    for (int i = 0; i < 4; ++i)
#pragma unroll
        for (int j = 0; j < 4; ++j) {
            accg[i][j] = (f32x4){0.f, 0.f, 0.f, 0.f};
            accu[i][j] = (f32x4){0.f, 0.f, 0.f, 0.f};
        }
    for (int k0 = 0; k0 < HID; k0 += 32) {
        gload16(gA0 + k0, lA0);
        gload16(gA1 + k0, lA1);
        gload16(gG0 + k0, lG0);
        gload16(gG1 + k0, lG1);
        gload16(gU0 + k0, lU0);
        gload16(gU1 + k0, lU1);
        __syncthreads();
        bf16x8 af[4], gf[4], uf[4];
#pragma unroll
        for (int i = 0; i < 4; ++i) {
            af[i] = *(const bf16x8*)(As + (wm * 64 + i * 16 + fr) * 32 + fc);
            gf[i] = *(const bf16x8*)(Gs + (wn * 64 + i * 16 + fr) * 32 + fc);
            uf[i] = *(const bf16x8*)(Us + (wn * 64 + i * 16 + fr) * 32 + fc);
        }
#pragma unroll
        for (int mf = 0; mf < 4; ++mf)
#pragma unroll
            for (int nf = 0; nf < 4; ++nf) {
                accg[mf][nf] = __builtin_amdgcn_mfma_f32_16x16x32_bf16(
                    af[mf], gf[nf], accg[mf][nf], 0, 0, 0);
                accu[mf][nf] = __builtin_amdgcn_mfma_f32_16x16x32_bf16(
                    af[mf], uf[nf], accu[mf][nf], 0, 0, 0);
            }
        __syncthreads();
    }
    const int er = (l >> 4) << 2, ec = l & 15;
#pragma unroll
    for (int mf = 0; mf < 4; ++mf)
#pragma unroll
        for (int i = 0; i < 4; ++i) {
            int row = m0 + wm * 64 + mf * 16 + er + i;
            if (row >= Ce) continue;
            size_t sl = (size_t)(base + row);
#pragma unroll
            for (int nf = 0; nf < 4; ++nf) {
                int col = n0 + wn * 64 + nf * 16 + ec;
                float g = accg[mf][nf][i];
                float u = accu[mf][nf][i];
                float h = g / (1.0f + __expf(-g)) * u;
                H[sl * IEXP + col] = f2bf(h);
            }
        }
}

// ---------------------------------------------------------------------------
// MoE down grouped GEMM bf16: D[slot][HID] fp32 = slot_w * (H @ Wd^T)
// ---------------------------------------------------------------------------
__global__ __launch_bounds__(256)
void moe_down_bf16(const u16* __restrict__ Hb, const u16* __restrict__ Wd,
                   const float* __restrict__ slot_w,
                   const int* __restrict__ counts,
                   const int* __restrict__ offsets, float* __restrict__ D) {
    const int e = blockIdx.z;
    const int Ce = counts[e];
    const int m0 = blockIdx.y << 7;
    if (Ce == 0 || m0 >= Ce) return;
    const int n0 = blockIdx.x << 7;
    const int base = offsets[e];
    __shared__ __align__(16) u16 As[4096];
    __shared__ __align__(16) u16 Bs[4096];
    const int tid = threadIdx.x, l = tid & 63, w = tid >> 6;
    const int wm = w & 1, wn = w >> 1;
    const int sr = l >> 2, sc = (l & 3) << 3;
    const u16* Ae = Hb + (size_t)base * IEXP;
    int r0 = min(m0 + w * 32 + sr, Ce - 1);
    int r1 = min(m0 + w * 32 + 16 + sr, Ce - 1);
    const u16* gA0 = Ae + (size_t)r0 * IEXP + sc;
    const u16* gA1 = Ae + (size_t)r1 * IEXP + sc;
    const u16* Wde = Wd + (size_t)e * HID * IEXP;
    const u16* gB0 = Wde + (size_t)(n0 + w * 32 + sr) * IEXP + sc;
    const u16* gB1 = gB0 + 16 * IEXP;
    u16* lA0 = As + w * 1024; u16* lA1 = lA0 + 512;
    u16* lB0 = Bs + w * 1024; u16* lB1 = lB0 + 512;
    const int fr = l & 15, fc = (l >> 4) << 3;
    f32x4 acc[4][4];
#pragma unroll
    for (int i = 0; i < 4; ++i)
#pragma unroll
        for (int j = 0; j < 4; ++j) acc[i][j] = (f32x4){0.f, 0.f, 0.f, 0.f};
    for (int k0 = 0; k0 < IEXP; k0 += 32) {
        gload16(gA0 + k0, lA0);
        gload16(gA1 + k0, lA1);
        gload16(gB0 + k0, lB0);
        gload16(gB1 + k0, lB1);
        __syncthreads();
        bf16x8 af[4], bfv[4];
#pragma unroll
        for (int i = 0; i < 4; ++i) {
            af[i]  = *(const bf16x8*)(As + (wm * 64 + i * 16 + fr) * 32 + fc);
            bfv[i] = *(const bf16x8*)(Bs + (wn * 64 + i * 16 + fr) * 32 + fc);
        }
#pragma unroll
        for (int mf = 0; mf < 4; ++mf)
#pragma unroll
            for (int nf = 0; nf < 4; ++nf)
                acc[mf][nf] = __builtin_amdgcn_mfma_f32_16x16x32_bf16(
                    af[mf], bfv[nf], acc[mf][nf], 0, 0, 0);
        __syncthreads();
    }
    const int er = (l >> 4) << 2, ec = l & 15;
#pragma unroll
    for (int mf = 0; mf < 4; ++mf)
#pragma unroll
        for (int i = 0; i < 4; ++i) {
            int row = m0 + wm * 64 + mf * 16 + er + i;
            if (row >= Ce) continue;
            size_t sl = (size_t)(base + row);
            float sw = slot_w[sl];
#pragma unroll
            for (int nf = 0; nf < 4; ++nf) {
                int col = n0 + wn * 64 + nf * 16 + ec;
                D[sl * HID + col] = acc[mf][nf][i] * sw;
            }
        }
}

__global__ __launch_bounds__(256)
void moe_add(float* __restrict__ out, const float* __restrict__ D,
             const int* __restrict__ token_slot) {
    const int t = blockIdx.y;
    const int h = blockIdx.x * 256 + threadIdx.x;
    int s0 = token_slot[t * 2], s1 = token_slot[t * 2 + 1];
    out[(size_t)t * HID + h] += D[(size_t)s0 * HID + h] + D[(size_t)s1 * HID + h];
}

// ---------------------------------------------------------------------------
extern "C" void kernel_launch(void* const* d_in, const int* in_sizes, int n_in,
                              void* d_out, int out_size, void* d_ws, size_t ws_size,
                              hipStream_t stream) {
    const float* hidden = (const float*)d_in[0];
    const float* amask  = (const float*)d_in[1];
    const float* gmask  = (const float*)d_in[2];
    const int*   posids = (const int*)d_in[3];
    const float* ln1 = (const float*)d_in[4];
    const float* ln2 = (const float*)d_in[5];
    const float* ln3 = (const float*)d_in[6];
    const float* sqw = (const float*)d_in[7];  const float* sqb = (const float*)d_in[8];
    const float* skw = (const float*)d_in[9];  const float* skb = (const float*)d_in[10];
    const float* svw = (const float*)d_in[11]; const float* svb = (const float*)d_in[12];
    const float* sow = (const float*)d_in[13];
    const float* gqw = (const float*)d_in[14]; const float* gqb = (const float*)d_in[15];
    const float* gkw = (const float*)d_in[16]; const float* gkb = (const float*)d_in[17];
    const float* gvw = (const float*)d_in[18]; const float* gvb = (const float*)d_in[19];
    const float* gow = (const float*)d_in[20];
    const float* gatew = (const float*)d_in[21];
    const float* wg = (const float*)d_in[22];
    const float* wu = (const float*)d_in[23];
    const float* wd = (const float*)d_in[24];
    float* out = (float*)d_out;
    (void)amask;

    // ---- workspace carve (byte offsets), ~121.8 MB (same budget as R9) ----
    char* base = (char*)d_ws;
    u16* xh   = (u16*)(base + 0);           //  6,291,456
    u16* xl   = (u16*)(base + 6291456);     //  -> 12,582,912
    u16* qh   = (u16*)(base + 12582912);    //  -> 18,874,368
    u16* ql   = (u16*)(base + 18874368);    //  -> 25,165,824
    u16* kh   = (u16*)(base + 25165824);    //  -> 27,262,976
    u16* kl   = (u16*)(base + 27262976);    //  -> 29,360,128
    float* vbuf = (float*)(base + 29360128);//  -> 33,554,432
    u16* oh   = (u16*)(base + 33554432);    //  -> 39,845,888
    u16* ol   = (u16*)(base + 39845888);    //  -> 46,137,344
    u16* wqkv_sh = (u16*)(base + 46137344);
    u16* wqkv_sl = (u16*)(base + 48103424);
    u16* wo_sh   = (u16*)(base + 50069504);
    u16* wo_sl   = (u16*)(base + 51249152);
    u16* wqkv_gh = (u16*)(base + 52428800);
    u16* wqkv_gl = (u16*)(base + 54394880);
    u16* wo_gh   = (u16*)(base + 56360960);
    u16* wo_gl   = (u16*)(base + 57540608); //  -> 58,720,256
    u16* wgt = (u16*)(base + 58720256);     //  -> 77,594,624
    u16* wut = (u16*)(base + 77594624);     //  -> 96,468,992
    u16* wdt = (u16*)(base + 96468992);     //  -> 115,343,360
    float* slotw = (float*)(base + 115343360);
    float* topw  = (float*)(base + 115376128);
    int* counts  = (int*)(base + 115408896);
    int* offsets = (int*)(base + 115409024);
    int* topi    = (int*)(base + 115409408);
    int* posb    = (int*)(base + 115442176);
    int* slot_token = (int*)(base + 115474944);
    int* token_slot = (int*)(base + 115507712);
    u16* xbf = (u16*)(base + 115540480);    //  -> 121,831,936
    // MoE-phase overlays (attention activations + attn weights dead by then):
    float* xb   = (float*)(base + 0);        // 12,582,912 over xh/xl
    u16*   Hbuf = (u16*)(base + 12582912);   // 25,165,824 over qh..vbuf+oh head
    float* Dbuf = (float*)(base + 37748736); // 25,165,824 over ol+attnW+wgt head

    // ---- weight prep ----
    cvt_split<<<576, 256, 0, stream>>>(sqw, wqkv_sh, wqkv_sl, 589824);
    cvt_split<<<192, 256, 0, stream>>>(skw, wqkv_sh + 589824, wqkv_sl + 589824, 196608);
    cvt_split<<<192, 256, 0, stream>>>(svw, wqkv_sh + 786432, wqkv_sl + 786432, 196608);
    cvt_split<<<576, 256, 0, stream>>>(sow, wo_sh, wo_sl, 589824);
    cvt_split<<<576, 256, 0, stream>>>(gqw, wqkv_gh, wqkv_gl, 589824);
    cvt_split<<<192, 256, 0, stream>>>(gkw, wqkv_gh + 589824, wqkv_gl + 589824, 196608);
    cvt_split<<<192, 256, 0, stream>>>(gvw, wqkv_gh + 786432, wqkv_gl + 786432, 196608);
    cvt_split<<<576, 256, 0, stream>>>(gow, wo_gh, wo_gl, 589824);
    transpose_cvt<<<dim3(48, 24, 8), dim3(32, 8), 0, stream>>>(wg, wgt, HID, IEXP);
    transpose_cvt<<<dim3(48, 24, 8), dim3(32, 8), 0, stream>>>(wu, wut, HID, IEXP);
    transpose_cvt<<<dim3(24, 48, 8), dim3(32, 8), 0, stream>>>(wd, wdt, IEXP, HID);

    // ---- self attention ----
    rmsnorm_split<<<NTOK, 256, 0, stream>>>(hidden, ln1, xh, xl);
    qkv_split<<<dim3(10, 32), 256, 0, stream>>>(xh, xl, wqkv_sh, wqkv_sl,
                                                sqb, skb, svb,
                                                qh, ql, kh, kl, vbuf);
    rope_split<<<NTOK, 256, 0, stream>>>(qh, ql, kh, kl, posids);
    attn_self_mfma<<<dim3(SEQ / 32, NHEAD, BATCH), 256, 0, stream>>>(
        qh, ql, kh, kl, vbuf, oh, ol);
    oproj_split<<<dim3(6, 32), 256, 0, stream>>>(oh, ol, wo_sh, wo_sl,
                                                 hidden, out, NTOK, HID, HID);

    // ---- group attention ----
    rmsnorm_split<<<NTOK, 256, 0, stream>>>(out, ln2, xh, xl);
    qkv_split<<<dim3(10, 32), 256, 0, stream>>>(xh, xl, wqkv_gh, wqkv_gl,
                                                gqb, gkb, gvb,
                                                qh, ql, kh, kl, vbuf);
    attn_group<<<SEQ * NHEAD, 64, 0, stream>>>(qh, ql, kh, kl, vbuf, gmask,
                                               oh, ol);
    oproj_split<<<dim3(6, 32), 256, 0, stream>>>(oh, ol, wo_gh, wo_gl,
                                                 out, out, NTOK, HID, HID);

    // ---- MoE (bf16 MFMA: post-router, flip-free; R6 grid order) ----
    rmsnorm_kernel<<<NTOK, 256, 0, stream>>>(out, ln3, xb, xbf);
    hipMemsetAsync(counts, 0, 8 * sizeof(int), stream);
    router_kernel<<<NTOK, 64, 0, stream>>>(xb, gatew, counts, topi, topw, posb);
    scan_kernel<<<1, 1, 0, stream>>>(counts, offsets);
    fill_slots<<<16, 256, 0, stream>>>(topi, topw, posb, offsets,
                                       slot_token, slotw, token_slot);
    moe_gate_up<<<dim3(12, 32, 8), 256, 0, stream>>>(
        xbf, wgt, wut, slot_token, counts, offsets, Hbuf);
    moe_down_bf16<<<dim3(6, 32, 8), 256, 0, stream>>>(
        Hbuf, wdt, slotw, counts, offsets, Dbuf);
    moe_add<<<dim3(3, NTOK), 256, 0, stream>>>(out, Dbuf, token_slot);
}

// Round 11
// 565.186 us; speedup vs baseline: 1.5427x; 1.0600x over previous
//
#include <hip/hip_runtime.h>
#include <math.h>

// Problem constants
#define BATCH 8
#define SEQ 512
#define HID 768
#define NHEAD 12
#define KVHEAD 4
#define HDIM 64
#define NEXP 8
#define TOPK 2
#define IEXP 1536
#define NTOK (BATCH * SEQ)     // 4096
#define NSLOT (NTOK * TOPK)    // 8192
#define REP (NHEAD / KVHEAD)   // 3
#define KVD (KVHEAD * HDIM)    // 256

typedef unsigned short u16;
typedef float f32x4 __attribute__((ext_vector_type(4)));
typedef __bf16 bf16x8 __attribute__((ext_vector_type(8)));
typedef unsigned short u16x8 __attribute__((ext_vector_type(8)));

__device__ __forceinline__ u16 f2bf(float f) {
    unsigned u = __float_as_uint(f);
    u += 0x7fffu + ((u >> 16) & 1u);   // RNE
    return (u16)(u >> 16);
}
__device__ __forceinline__ float bf2f(u16 h) {
    return __uint_as_float(((unsigned)h) << 16);
}

__device__ __forceinline__ void gload16(const void* g, void* l) {
    __builtin_amdgcn_global_load_lds(
        (const __attribute__((address_space(1))) void*)g,
        (__attribute__((address_space(3))) void*)l, 16, 0, 0);
}

// split 8 fp32 -> hi/lo bf16
__device__ __forceinline__ void cvt8(float4 a, float4 b, u16x8& hi, u16x8& lo) {
    float x[8] = {a.x, a.y, a.z, a.w, b.x, b.y, b.z, b.w};
#pragma unroll
    for (int i = 0; i < 8; ++i) {
        u16 h = f2bf(x[i]);
        hi[i] = h;
        lo[i] = f2bf(x[i] - bf2f(h));
    }
}

// swizzled element offset in a row-major [R][64] bf16 LDS tile (stride 128B)
#define SW(row, col) (((row) << 6) + ((col) ^ (((row) & 7) << 3)))

// ---------------------------------------------------------------------------
// All 8 attention weight tensors: fp32 -> hi/lo bf16 split, one launch.
// Flat index space 3,145,728 elems; grid 3072 x 256, 4 elems/thread.
// ---------------------------------------------------------------------------
__global__ __launch_bounds__(256)
void cvt_split8(const float* __restrict__ sq, const float* __restrict__ sk,
                const float* __restrict__ sv, const float* __restrict__ so,
                const float* __restrict__ gq, const float* __restrict__ gk,
                const float* __restrict__ gv, const float* __restrict__ go,
                u16* __restrict__ wqs_h, u16* __restrict__ wqs_l,
                u16* __restrict__ wos_h, u16* __restrict__ wos_l,
                u16* __restrict__ wqg_h, u16* __restrict__ wqg_l,
                u16* __restrict__ wog_h, u16* __restrict__ wog_l) {
    int i4 = (blockIdx.x * 256 + threadIdx.x) * 4;
    const float* src;
    u16 *dh, *dl;
    int s;
    if (i4 < 983040) {
        dh = wqs_h; dl = wqs_l;
        if (i4 < 589824)      { src = sq; s = i4; }
        else if (i4 < 786432) { src = sk; s = i4 - 589824; dh += 589824; dl += 589824; }
        else                  { src = sv; s = i4 - 786432; dh += 786432; dl += 786432; }
    } else if (i4 < 1572864) {
        src = so; s = i4 - 983040; dh = wos_h; dl = wos_l;
    } else if (i4 < 2555904) {
        int j = i4 - 1572864;
        dh = wqg_h; dl = wqg_l;
        if (j < 589824)      { src = gq; s = j; }
        else if (j < 786432) { src = gk; s = j - 589824; dh += 589824; dl += 589824; }
        else                 { src = gv; s = j - 786432; dh += 786432; dl += 786432; }
    } else {
        src = go; s = i4 - 2555904; dh = wog_h; dl = wog_l;
    }
    float4 v = *(const float4*)(src + s);
    float a[4] = {v.x, v.y, v.z, v.w};
    ushort4 h, lo;
    u16 t;
    t = f2bf(a[0]); h.x = t; lo.x = f2bf(a[0] - bf2f(t));
    t = f2bf(a[1]); h.y = t; lo.y = f2bf(a[1] - bf2f(t));
    t = f2bf(a[2]); h.z = t; lo.z = f2bf(a[2] - bf2f(t));
    t = f2bf(a[3]); h.w = t; lo.w = f2bf(a[3] - bf2f(t));
    *(ushort4*)(dh + s) = h;
    *(ushort4*)(dl + s) = lo;
}

// ---------------------------------------------------------------------------
// per-expert transpose + convert: src[e][R][C] fp32 -> dst[e][C][R] bf16
// ---------------------------------------------------------------------------
__global__ __launch_bounds__(256)
void transpose_cvt(const float* __restrict__ src, u16* __restrict__ dst,
                   int R, int C) {
    const int e = blockIdx.z;
    src += (size_t)e * R * C;
    dst += (size_t)e * R * C;
    __shared__ float t[32][33];
    const int c0 = blockIdx.x << 5, r0 = blockIdx.y << 5;
    const int tx = threadIdx.x, ty = threadIdx.y;
#pragma unroll
    for (int i = 0; i < 4; ++i)
        t[ty * 4 + i][tx] = src[(size_t)(r0 + ty * 4 + i) * C + c0 + tx];
    __syncthreads();
#pragma unroll
    for (int i = 0; i < 4; ++i)
        dst[(size_t)(c0 + ty * 4 + i) * R + r0 + tx] = f2bf(t[tx][ty * 4 + i]);
}

// ---------------------------------------------------------------------------
// RMSNorm variant 1: hi/lo bf16 out (attention paths)
// ---------------------------------------------------------------------------
__global__ __launch_bounds__(256)
void rmsnorm_split(const float* __restrict__ X, const float* __restrict__ W,
                   u16* __restrict__ Yh, u16* __restrict__ Yl) {
    const int t = blockIdx.x;
    const int tid = threadIdx.x;
    const float* x = X + (size_t)t * HID;
    float x0 = x[tid], x1 = x[tid + 256], x2 = x[tid + 512];
    float ss = x0 * x0 + x1 * x1 + x2 * x2;
    for (int m = 1; m < 64; m <<= 1) ss += __shfl_xor(ss, m);
    __shared__ float red[4];
    if ((tid & 63) == 0) red[tid >> 6] = ss;
    __syncthreads();
    float tot = red[0] + red[1] + red[2] + red[3];
    float inv = rsqrtf(tot * (1.0f / HID) + 1e-6f);
    u16* yh = Yh + (size_t)t * HID;
    u16* yl = Yl + (size_t)t * HID;
#pragma unroll
    for (int j = 0; j < 3; ++j) {
        int idx = tid + j * 256;
        float r = x[idx] * inv * W[idx];
        u16 h = f2bf(r);
        yh[idx] = h;
        yl[idx] = f2bf(r - bf2f(h));
    }
}

// ---------------------------------------------------------------------------
// RMSNorm variant 2: fp32 + single bf16 out (MoE path: router + experts)
// ---------------------------------------------------------------------------
__global__ __launch_bounds__(256)
void rmsnorm_kernel(const float* __restrict__ X, const float* __restrict__ W,
                    float* __restrict__ Y, u16* __restrict__ Ybf) {
    const int t = blockIdx.x;
    const int tid = threadIdx.x;
    const float* x = X + (size_t)t * HID;
    float x0 = x[tid], x1 = x[tid + 256], x2 = x[tid + 512];
    float ss = x0 * x0 + x1 * x1 + x2 * x2;
    for (int m = 1; m < 64; m <<= 1) ss += __shfl_xor(ss, m);
    __shared__ float red[4];
    if ((tid & 63) == 0) red[tid >> 6] = ss;
    __syncthreads();
    float tot = red[0] + red[1] + red[2] + red[3];
    float inv = rsqrtf(tot * (1.0f / HID) + 1e-6f);
    float r0 = x0 * inv * W[tid];
    float r1 = x1 * inv * W[tid + 256];
    float r2 = x2 * inv * W[tid + 512];
    float* y = Y + (size_t)t * HID;
    y[tid] = r0; y[tid + 256] = r1; y[tid + 512] = r2;
    u16* yb = Ybf + (size_t)t * HID;
    yb[tid] = f2bf(r0); yb[tid + 256] = f2bf(r1); yb[tid + 512] = f2bf(r2);
}

// ---------------------------------------------------------------------------
// Split-precision MFMA NT GEMM for QKV. A pre-split hi/lo bf16 (gload_lds),
// Wh/Wl bf16 [1280][768]. Q,K out hi/lo bf16; V out fp32. Grid (10, 32).
// acc = ah*bh + al*bh + ah*bl
// ---------------------------------------------------------------------------
__global__ __launch_bounds__(256)
void qkv_split(const u16* __restrict__ Xh, const u16* __restrict__ Xl,
               const u16* __restrict__ Wh, const u16* __restrict__ Wl,
               const float* __restrict__ bq, const float* __restrict__ bk,
               const float* __restrict__ bv,
               u16* __restrict__ Qh, u16* __restrict__ Ql,
               u16* __restrict__ Kh, u16* __restrict__ Kl,
               float* __restrict__ Vo) {
    __shared__ __align__(16) u16 Ah[4096], Al[4096], Bh[4096], Bl[4096];
    const int tid = threadIdx.x, l = tid & 63, w = tid >> 6;
    const int wm = w & 1, wn = w >> 1;
    const int m0 = blockIdx.y << 7, n0 = blockIdx.x << 7;
    const int sr = l >> 2, sc8 = (l & 3) << 3;
    const u16* gAh0 = Xh + (size_t)(m0 + w * 32 + sr) * HID + sc8;
    const u16* gAh1 = gAh0 + 16 * HID;
    const u16* gAl0 = Xl + (size_t)(m0 + w * 32 + sr) * HID + sc8;
    const u16* gAl1 = gAl0 + 16 * HID;
    const u16* gBh0 = Wh + (size_t)(n0 + w * 32 + sr) * HID + sc8;
    const u16* gBh1 = gBh0 + 16 * HID;
    const u16* gBl0 = Wl + (size_t)(n0 + w * 32 + sr) * HID + sc8;
    const u16* gBl1 = gBl0 + 16 * HID;
    u16* lAh0 = Ah + w * 1024; u16* lAh1 = lAh0 + 512;
    u16* lAl0 = Al + w * 1024; u16* lAl1 = lAl0 + 512;
    u16* lBh0 = Bh + w * 1024; u16* lBh1 = lBh0 + 512;
    u16* lBl0 = Bl + w * 1024; u16* lBl1 = lBl0 + 512;
    const int fr = l & 15, fc = (l >> 4) << 3;
    f32x4 acc[4][4];
#pragma unroll
    for (int i = 0; i < 4; ++i)
#pragma unroll
        for (int j = 0; j < 4; ++j) acc[i][j] = (f32x4){0.f, 0.f, 0.f, 0.f};
    for (int k0 = 0; k0 < HID; k0 += 32) {
        gload16(gAh0 + k0, lAh0);
        gload16(gAh1 + k0, lAh1);
        gload16(gAl0 + k0, lAl0);
        gload16(gAl1 + k0, lAl1);
        gload16(gBh0 + k0, lBh0);
        gload16(gBh1 + k0, lBh1);
        gload16(gBl0 + k0, lBl0);
        gload16(gBl1 + k0, lBl1);
        __syncthreads();
        bf16x8 ah[4], al[4], bh[4], bl[4];
#pragma unroll
        for (int i = 0; i < 4; ++i) {
            ah[i] = *(const bf16x8*)(Ah + (wm * 64 + i * 16 + fr) * 32 + fc);
            al[i] = *(const bf16x8*)(Al + (wm * 64 + i * 16 + fr) * 32 + fc);
            bh[i] = *(const bf16x8*)(Bh + (wn * 64 + i * 16 + fr) * 32 + fc);
            bl[i] = *(const bf16x8*)(Bl + (wn * 64 + i * 16 + fr) * 32 + fc);
        }
#pragma unroll
        for (int mf = 0; mf < 4; ++mf)
#pragma unroll
            for (int nf = 0; nf < 4; ++nf) {
                acc[mf][nf] = __builtin_amdgcn_mfma_f32_16x16x32_bf16(
                    ah[mf], bh[nf], acc[mf][nf], 0, 0, 0);
                acc[mf][nf] = __builtin_amdgcn_mfma_f32_16x16x32_bf16(
                    al[mf], bh[nf], acc[mf][nf], 0, 0, 0);
                acc[mf][nf] = __builtin_amdgcn_mfma_f32_16x16x32_bf16(
                    ah[mf], bl[nf], acc[mf][nf], 0, 0, 0);
            }
        __syncthreads();
    }
    const int er = (l >> 4) << 2, ec = l & 15;
    if (n0 < 1024) {
        u16 *oh, *olo; const float* bp; int ldc, nl;
        if (n0 < 768) { oh = Qh; olo = Ql; bp = bq; ldc = 768; nl = n0; }
        else          { oh = Kh; olo = Kl; bp = bk; ldc = KVD; nl = n0 - 768; }
#pragma unroll
        for (int mf = 0; mf < 4; ++mf)
#pragma unroll
            for (int i = 0; i < 4; ++i) {
                int row = m0 + wm * 64 + mf * 16 + er + i;
#pragma unroll
                for (int nf = 0; nf < 4; ++nf) {
                    int col = nl + wn * 64 + nf * 16 + ec;
                    float v = acc[mf][nf][i] + bp[col];
                    size_t idx = (size_t)row * ldc + col;
                    u16 h = f2bf(v);
                    oh[idx] = h;
                    olo[idx] = f2bf(v - bf2f(h));
                }
            }
    } else {
        int nl = n0 - 1024;
#pragma unroll
        for (int mf = 0; mf < 4; ++mf)
#pragma unroll
            for (int i = 0; i < 4; ++i) {
                int row = m0 + wm * 64 + mf * 16 + er + i;
#pragma unroll
                for (int nf = 0; nf < 4; ++nf) {
                    int col = nl + wn * 64 + nf * 16 + ec;
                    Vo[(size_t)row * KVD + col] = acc[mf][nf][i] + bv[col];
                }
            }
    }
}

// ---------------------------------------------------------------------------
// Split-precision MFMA NT GEMM with residual: C = A@W^T + resid.
// A pre-split hi/lo bf16 (gload_lds). Grid (6, 32).
// ---------------------------------------------------------------------------
__global__ __launch_bounds__(256)
void oproj_split(const u16* __restrict__ Ahg, const u16* __restrict__ Alg,
                 const u16* __restrict__ Wh, const u16* __restrict__ Wl,
                 const float* __restrict__ resid, float* __restrict__ C,
                 int M, int N, int K) {
    __shared__ __align__(16) u16 Ah[4096], Al[4096], Bh[4096], Bl[4096];
    const int tid = threadIdx.x, l = tid & 63, w = tid >> 6;
    const int wm = w & 1, wn = w >> 1;
    const int m0 = blockIdx.y << 7, n0 = blockIdx.x << 7;
    const int sr = l >> 2, sc8 = (l & 3) << 3;
    const u16* gAh0 = Ahg + (size_t)(m0 + w * 32 + sr) * K + sc8;
    const u16* gAh1 = gAh0 + (size_t)16 * K;
    const u16* gAl0 = Alg + (size_t)(m0 + w * 32 + sr) * K + sc8;
    const u16* gAl1 = gAl0 + (size_t)16 * K;
    const u16* gBh0 = Wh + (size_t)(n0 + w * 32 + sr) * K + sc8;
    const u16* gBh1 = gBh0 + (size_t)16 * K;
    const u16* gBl0 = Wl + (size_t)(n0 + w * 32 + sr) * K + sc8;
    const u16* gBl1 = gBl0 + (size_t)16 * K;
    u16* lAh0 = Ah + w * 1024; u16* lAh1 = lAh0 + 512;
    u16* lAl0 = Al + w * 1024; u16* lAl1 = lAl0 + 512;
    u16* lBh0 = Bh + w * 1024; u16* lBh1 = lBh0 + 512;
    u16* lBl0 = Bl + w * 1024; u16* lBl1 = lBl0 + 512;
    const int fr = l & 15, fc = (l >> 4) << 3;
    f32x4 acc[4][4];
#pragma unroll
    for (int i = 0; i < 4; ++i)
#pragma unroll
        for (int j = 0; j < 4; ++j) acc[i][j] = (f32x4){0.f, 0.f, 0.f, 0.f};
    for (int k0 = 0; k0 < K; k0 += 32) {
        gload16(gAh0 + k0, lAh0);
        gload16(gAh1 + k0, lAh1);
        gload16(gAl0 + k0, lAl0);
        gload16(gAl1 + k0, lAl1);
        gload16(gBh0 + k0, lBh0);
        gload16(gBh1 + k0, lBh1);
        gload16(gBl0 + k0, lBl0);
        gload16(gBl1 + k0, lBl1);
        __syncthreads();
        bf16x8 ah[4], al[4], bh[4], bl[4];
#pragma unroll
        for (int i = 0; i < 4; ++i) {
            ah[i] = *(const bf16x8*)(Ah + (wm * 64 + i * 16 + fr) * 32 + fc);
            al[i] = *(const bf16x8*)(Al + (wm * 64 + i * 16 + fr) * 32 + fc);
            bh[i] = *(const bf16x8*)(Bh + (wn * 64 + i * 16 + fr) * 32 + fc);
            bl[i] = *(const bf16x8*)(Bl + (wn * 64 + i * 16 + fr) * 32 + fc);
        }
#pragma unroll
        for (int mf = 0; mf < 4; ++mf)
#pragma unroll
            for (int nf = 0; nf < 4; ++nf) {
                acc[mf][nf] = __builtin_amdgcn_mfma_f32_16x16x32_bf16(
                    ah[mf], bh[nf], acc[mf][nf], 0, 0, 0);
                acc[mf][nf] = __builtin_amdgcn_mfma_f32_16x16x32_bf16(
                    al[mf], bh[nf], acc[mf][nf], 0, 0, 0);
                acc[mf][nf] = __builtin_amdgcn_mfma_f32_16x16x32_bf16(
                    ah[mf], bl[nf], acc[mf][nf], 0, 0, 0);
            }
        __syncthreads();
    }
    const int er = (l >> 4) << 2, ec = l & 15;
#pragma unroll
    for (int mf = 0; mf < 4; ++mf)
#pragma unroll
        for (int i = 0; i < 4; ++i) {
            int row = m0 + wm * 64 + mf * 16 + er + i;
#pragma unroll
            for (int nf = 0; nf < 4; ++nf) {
                int col = n0 + wn * 64 + nf * 16 + ec;
                C[(size_t)row * N + col] =
                    acc[mf][nf][i] + resid[(size_t)row * N + col];
            }
        }
}

// ---------------------------------------------------------------------------
// RoPE on hi/lo split q (12 heads) and k (4 heads) per token
// ---------------------------------------------------------------------------
__global__ __launch_bounds__(256)
void rope_split(u16* __restrict__ Qh, u16* __restrict__ Ql,
                u16* __restrict__ Kh, u16* __restrict__ Kl,
                const int* __restrict__ pos_ids) {
    const int t = blockIdx.x;
    const float pos = (float)pos_ids[t];
    const int tid = threadIdx.x;
#pragma unroll
    for (int it = 0; it < 2; ++it) {
        int p = tid + (it << 8);
        int head = p >> 5, i = p & 31;
        float invf = expf(-(float)i * 0.28782313662425572f); // ln(1e4)/32
        float ang = pos * invf;
        float c = cosf(ang), sn = sinf(ang);
        u16 *ah, *al;
        size_t bofs;
        if (head < NHEAD) { ah = Qh; al = Ql; bofs = (size_t)t * HID + head * HDIM; }
        else { ah = Kh; al = Kl; bofs = (size_t)t * KVD + (head - NHEAD) * HDIM; }
        float x1 = bf2f(ah[bofs + i]) + bf2f(al[bofs + i]);
        float x2 = bf2f(ah[bofs + i + 32]) + bf2f(al[bofs + i + 32]);
        float y1 = x1 * c - x2 * sn;
        float y2 = x2 * c + x1 * sn;
        u16 h1 = f2bf(y1);
        ah[bofs + i] = h1;
        al[bofs + i] = f2bf(y1 - bf2f(h1));
        u16 h2 = f2bf(y2);
        ah[bofs + i + 32] = h2;
        al[bofs + i + 32] = f2bf(y2 - bf2f(h2));
    }
}

// ---------------------------------------------------------------------------
// Self attention (causal GQA), split-precision MFMA, online softmax.
// ---------------------------------------------------------------------------
__global__ __launch_bounds__(256)
void attn_self_mfma(const u16* __restrict__ Qhg, const u16* __restrict__ Qlg,
                    const u16* __restrict__ Khg, const u16* __restrict__ Klg,
                    const float* __restrict__ V,
                    u16* __restrict__ Oh, u16* __restrict__ Ol) {
    const int qt = blockIdx.x, n = blockIdx.y, b = blockIdx.z;
    const int kv = n / REP;
    const int tid = threadIdx.x, l = tid & 63, w = tid >> 6;
    const int q0 = qt << 5;
    __shared__ __align__(16) u16 sQh[2048], sQl[2048];  // [32][64]
    __shared__ __align__(16) u16 sKh[4096], sKl[4096];  // [64][64]
    __shared__ __align__(16) u16 sVh[4096], sVl[4096];  // transposed [d][key]
    __shared__ float Ps[32][68];
    __shared__ float scal[32];

    {
        int row = tid >> 3, cg = (tid & 7) << 3;
        size_t gq = (size_t)(b * SEQ + q0 + row) * HID + n * HDIM + cg;
        *(u16x8*)(sQh + SW(row, cg)) = *(const u16x8*)(Qhg + gq);
        *(u16x8*)(sQl + SW(row, cg)) = *(const u16x8*)(Qlg + gq);
    }
    __syncthreads();

    const int fr = l & 15, fcg = (l >> 4) << 3;
    const int qf16 = (w & 1) << 4;
    const int fp2 = (w >> 1) << 1;
    bf16x8 qfh[2], qfl[2];
#pragma unroll
    for (int dc = 0; dc < 2; ++dc) {
        int off = SW(qf16 + fr, dc * 32 + fcg);
        qfh[dc] = *(const bf16x8*)(sQh + off);
        qfl[dc] = *(const bf16x8*)(sQl + off);
    }

    f32x4 o[2];
    o[0] = (f32x4){0.f, 0.f, 0.f, 0.f};
    o[1] = (f32x4){0.f, 0.f, 0.f, 0.f};
    float m_run = -3.4e38f, l_run = 0.f;
    const int sq = tid >> 3;
    const int skb = (tid & 7) << 3;
    const float scale = 0.125f;
    const int nt = (qt >> 1) + 1;

    for (int t = 0; t < nt; ++t) {
        __syncthreads();
        {
            int row = tid >> 2, cg = (tid & 3) << 4;
            size_t gk = (size_t)(b * SEQ + (t << 6) + row) * KVD + kv * HDIM + cg;
            *(u16x8*)(sKh + SW(row, cg))     = *(const u16x8*)(Khg + gk);
            *(u16x8*)(sKh + SW(row, cg + 8)) = *(const u16x8*)(Khg + gk + 8);
            *(u16x8*)(sKl + SW(row, cg))     = *(const u16x8*)(Klg + gk);
            *(u16x8*)(sKl + SW(row, cg + 8)) = *(const u16x8*)(Klg + gk + 8);
        }
        {
            int kp = (tid & 31) << 1, dc = (tid >> 5) << 3;
            const float* vg0 = V + (size_t)(b * SEQ + (t << 6) + kp) * KVD
                               + kv * HDIM + dc;
            const float* vg1 = vg0 + KVD;
            float4 a0 = *(const float4*)vg0;
            float4 a1 = *(const float4*)(vg0 + 4);
            float4 b0 = *(const float4*)vg1;
            float4 b1 = *(const float4*)(vg1 + 4);
            float va[8] = {a0.x, a0.y, a0.z, a0.w, a1.x, a1.y, a1.z, a1.w};
            float vb[8] = {b0.x, b0.y, b0.z, b0.w, b1.x, b1.y, b1.z, b1.w};
#pragma unroll
            for (int j = 0; j < 8; ++j) {
                u16 h0 = f2bf(va[j]);
                u16 h1 = f2bf(vb[j]);
                u16 p0 = f2bf(va[j] - bf2f(h0));
                u16 p1 = f2bf(vb[j] - bf2f(h1));
                int off = SW(dc + j, kp);
                *(unsigned*)(sVh + off) = (unsigned)h0 | ((unsigned)h1 << 16);
                *(unsigned*)(sVl + off) = (unsigned)p0 | ((unsigned)p1 << 16);
            }
        }
        __syncthreads();
#pragma unroll
        for (int kk = 0; kk < 2; ++kk) {
            int kf = fp2 + kk;
            bf16x8 kh[2], klv[2];
#pragma unroll
            for (int dc = 0; dc < 2; ++dc) {
                int off = SW(kf * 16 + fr, dc * 32 + fcg);
                kh[dc]  = *(const bf16x8*)(sKh + off);
                klv[dc] = *(const bf16x8*)(sKl + off);
            }
            f32x4 s = (f32x4){0.f, 0.f, 0.f, 0.f};
            s = __builtin_amdgcn_mfma_f32_16x16x32_bf16(qfh[0], kh[0], s, 0, 0, 0);
            s = __builtin_amdgcn_mfma_f32_16x16x32_bf16(qfh[1], kh[1], s, 0, 0, 0);
            s = __builtin_amdgcn_mfma_f32_16x16x32_bf16(qfl[0], kh[0], s, 0, 0, 0);
            s = __builtin_amdgcn_mfma_f32_16x16x32_bf16(qfl[1], kh[1], s, 0, 0, 0);
            s = __builtin_amdgcn_mfma_f32_16x16x32_bf16(qfh[0], klv[0], s, 0, 0, 0);
            s = __builtin_amdgcn_mfma_f32_16x16x32_bf16(qfh[1], klv[1], s, 0, 0, 0);
            int col = kf * 16 + fr;
            int key = (t << 6) + col;
#pragma unroll
            for (int r = 0; r < 4; ++r) {
                int qrow = qf16 + ((l >> 4) << 2) + r;
                Ps[qrow][col] = (key <= q0 + qrow) ? s[r] * scale : -1e9f;
            }
        }
        __syncthreads();
        {
            float4 s0 = *(const float4*)&Ps[sq][skb];
            float4 s1 = *(const float4*)&Ps[sq][skb + 4];
            float sv[8] = {s0.x, s0.y, s0.z, s0.w, s1.x, s1.y, s1.z, s1.w};
            float mx = sv[0];
#pragma unroll
            for (int j = 1; j < 8; ++j) mx = fmaxf(mx, sv[j]);
            for (int x = 1; x < 8; x <<= 1) mx = fmaxf(mx, __shfl_xor(mx, x));
            float mnew = fmaxf(m_run, mx);
            float corr = __expf(m_run - mnew);
            float lsum = 0.f;
#pragma unroll
            for (int j = 0; j < 8; ++j) {
                sv[j] = __expf(sv[j] - mnew);
                lsum += sv[j];
            }
            for (int x = 1; x < 8; x <<= 1) lsum += __shfl_xor(lsum, x);
            l_run = l_run * corr + lsum;
            m_run = mnew;
            *(float4*)&Ps[sq][skb]     = make_float4(sv[0], sv[1], sv[2], sv[3]);
            *(float4*)&Ps[sq][skb + 4] = make_float4(sv[4], sv[5], sv[6], sv[7]);
            if ((tid & 7) == 0) scal[sq] = corr;
        }
        __syncthreads();
        {
            float4 c4 = *(const float4*)&scal[qf16 + ((l >> 4) << 2)];
            float cr[4] = {c4.x, c4.y, c4.z, c4.w};
#pragma unroll
            for (int dfi = 0; dfi < 2; ++dfi)
#pragma unroll
                for (int r = 0; r < 4; ++r) o[dfi][r] *= cr[r];
            bf16x8 ph[2], pl[2];
#pragma unroll
            for (int kc = 0; kc < 2; ++kc) {
                float4 p0 = *(const float4*)&Ps[qf16 + fr][kc * 32 + fcg];
                float4 p1 = *(const float4*)&Ps[qf16 + fr][kc * 32 + fcg + 4];
                u16x8 hh, ll;
                cvt8(p0, p1, hh, ll);
                ph[kc] = *(bf16x8*)&hh;
                pl[kc] = *(bf16x8*)&ll;
            }
#pragma unroll
            for (int dfi = 0; dfi < 2; ++dfi) {
                int df = fp2 + dfi;
#pragma unroll
                for (int kc = 0; kc < 2; ++kc) {
                    int off = SW(df * 16 + fr, kc * 32 + fcg);
                    bf16x8 vh = *(const bf16x8*)(sVh + off);
                    bf16x8 vl = *(const bf16x8*)(sVl + off);
                    o[dfi] = __builtin_amdgcn_mfma_f32_16x16x32_bf16(
                        ph[kc], vh, o[dfi], 0, 0, 0);
                    o[dfi] = __builtin_amdgcn_mfma_f32_16x16x32_bf16(
                        pl[kc], vh, o[dfi], 0, 0, 0);
                    o[dfi] = __builtin_amdgcn_mfma_f32_16x16x32_bf16(
                        ph[kc], vl, o[dfi], 0, 0, 0);
                }
            }
        }
    }
    __syncthreads();
    if ((tid & 7) == 0) scal[sq] = 1.0f / l_run;
    __syncthreads();
    {
        int qrb = qf16 + ((l >> 4) << 2);
        float4 li4 = *(const float4*)&scal[qrb];
        float li[4] = {li4.x, li4.y, li4.z, li4.w};
#pragma unroll
        for (int dfi = 0; dfi < 2; ++dfi) {
            int df = fp2 + dfi;
            int col = n * HDIM + df * 16 + fr;
#pragma unroll
            for (int r = 0; r < 4; ++r) {
                int row = q0 + qrb + r;
                float val = o[dfi][r] * li[r];
                size_t oidx = (size_t)(b * SEQ + row) * HID + col;
                u16 h = f2bf(val);
                Oh[oidx] = h;
                Ol[oidx] = f2bf(val - bf2f(h));
            }
        }
    }
}

// ---------------------------------------------------------------------------
// Group attention: MHA across the 8 channels. One wave per (s, head).
// ---------------------------------------------------------------------------
__global__ __launch_bounds__(64)
void attn_group(const u16* __restrict__ Qh, const u16* __restrict__ Ql,
                const u16* __restrict__ Kh, const u16* __restrict__ Kl,
                const float* __restrict__ V, const float* __restrict__ gmask,
                u16* __restrict__ Oh, u16* __restrict__ Ol) {
    const int n = blockIdx.x % NHEAD;
    const int s = blockIdx.x / NHEAD;
    const int kv = n / REP;
    const int lane = threadIdx.x;
    __shared__ float Qs[8][65], Ks[8][65], Vs[8][65], Ps[64];
    for (int c = 0; c < 8; ++c) {
        size_t qi = (size_t)(c * SEQ + s) * HID + n * HDIM + lane;
        size_t ki = (size_t)(c * SEQ + s) * KVD + kv * HDIM + lane;
        Qs[c][lane] = bf2f(Qh[qi]) + bf2f(Ql[qi]);
        Ks[c][lane] = bf2f(Kh[ki]) + bf2f(Kl[ki]);
        Vs[c][lane] = V[ki];
    }
    __syncthreads();
    const int qb = lane >> 3, kb = lane & 7;
    float sc = 0;
    for (int d = 0; d < 64; ++d) sc += Qs[qb][d] * Ks[kb][d];
    sc = sc * 0.125f + gmask[(size_t)s * 64 + qb * 8 + kb];
    float m = sc;
    for (int x = 1; x < 8; x <<= 1) m = fmaxf(m, __shfl_xor(m, x));
    float p = __expf(sc - m);
    float l = p;
    for (int x = 1; x < 8; x <<= 1) l += __shfl_xor(l, x);
    Ps[lane] = p / l;
    __syncthreads();
    for (int q2 = 0; q2 < 8; ++q2) {
        float o = 0;
        for (int c = 0; c < 8; ++c) o += Ps[q2 * 8 + c] * Vs[c][lane];
        size_t oidx = (size_t)(q2 * SEQ + s) * HID + n * HDIM + lane;
        u16 h = f2bf(o);
        Oh[oidx] = h;
        Ol[oidx] = f2bf(o - bf2f(h));
    }
}

// ---------------------------------------------------------------------------
// MoE router (fp32)
// ---------------------------------------------------------------------------
__global__ __launch_bounds__(64)
void router_kernel(const float* __restrict__ X, const float* __restrict__ GW,
                   int* __restrict__ counts, int* __restrict__ topi,
                   float* __restrict__ topw, int* __restrict__ posb) {
    const int t = blockIdx.x;
    const int lane = threadIdx.x;
    const int e = lane >> 3, c = lane & 7;
    const float4* x4 = (const float4*)(X + (size_t)t * HID + c * 96);
    const float4* g4 = (const float4*)(GW + (size_t)e * HID + c * 96);
    float p = 0;
#pragma unroll
    for (int i = 0; i < 24; ++i) {
        float4 xv = x4[i], gv = g4[i];
        p += xv.x * gv.x + xv.y * gv.y + xv.z * gv.z + xv.w * gv.w;
    }
    p += __shfl_xor(p, 1);
    p += __shfl_xor(p, 2);
    p += __shfl_xor(p, 4);
    float lg[8];
#pragma unroll
    for (int i = 0; i < 8; ++i) lg[i] = __shfl(p, i * 8);
    float m = lg[0];
#pragma unroll
    for (int i = 1; i < 8; ++i) m = fmaxf(m, lg[i]);
    float s = 0;
#pragma unroll
    for (int i = 0; i < 8; ++i) { lg[i] = expf(lg[i] - m); s += lg[i]; }
    float inv = 1.0f / s;
    int i1 = 0; float b1 = lg[0];
#pragma unroll
    for (int i = 1; i < 8; ++i) if (lg[i] > b1) { b1 = lg[i]; i1 = i; }
    int i2 = -1; float b2 = -1.0f;
#pragma unroll
    for (int i = 0; i < 8; ++i)
        if (i != i1 && lg[i] > b2) { b2 = lg[i]; i2 = i; }
    if (lane == 0) {
        topi[t * 2] = i1; topi[t * 2 + 1] = i2;
        topw[t * 2] = b1 * inv; topw[t * 2 + 1] = b2 * inv;
        posb[t * 2] = atomicAdd(&counts[i1], 1);
        posb[t * 2 + 1] = atomicAdd(&counts[i2], 1);
    }
}

__global__ void scan_kernel(const int* __restrict__ counts, int* __restrict__ offsets) {
    int acc = 0;
    for (int e = 0; e < NEXP; ++e) { offsets[e] = acc; acc += counts[e]; }
}

__global__ __launch_bounds__(256)
void fill_slots(const int* __restrict__ topi, const float* __restrict__ topw,
                const int* __restrict__ posb, const int* __restrict__ offsets,
                int* __restrict__ slot_token, float* __restrict__ slot_w,
                int* __restrict__ token_slot) {
    int t = blockIdx.x * 256 + threadIdx.x;
    if (t >= NTOK) return;
#pragma unroll
    for (int k = 0; k < TOPK; ++k) {
        int e = topi[t * 2 + k];
        int sl = offsets[e] + posb[t * 2 + k];
        slot_token[sl] = t;
        slot_w[sl] = topw[t * 2 + k];
        token_slot[t * 2 + k] = sl;
    }
}

// ---------------------------------------------------------------------------
// MoE gate+up grouped GEMM, single-bf16 A, BK=64 as 2x32 sub-slices
// (half the barriers). LDS 48KB. Grid (n=12, m=32, e=8).
// ---------------------------------------------------------------------------
__global__ __launch_bounds__(256)
void moe_gate_up(const u16* __restrict__ Xb, const u16* __restrict__ Wg,
                 const u16* __restrict__ Wu,
                 const int* __restrict__ slot_token,
                 const int* __restrict__ counts,
                 const int* __restrict__ offsets, u16* __restrict__ H) {
    const int e = blockIdx.z;
    const int Ce = counts[e];
    const int m0 = blockIdx.y << 7;
    if (Ce == 0 || m0 >= Ce) return;
    const int n0 = blockIdx.x << 7;
    const int base = offsets[e];
    __shared__ __align__(16) u16 As[8192];   // [2][4096]
    __shared__ __align__(16) u16 Gs[8192];
    __shared__ __align__(16) u16 Us[8192];
    const int tid = threadIdx.x, l = tid & 63, w = tid >> 6;
    const int wm = w & 1, wn = w >> 1;
    const int sr = l >> 2, sc8 = (l & 3) << 3;
    int r0 = m0 + w * 32 + sr;
    int r1 = r0 + 16;
    int t0 = slot_token[base + min(r0, Ce - 1)];
    int t1 = slot_token[base + min(r1, Ce - 1)];
    const u16* gA0 = Xb + (size_t)t0 * HID + sc8;
    const u16* gA1 = Xb + (size_t)t1 * HID + sc8;
    const u16* Wge = Wg + (size_t)e * IEXP * HID;
    const u16* Wue = Wu + (size_t)e * IEXP * HID;
    const u16* gG0 = Wge + (size_t)(n0 + w * 32 + sr) * HID + sc8;
    const u16* gG1 = gG0 + 16 * HID;
    const u16* gU0 = Wue + (size_t)(n0 + w * 32 + sr) * HID + sc8;
    const u16* gU1 = gU0 + 16 * HID;
    u16* lA0 = As + w * 1024; u16* lA1 = lA0 + 512;
    u16* lG0 = Gs + w * 1024; u16* lG1 = lG0 + 512;
    u16* lU0 = Us + w * 1024; u16* lU1 = lU0 + 512;
    const int fr = l & 15, fc = (l >> 4) << 3;
    f32x4 accg[4][4], accu[4][4];
#pragma unroll
    for (int i = 0; i < 4; ++i)
#pragma unroll
        for (int j = 0; j < 4; ++j) {
            accg[i][j] = (f32x4){0.f, 0.f, 0.f, 0.f};
            accu[i][j] = (f32x4){0.f, 0.f, 0.f, 0.f};
        }
    for (int k0 = 0; k0 < HID; k0 += 64) {
        gload16(gA0 + k0, lA0);
        gload16(gA1 + k0, lA1);
        gload16(gG0 + k0, lG0);
        gload16(gG1 + k0, lG1);
        gload16(gU0 + k0, lU0);
        gload16(gU1 + k0, lU1);
        gload16(gA0 + k0 + 32, lA0 + 4096);
        gload16(gA1 + k0 + 32, lA1 + 4096);
        gload16(gG0 + k0 + 32, lG0 + 4096);
        gload16(gG1 + k0 + 32, lG1 + 4096);
        gload16(gU0 + k0 + 32, lU0 + 4096);
        gload16(gU1 + k0 + 32, lU1 + 4096);
        __syncthreads();
#pragma unroll
        for (int ks = 0; ks < 2; ++ks) {
            const u16* Ab = As + ks * 4096;
            const u16* Gb = Gs + ks * 4096;
            const u16* Ub = Us + ks * 4096;
            bf16x8 af[4], gf[4], uf[4];
#pragma unroll
            for (int i = 0; i < 4; ++i) {
                af[i] = *(const bf16x8*)(Ab + (wm * 64 + i * 16 + fr) * 32 + fc);
                gf[i] = *(const bf16x8*)(Gb + (wn * 64 + i * 16 + fr) * 32 + fc);
                uf[i] = *(const bf16x8*)(Ub + (wn * 64 + i * 16 + fr) * 32 + fc);
            }
#pragma unroll
            for (int mf = 0; mf < 4; ++mf)
#pragma unroll
                for (int nf = 0; nf < 4; ++nf) {
                    accg[mf][nf] = __builtin_amdgcn_mfma_f32_16x16x32_bf16(
                        af[mf], gf[nf], accg[mf][nf], 0, 0, 0);
                    accu[mf][nf] = __builtin_amdgcn_mfma_f32_16x16x32_bf16(
                        af[mf], uf[nf], accu[mf][nf], 0, 0, 0);
                }
        }
        __syncthreads();
    }
    const int er = (l >> 4) << 2, ec = l & 15;
#pragma unroll
    for (int mf = 0; mf < 4; ++mf)
#pragma unroll
        for (int i = 0; i < 4; ++i) {
            int row = m0 + wm * 64 + mf * 16 + er + i;
            if (row >= Ce) continue;
            size_t sl = (size_t)(base + row);
#pragma unroll
            for (int nf = 0; nf < 4; ++nf) {
                int col = n0 + wn * 64 + nf * 16 + ec;
                float g = accg[mf][nf][i];
                float u = accu[mf][nf][i];
                float h = g / (1.0f + __expf(-g)) * u;
                H[sl * IEXP + col] = f2bf(h);
            }
        }
}

// ---------------------------------------------------------------------------
// MoE down grouped GEMM bf16, BK=64 as 2x32 sub-slices. LDS 32KB.
// Grid (n=6, m=32, e=8).
// ---------------------------------------------------------------------------
__global__ __launch_bounds__(256)
void moe_down_bf16(const u16* __restrict__ Hb, const u16* __restrict__ Wd,
                   const float* __restrict__ slot_w,
                   const int* __restrict__ counts,
                   const int* __restrict__ offsets, float* __restrict__ D) {
    const int e = blockIdx.z;
    const int Ce = counts[e];
    const int m0 = blockIdx.y << 7;
    if (Ce == 0 || m0 >= Ce) return;
    const int n0 = blockIdx.x << 7;
    const int base = offsets[e];
    __shared__ __align__(16) u16 As[8192];   // [2][4096]
    __shared__ __align__(16) u16 Bs[8192];
    const int tid = threadIdx.x, l = tid & 63, w = tid >> 6;
    const int wm = w & 1, wn = w >> 1;
    const int sr = l >> 2, sc = (l & 3) << 3;
    const u16* Ae = Hb + (size_t)base * IEXP;
    int r0 = min(m0 + w * 32 + sr, Ce - 1);
    int r1 = min(m0 + w * 32 + 16 + sr, Ce - 1);
    const u16* gA0 = Ae + (size_t)r0 * IEXP + sc;
    const u16* gA1 = Ae + (size_t)r1 * IEXP + sc;
    const u16* Wde = Wd + (size_t)e * HID * IEXP;
    const u16* gB0 = Wde + (size_t)(n0 + w * 32 + sr) * IEXP + sc;
    const u16* gB1 = gB0 + 16 * IEXP;
    u16* lA0 = As + w * 1024; u16* lA1 = lA0 + 512;
    u16* lB0 = Bs + w * 1024; u16* lB1 = lB0 + 512;
    const int fr = l & 15, fc = (l >> 4) << 3;
    f32x4 acc[4][4];
#pragma unroll
    for (int i = 0; i < 4; ++i)
#pragma unroll
        for (int j = 0; j < 4; ++j) acc[i][j] = (f32x4){0.f, 0.f, 0.f, 0.f};
    for (int k0 = 0; k0 < IEXP; k0 += 64) {
        gload16(gA0 + k0, lA0);
        gload16(gA1 + k0, lA1);
        gload16(gB0 + k0, lB0);
        gload16(gB1 + k0, lB1);
        gload16(gA0 + k0 + 32, lA0 + 4096);
        gload16(gA1 + k0 + 32, lA1 + 4096);
        gload16(gB0 + k0 + 32, lB0 + 4096);
        gload16(gB1 + k0 + 32, lB1 + 4096);
        __syncthreads();
#pragma unroll
        for (int ks = 0; ks < 2; ++ks) {
            const u16* Ab = As + ks * 4096;
            const u16* Bb = Bs + ks * 4096;
            bf16x8 af[4], bfv[4];
#pragma unroll
            for (int i = 0; i < 4; ++i) {
                af[i]  = *(const bf16x8*)(Ab + (wm * 64 + i * 16 + fr) * 32 + fc);
                bfv[i] = *(const bf16x8*)(Bb + (wn * 64 + i * 16 + fr) * 32 + fc);
            }
#pragma unroll
            for (int mf = 0; mf < 4; ++mf)
#pragma unroll
                for (int nf = 0; nf < 4; ++nf)
                    acc[mf][nf] = __builtin_amdgcn_mfma_f32_16x16x32_bf16(
                        af[mf], bfv[nf], acc[mf][nf], 0, 0, 0);
        }
        __syncthreads();
    }
    const int er = (l >> 4) << 2, ec = l & 15;
#pragma unroll
    for (int mf = 0; mf < 4; ++mf)
#pragma unroll
        for (int i = 0; i < 4; ++i) {
            int row = m0 + wm * 64 + mf * 16 + er + i;
            if (row >= Ce) continue;
            size_t sl = (size_t)(base + row);
            float sw = slot_w[sl];
#pragma unroll
            for (int nf = 0; nf < 4; ++nf) {
                int col = n0 + wn * 64 + nf * 16 + ec;
                D[sl * HID + col] = acc[mf][nf][i] * sw;
            }
        }
}

__global__ __launch_bounds__(256)
void moe_add(float* __restrict__ out, const float* __restrict__ D,
             const int* __restrict__ token_slot) {
    const int t = blockIdx.y;
    const int h = blockIdx.x * 256 + threadIdx.x;
    int s0 = token_slot[t * 2], s1 = token_slot[t * 2 + 1];
    out[(size_t)t * HID + h] += D[(size_t)s0 * HID + h] + D[(size_t)s1 * HID + h];
}

// ---------------------------------------------------------------------------
extern "C" void kernel_launch(void* const* d_in, const int* in_sizes, int n_in,
                              void* d_out, int out_size, void* d_ws, size_t ws_size,
                              hipStream_t stream) {
    const float* hidden = (const float*)d_in[0];
    const float* amask  = (const float*)d_in[1];
    const float* gmask  = (const float*)d_in[2];
    const int*   posids = (const int*)d_in[3];
    const float* ln1 = (const float*)d_in[4];
    const float* ln2 = (const float*)d_in[5];
    const float* ln3 = (const float*)d_in[6];
    const float* sqw = (const float*)d_in[7];  const float* sqb = (const float*)d_in[8];
    const float* skw = (const float*)d_in[9];  const float* skb = (const float*)d_in[10];
    const float* svw = (const float*)d_in[11]; const float* svb = (const float*)d_in[12];
    const float* sow = (const float*)d_in[13];
    const float* gqw = (const float*)d_in[14]; const float* gqb = (const float*)d_in[15];
    const float* gkw = (const float*)d_in[16]; const float* gkb = (const float*)d_in[17];
    const float* gvw = (const float*)d_in[18]; const float* gvb = (const float*)d_in[19];
    const float* gow = (const float*)d_in[20];
    const float* gatew = (const float*)d_in[21];
    const float* wg = (const float*)d_in[22];
    const float* wu = (const float*)d_in[23];
    const float* wd = (const float*)d_in[24];
    float* out = (float*)d_out;
    (void)amask;

    // ---- workspace carve (byte offsets), ~121.8 MB ----
    char* base = (char*)d_ws;
    u16* xh   = (u16*)(base + 0);           //  6,291,456
    u16* xl   = (u16*)(base + 6291456);     //  -> 12,582,912
    u16* qh   = (u16*)(base + 12582912);    //  -> 18,874,368
    u16* ql   = (u16*)(base + 18874368);    //  -> 25,165,824
    u16* kh   = (u16*)(base + 25165824);    //  -> 27,262,976
    u16* kl   = (u16*)(base + 27262976);    //  -> 29,360,128
    float* vbuf = (float*)(base + 29360128);//  -> 33,554,432
    u16* oh   = (u16*)(base + 33554432);    //  -> 39,845,888
    u16* ol   = (u16*)(base + 39845888);    //  -> 46,137,344
    u16* wqkv_sh = (u16*)(base + 46137344);
    u16* wqkv_sl = (u16*)(base + 48103424);
    u16* wo_sh   = (u16*)(base + 50069504);
    u16* wo_sl   = (u16*)(base + 51249152);
    u16* wqkv_gh = (u16*)(base + 52428800);
    u16* wqkv_gl = (u16*)(base + 54394880);
    u16* wo_gh   = (u16*)(base + 56360960);
    u16* wo_gl   = (u16*)(base + 57540608); //  -> 58,720,256
    u16* wgt = (u16*)(base + 58720256);     //  -> 77,594,624
    u16* wut = (u16*)(base + 77594624);     //  -> 96,468,992
    u16* wdt = (u16*)(base + 96468992);     //  -> 115,343,360
    float* slotw = (float*)(base + 115343360);
    float* topw  = (float*)(base + 115376128);
    int* counts  = (int*)(base + 115408896);
    int* offsets = (int*)(base + 115409024);
    int* topi    = (int*)(base + 115409408);
    int* posb    = (int*)(base + 115442176);
    int* slot_token = (int*)(base + 115474944);
    int* token_slot = (int*)(base + 115507712);
    u16* xbf = (u16*)(base + 115540480);    //  -> 121,831,936
    // MoE-phase overlays (attention activations + attn weights dead by then):
    float* xb   = (float*)(base + 0);        // 12,582,912 over xh/xl
    u16*   Hbuf = (u16*)(base + 12582912);   // 25,165,824 over qh..vbuf+oh head
    float* Dbuf = (float*)(base + 37748736); // 25,165,824 over ol+attnW+wgt head

    // ---- weight prep ----
    cvt_split8<<<3072, 256, 0, stream>>>(sqw, skw, svw, sow, gqw, gkw, gvw, gow,
                                         wqkv_sh, wqkv_sl, wo_sh, wo_sl,
                                         wqkv_gh, wqkv_gl, wo_gh, wo_gl);
    transpose_cvt<<<dim3(48, 24, 8), dim3(32, 8), 0, stream>>>(wg, wgt, HID, IEXP);
    transpose_cvt<<<dim3(48, 24, 8), dim3(32, 8), 0, stream>>>(wu, wut, HID, IEXP);
    transpose_cvt<<<dim3(24, 48, 8), dim3(32, 8), 0, stream>>>(wd, wdt, IEXP, HID);

    // ---- self attention ----
    rmsnorm_split<<<NTOK, 256, 0, stream>>>(hidden, ln1, xh, xl);
    qkv_split<<<dim3(10, 32), 256, 0, stream>>>(xh, xl, wqkv_sh, wqkv_sl,
                                                sqb, skb, svb,
                                                qh, ql, kh, kl, vbuf);
    rope_split<<<NTOK, 256, 0, stream>>>(qh, ql, kh, kl, posids);
    attn_self_mfma<<<dim3(SEQ / 32, NHEAD, BATCH), 256, 0, stream>>>(
        qh, ql, kh, kl, vbuf, oh, ol);
    oproj_split<<<dim3(6, 32), 256, 0, stream>>>(oh, ol, wo_sh, wo_sl,
                                                 hidden, out, NTOK, HID, HID);

    // ---- group attention ----
    rmsnorm_split<<<NTOK, 256, 0, stream>>>(out, ln2, xh, xl);
    qkv_split<<<dim3(10, 32), 256, 0, stream>>>(xh, xl, wqkv_gh, wqkv_gl,
                                                gqb, gkb, gvb,
                                                qh, ql, kh, kl, vbuf);
    attn_group<<<SEQ * NHEAD, 64, 0, stream>>>(qh, ql, kh, kl, vbuf, gmask,
                                               oh, ol);
    oproj_split<<<dim3(6, 32), 256, 0, stream>>>(oh, ol, wo_gh, wo_gl,
                                                 out, out, NTOK, HID, HID);

    // ---- MoE (bf16 MFMA: post-router, flip-free; R6 grid, BK=64) ----
    rmsnorm_kernel<<<NTOK, 256, 0, stream>>>(out, ln3, xb, xbf);
    hipMemsetAsync(counts, 0, 8 * sizeof(int), stream);
    router_kernel<<<NTOK, 64, 0, stream>>>(xb, gatew, counts, topi, topw, posb);
    scan_kernel<<<1, 1, 0, stream>>>(counts, offsets);
    fill_slots<<<16, 256, 0, stream>>>(topi, topw, posb, offsets,
                                       slot_token, slotw, token_slot);
    moe_gate_up<<<dim3(12, 32, 8), 256, 0, stream>>>(
        xbf, wgt, wut, slot_token, counts, offsets, Hbuf);
    moe_down_bf16<<<dim3(6, 32, 8), 256, 0, stream>>>(
        Hbuf, wdt, slotw, counts, offsets, Dbuf);
    moe_add<<<dim3(3, NTOK), 256, 0, stream>>>(out, Dbuf, token_slot);
}

// Round 12
// 560.360 us; speedup vs baseline: 1.5560x; 1.0086x over previous
//
#include <hip/hip_runtime.h>
#include <math.h>

// Problem constants
#define BATCH 8
#define SEQ 512
#define HID 768
#define NHEAD 12
#define KVHEAD 4
#define HDIM 64
#define NEXP 8
#define TOPK 2
#define IEXP 1536
#define NTOK (BATCH * SEQ)     // 4096
#define NSLOT (NTOK * TOPK)    // 8192
#define REP (NHEAD / KVHEAD)   // 3
#define KVD (KVHEAD * HDIM)    // 256

typedef unsigned short u16;
typedef float f32x4 __attribute__((ext_vector_type(4)));
typedef __bf16 bf16x8 __attribute__((ext_vector_type(8)));
typedef unsigned short u16x8 __attribute__((ext_vector_type(8)));

__device__ __forceinline__ u16 f2bf(float f) {
    unsigned u = __float_as_uint(f);
    u += 0x7fffu + ((u >> 16) & 1u);   // RNE
    return (u16)(u >> 16);
}
__device__ __forceinline__ float bf2f(u16 h) {
    return __uint_as_float(((unsigned)h) << 16);
}

__device__ __forceinline__ void gload16(const void* g, void* l) {
    __builtin_amdgcn_global_load_lds(
        (const __attribute__((address_space(1))) void*)g,
        (__attribute__((address_space(3))) void*)l, 16, 0, 0);
}

// split 8 fp32 -> hi/lo bf16
__device__ __forceinline__ void cvt8(float4 a, float4 b, u16x8& hi, u16x8& lo) {
    float x[8] = {a.x, a.y, a.z, a.w, b.x, b.y, b.z, b.w};
#pragma unroll
    for (int i = 0; i < 8; ++i) {
        u16 h = f2bf(x[i]);
        hi[i] = h;
        lo[i] = f2bf(x[i] - bf2f(h));
    }
}

// swizzled element offset in a row-major [R][64] bf16 LDS tile (stride 128B)
#define SW(row, col) (((row) << 6) + ((col) ^ (((row) & 7) << 3)))

// ---------------------------------------------------------------------------
// All 8 attention weight tensors: fp32 -> hi/lo bf16 split, one launch.
// ---------------------------------------------------------------------------
__global__ __launch_bounds__(256)
void cvt_split8(const float* __restrict__ sq, const float* __restrict__ sk,
                const float* __restrict__ sv, const float* __restrict__ so,
                const float* __restrict__ gq, const float* __restrict__ gk,
                const float* __restrict__ gv, const float* __restrict__ go,
                u16* __restrict__ wqs_h, u16* __restrict__ wqs_l,
                u16* __restrict__ wos_h, u16* __restrict__ wos_l,
                u16* __restrict__ wqg_h, u16* __restrict__ wqg_l,
                u16* __restrict__ wog_h, u16* __restrict__ wog_l) {
    int i4 = (blockIdx.x * 256 + threadIdx.x) * 4;
    const float* src;
    u16 *dh, *dl;
    int s;
    if (i4 < 983040) {
        dh = wqs_h; dl = wqs_l;
        if (i4 < 589824)      { src = sq; s = i4; }
        else if (i4 < 786432) { src = sk; s = i4 - 589824; dh += 589824; dl += 589824; }
        else                  { src = sv; s = i4 - 786432; dh += 786432; dl += 786432; }
    } else if (i4 < 1572864) {
        src = so; s = i4 - 983040; dh = wos_h; dl = wos_l;
    } else if (i4 < 2555904) {
        int j = i4 - 1572864;
        dh = wqg_h; dl = wqg_l;
        if (j < 589824)      { src = gq; s = j; }
        else if (j < 786432) { src = gk; s = j - 589824; dh += 589824; dl += 589824; }
        else                 { src = gv; s = j - 786432; dh += 786432; dl += 786432; }
    } else {
        src = go; s = i4 - 2555904; dh = wog_h; dl = wog_l;
    }
    float4 v = *(const float4*)(src + s);
    float a[4] = {v.x, v.y, v.z, v.w};
    ushort4 h, lo;
    u16 t;
    t = f2bf(a[0]); h.x = t; lo.x = f2bf(a[0] - bf2f(t));
    t = f2bf(a[1]); h.y = t; lo.y = f2bf(a[1] - bf2f(t));
    t = f2bf(a[2]); h.z = t; lo.z = f2bf(a[2] - bf2f(t));
    t = f2bf(a[3]); h.w = t; lo.w = f2bf(a[3] - bf2f(t));
    *(ushort4*)(dh + s) = h;
    *(ushort4*)(dl + s) = lo;
}

// ---------------------------------------------------------------------------
// per-expert transpose + convert: src[e][R][C] fp32 -> dst[e][C][R] bf16
// ---------------------------------------------------------------------------
__global__ __launch_bounds__(256)
void transpose_cvt(const float* __restrict__ src, u16* __restrict__ dst,
                   int R, int C) {
    const int e = blockIdx.z;
    src += (size_t)e * R * C;
    dst += (size_t)e * R * C;
    __shared__ float t[32][33];
    const int c0 = blockIdx.x << 5, r0 = blockIdx.y << 5;
    const int tx = threadIdx.x, ty = threadIdx.y;
#pragma unroll
    for (int i = 0; i < 4; ++i)
        t[ty * 4 + i][tx] = src[(size_t)(r0 + ty * 4 + i) * C + c0 + tx];
    __syncthreads();
#pragma unroll
    for (int i = 0; i < 4; ++i)
        dst[(size_t)(c0 + ty * 4 + i) * R + r0 + tx] = f2bf(t[tx][ty * 4 + i]);
}

// ---------------------------------------------------------------------------
// RMSNorm variant 1: hi/lo bf16 out (attention paths)
// ---------------------------------------------------------------------------
__global__ __launch_bounds__(256)
void rmsnorm_split(const float* __restrict__ X, const float* __restrict__ W,
                   u16* __restrict__ Yh, u16* __restrict__ Yl) {
    const int t = blockIdx.x;
    const int tid = threadIdx.x;
    const float* x = X + (size_t)t * HID;
    float x0 = x[tid], x1 = x[tid + 256], x2 = x[tid + 512];
    float ss = x0 * x0 + x1 * x1 + x2 * x2;
    for (int m = 1; m < 64; m <<= 1) ss += __shfl_xor(ss, m);
    __shared__ float red[4];
    if ((tid & 63) == 0) red[tid >> 6] = ss;
    __syncthreads();
    float tot = red[0] + red[1] + red[2] + red[3];
    float inv = rsqrtf(tot * (1.0f / HID) + 1e-6f);
    u16* yh = Yh + (size_t)t * HID;
    u16* yl = Yl + (size_t)t * HID;
#pragma unroll
    for (int j = 0; j < 3; ++j) {
        int idx = tid + j * 256;
        float r = x[idx] * inv * W[idx];
        u16 h = f2bf(r);
        yh[idx] = h;
        yl[idx] = f2bf(r - bf2f(h));
    }
}

// ---------------------------------------------------------------------------
// RMSNorm variant 2: fp32 + single bf16 out (MoE path: router + experts)
// ---------------------------------------------------------------------------
__global__ __launch_bounds__(256)
void rmsnorm_kernel(const float* __restrict__ X, const float* __restrict__ W,
                    float* __restrict__ Y, u16* __restrict__ Ybf) {
    const int t = blockIdx.x;
    const int tid = threadIdx.x;
    const float* x = X + (size_t)t * HID;
    float x0 = x[tid], x1 = x[tid + 256], x2 = x[tid + 512];
    float ss = x0 * x0 + x1 * x1 + x2 * x2;
    for (int m = 1; m < 64; m <<= 1) ss += __shfl_xor(ss, m);
    __shared__ float red[4];
    if ((tid & 63) == 0) red[tid >> 6] = ss;
    __syncthreads();
    float tot = red[0] + red[1] + red[2] + red[3];
    float inv = rsqrtf(tot * (1.0f / HID) + 1e-6f);
    float r0 = x0 * inv * W[tid];
    float r1 = x1 * inv * W[tid + 256];
    float r2 = x2 * inv * W[tid + 512];
    float* y = Y + (size_t)t * HID;
    y[tid] = r0; y[tid + 256] = r1; y[tid + 512] = r2;
    u16* yb = Ybf + (size_t)t * HID;
    yb[tid] = f2bf(r0); yb[tid + 256] = f2bf(r1); yb[tid + 512] = f2bf(r2);
}

// ---------------------------------------------------------------------------
// Split-precision MFMA NT GEMM for QKV. A pre-split hi/lo bf16 (gload_lds),
// Wh/Wl bf16 [1280][768]. Q,K out hi/lo bf16; V out fp32. Grid (10, 32).
// ---------------------------------------------------------------------------
__global__ __launch_bounds__(256)
void qkv_split(const u16* __restrict__ Xh, const u16* __restrict__ Xl,
               const u16* __restrict__ Wh, const u16* __restrict__ Wl,
               const float* __restrict__ bq, const float* __restrict__ bk,
               const float* __restrict__ bv,
               u16* __restrict__ Qh, u16* __restrict__ Ql,
               u16* __restrict__ Kh, u16* __restrict__ Kl,
               float* __restrict__ Vo) {
    __shared__ __align__(16) u16 Ah[4096], Al[4096], Bh[4096], Bl[4096];
    const int tid = threadIdx.x, l = tid & 63, w = tid >> 6;
    const int wm = w & 1, wn = w >> 1;
    const int m0 = blockIdx.y << 7, n0 = blockIdx.x << 7;
    const int sr = l >> 2, sc8 = (l & 3) << 3;
    const u16* gAh0 = Xh + (size_t)(m0 + w * 32 + sr) * HID + sc8;
    const u16* gAh1 = gAh0 + 16 * HID;
    const u16* gAl0 = Xl + (size_t)(m0 + w * 32 + sr) * HID + sc8;
    const u16* gAl1 = gAl0 + 16 * HID;
    const u16* gBh0 = Wh + (size_t)(n0 + w * 32 + sr) * HID + sc8;
    const u16* gBh1 = gBh0 + 16 * HID;
    const u16* gBl0 = Wl + (size_t)(n0 + w * 32 + sr) * HID + sc8;
    const u16* gBl1 = gBl0 + 16 * HID;
    u16* lAh0 = Ah + w * 1024; u16* lAh1 = lAh0 + 512;
    u16* lAl0 = Al + w * 1024; u16* lAl1 = lAl0 + 512;
    u16* lBh0 = Bh + w * 1024; u16* lBh1 = lBh0 + 512;
    u16* lBl0 = Bl + w * 1024; u16* lBl1 = lBl0 + 512;
    const int fr = l & 15, fc = (l >> 4) << 3;
    f32x4 acc[4][4];
#pragma unroll
    for (int i = 0; i < 4; ++i)
#pragma unroll
        for (int j = 0; j < 4; ++j) acc[i][j] = (f32x4){0.f, 0.f, 0.f, 0.f};
    for (int k0 = 0; k0 < HID; k0 += 32) {
        gload16(gAh0 + k0, lAh0);
        gload16(gAh1 + k0, lAh1);
        gload16(gAl0 + k0, lAl0);
        gload16(gAl1 + k0, lAl1);
        gload16(gBh0 + k0, lBh0);
        gload16(gBh1 + k0, lBh1);
        gload16(gBl0 + k0, lBl0);
        gload16(gBl1 + k0, lBl1);
        __syncthreads();
        bf16x8 ah[4], al[4], bh[4], bl[4];
#pragma unroll
        for (int i = 0; i < 4; ++i) {
            ah[i] = *(const bf16x8*)(Ah + (wm * 64 + i * 16 + fr) * 32 + fc);
            al[i] = *(const bf16x8*)(Al + (wm * 64 + i * 16 + fr) * 32 + fc);
            bh[i] = *(const bf16x8*)(Bh + (wn * 64 + i * 16 + fr) * 32 + fc);
            bl[i] = *(const bf16x8*)(Bl + (wn * 64 + i * 16 + fr) * 32 + fc);
        }
#pragma unroll
        for (int mf = 0; mf < 4; ++mf)
#pragma unroll
            for (int nf = 0; nf < 4; ++nf) {
                acc[mf][nf] = __builtin_amdgcn_mfma_f32_16x16x32_bf16(
                    ah[mf], bh[nf], acc[mf][nf], 0, 0, 0);
                acc[mf][nf] = __builtin_amdgcn_mfma_f32_16x16x32_bf16(
                    al[mf], bh[nf], acc[mf][nf], 0, 0, 0);
                acc[mf][nf] = __builtin_amdgcn_mfma_f32_16x16x32_bf16(
                    ah[mf], bl[nf], acc[mf][nf], 0, 0, 0);
            }
        __syncthreads();
    }
    const int er = (l >> 4) << 2, ec = l & 15;
    if (n0 < 1024) {
        u16 *oh, *olo; const float* bp; int ldc, nl;
        if (n0 < 768) { oh = Qh; olo = Ql; bp = bq; ldc = 768; nl = n0; }
        else          { oh = Kh; olo = Kl; bp = bk; ldc = KVD; nl = n0 - 768; }
#pragma unroll
        for (int mf = 0; mf < 4; ++mf)
#pragma unroll
            for (int i = 0; i < 4; ++i) {
                int row = m0 + wm * 64 + mf * 16 + er + i;
#pragma unroll
                for (int nf = 0; nf < 4; ++nf) {
                    int col = nl + wn * 64 + nf * 16 + ec;
                    float v = acc[mf][nf][i] + bp[col];
                    size_t idx = (size_t)row * ldc + col;
                    u16 h = f2bf(v);
                    oh[idx] = h;
                    olo[idx] = f2bf(v - bf2f(h));
                }
            }
    } else {
        int nl = n0 - 1024;
#pragma unroll
        for (int mf = 0; mf < 4; ++mf)
#pragma unroll
            for (int i = 0; i < 4; ++i) {
                int row = m0 + wm * 64 + mf * 16 + er + i;
#pragma unroll
                for (int nf = 0; nf < 4; ++nf) {
                    int col = nl + wn * 64 + nf * 16 + ec;
                    Vo[(size_t)row * KVD + col] = acc[mf][nf][i] + bv[col];
                }
            }
    }
}

// ---------------------------------------------------------------------------
// Split-precision MFMA NT GEMM with residual: C = A@W^T + resid.
// ---------------------------------------------------------------------------
__global__ __launch_bounds__(256)
void oproj_split(const u16* __restrict__ Ahg, const u16* __restrict__ Alg,
                 const u16* __restrict__ Wh, const u16* __restrict__ Wl,
                 const float* __restrict__ resid, float* __restrict__ C,
                 int M, int N, int K) {
    __shared__ __align__(16) u16 Ah[4096], Al[4096], Bh[4096], Bl[4096];
    const int tid = threadIdx.x, l = tid & 63, w = tid >> 6;
    const int wm = w & 1, wn = w >> 1;
    const int m0 = blockIdx.y << 7, n0 = blockIdx.x << 7;
    const int sr = l >> 2, sc8 = (l & 3) << 3;
    const u16* gAh0 = Ahg + (size_t)(m0 + w * 32 + sr) * K + sc8;
    const u16* gAh1 = gAh0 + (size_t)16 * K;
    const u16* gAl0 = Alg + (size_t)(m0 + w * 32 + sr) * K + sc8;
    const u16* gAl1 = gAl0 + (size_t)16 * K;
    const u16* gBh0 = Wh + (size_t)(n0 + w * 32 + sr) * K + sc8;
    const u16* gBh1 = gBh0 + (size_t)16 * K;
    const u16* gBl0 = Wl + (size_t)(n0 + w * 32 + sr) * K + sc8;
    const u16* gBl1 = gBl0 + (size_t)16 * K;
    u16* lAh0 = Ah + w * 1024; u16* lAh1 = lAh0 + 512;
    u16* lAl0 = Al + w * 1024; u16* lAl1 = lAl0 + 512;
    u16* lBh0 = Bh + w * 1024; u16* lBh1 = lBh0 + 512;
    u16* lBl0 = Bl + w * 1024; u16* lBl1 = lBl0 + 512;
    const int fr = l & 15, fc = (l >> 4) << 3;
    f32x4 acc[4][4];
#pragma unroll
    for (int i = 0; i < 4; ++i)
#pragma unroll
        for (int j = 0; j < 4; ++j) acc[i][j] = (f32x4){0.f, 0.f, 0.f, 0.f};
    for (int k0 = 0; k0 < K; k0 += 32) {
        gload16(gAh0 + k0, lAh0);
        gload16(gAh1 + k0, lAh1);
        gload16(gAl0 + k0, lAl0);
        gload16(gAl1 + k0, lAl1);
        gload16(gBh0 + k0, lBh0);
        gload16(gBh1 + k0, lBh1);
        gload16(gBl0 + k0, lBl0);
        gload16(gBl1 + k0, lBl1);
        __syncthreads();
        bf16x8 ah[4], al[4], bh[4], bl[4];
#pragma unroll
        for (int i = 0; i < 4; ++i) {
            ah[i] = *(const bf16x8*)(Ah + (wm * 64 + i * 16 + fr) * 32 + fc);
            al[i] = *(const bf16x8*)(Al + (wm * 64 + i * 16 + fr) * 32 + fc);
            bh[i] = *(const bf16x8*)(Bh + (wn * 64 + i * 16 + fr) * 32 + fc);
            bl[i] = *(const bf16x8*)(Bl + (wn * 64 + i * 16 + fr) * 32 + fc);
        }
#pragma unroll
        for (int mf = 0; mf < 4; ++mf)
#pragma unroll
            for (int nf = 0; nf < 4; ++nf) {
                acc[mf][nf] = __builtin_amdgcn_mfma_f32_16x16x32_bf16(
                    ah[mf], bh[nf], acc[mf][nf], 0, 0, 0);
                acc[mf][nf] = __builtin_amdgcn_mfma_f32_16x16x32_bf16(
                    al[mf], bh[nf], acc[mf][nf], 0, 0, 0);
                acc[mf][nf] = __builtin_amdgcn_mfma_f32_16x16x32_bf16(
                    ah[mf], bl[nf], acc[mf][nf], 0, 0, 0);
            }
        __syncthreads();
    }
    const int er = (l >> 4) << 2, ec = l & 15;
#pragma unroll
    for (int mf = 0; mf < 4; ++mf)
#pragma unroll
        for (int i = 0; i < 4; ++i) {
            int row = m0 + wm * 64 + mf * 16 + er + i;
#pragma unroll
            for (int nf = 0; nf < 4; ++nf) {
                int col = n0 + wn * 64 + nf * 16 + ec;
                C[(size_t)row * N + col] =
                    acc[mf][nf][i] + resid[(size_t)row * N + col];
            }
        }
}

// ---------------------------------------------------------------------------
// RoPE on hi/lo split q (12 heads) and k (4 heads) per token
// ---------------------------------------------------------------------------
__global__ __launch_bounds__(256)
void rope_split(u16* __restrict__ Qh, u16* __restrict__ Ql,
                u16* __restrict__ Kh, u16* __restrict__ Kl,
                const int* __restrict__ pos_ids) {
    const int t = blockIdx.x;
    const float pos = (float)pos_ids[t];
    const int tid = threadIdx.x;
#pragma unroll
    for (int it = 0; it < 2; ++it) {
        int p = tid + (it << 8);
        int head = p >> 5, i = p & 31;
        float invf = expf(-(float)i * 0.28782313662425572f); // ln(1e4)/32
        float ang = pos * invf;
        float c = cosf(ang), sn = sinf(ang);
        u16 *ah, *al;
        size_t bofs;
        if (head < NHEAD) { ah = Qh; al = Ql; bofs = (size_t)t * HID + head * HDIM; }
        else { ah = Kh; al = Kl; bofs = (size_t)t * KVD + (head - NHEAD) * HDIM; }
        float x1 = bf2f(ah[bofs + i]) + bf2f(al[bofs + i]);
        float x2 = bf2f(ah[bofs + i + 32]) + bf2f(al[bofs + i + 32]);
        float y1 = x1 * c - x2 * sn;
        float y2 = x2 * c + x1 * sn;
        u16 h1 = f2bf(y1);
        ah[bofs + i] = h1;
        al[bofs + i] = f2bf(y1 - bf2f(h1));
        u16 h2 = f2bf(y2);
        ah[bofs + i + 32] = h2;
        al[bofs + i + 32] = f2bf(y2 - bf2f(h2));
    }
}

// ---------------------------------------------------------------------------
// Self attention (causal GQA), split-precision MFMA, online softmax.
// ---------------------------------------------------------------------------
__global__ __launch_bounds__(256)
void attn_self_mfma(const u16* __restrict__ Qhg, const u16* __restrict__ Qlg,
                    const u16* __restrict__ Khg, const u16* __restrict__ Klg,
                    const float* __restrict__ V,
                    u16* __restrict__ Oh, u16* __restrict__ Ol) {
    const int qt = blockIdx.x, n = blockIdx.y, b = blockIdx.z;
    const int kv = n / REP;
    const int tid = threadIdx.x, l = tid & 63, w = tid >> 6;
    const int q0 = qt << 5;
    __shared__ __align__(16) u16 sQh[2048], sQl[2048];  // [32][64]
    __shared__ __align__(16) u16 sKh[4096], sKl[4096];  // [64][64]
    __shared__ __align__(16) u16 sVh[4096], sVl[4096];  // transposed [d][key]
    __shared__ float Ps[32][68];
    __shared__ float scal[32];

    {
        int row = tid >> 3, cg = (tid & 7) << 3;
        size_t gq = (size_t)(b * SEQ + q0 + row) * HID + n * HDIM + cg;
        *(u16x8*)(sQh + SW(row, cg)) = *(const u16x8*)(Qhg + gq);
        *(u16x8*)(sQl + SW(row, cg)) = *(const u16x8*)(Qlg + gq);
    }
    __syncthreads();

    const int fr = l & 15, fcg = (l >> 4) << 3;
    const int qf16 = (w & 1) << 4;
    const int fp2 = (w >> 1) << 1;
    bf16x8 qfh[2], qfl[2];
#pragma unroll
    for (int dc = 0; dc < 2; ++dc) {
        int off = SW(qf16 + fr, dc * 32 + fcg);
        qfh[dc] = *(const bf16x8*)(sQh + off);
        qfl[dc] = *(const bf16x8*)(sQl + off);
    }

    f32x4 o[2];
    o[0] = (f32x4){0.f, 0.f, 0.f, 0.f};
    o[1] = (f32x4){0.f, 0.f, 0.f, 0.f};
    float m_run = -3.4e38f, l_run = 0.f;
    const int sq = tid >> 3;
    const int skb = (tid & 7) << 3;
    const float scale = 0.125f;
    const int nt = (qt >> 1) + 1;

    for (int t = 0; t < nt; ++t) {
        __syncthreads();
        {
            int row = tid >> 2, cg = (tid & 3) << 4;
            size_t gk = (size_t)(b * SEQ + (t << 6) + row) * KVD + kv * HDIM + cg;
            *(u16x8*)(sKh + SW(row, cg))     = *(const u16x8*)(Khg + gk);
            *(u16x8*)(sKh + SW(row, cg + 8)) = *(const u16x8*)(Khg + gk + 8);
            *(u16x8*)(sKl + SW(row, cg))     = *(const u16x8*)(Klg + gk);
            *(u16x8*)(sKl + SW(row, cg + 8)) = *(const u16x8*)(Klg + gk + 8);
        }
        {
            int kp = (tid & 31) << 1, dc = (tid >> 5) << 3;
            const float* vg0 = V + (size_t)(b * SEQ + (t << 6) + kp) * KVD
                               + kv * HDIM + dc;
            const float* vg1 = vg0 + KVD;
            float4 a0 = *(const float4*)vg0;
            float4 a1 = *(const float4*)(vg0 + 4);
            float4 b0 = *(const float4*)vg1;
            float4 b1 = *(const float4*)(vg1 + 4);
            float va[8] = {a0.x, a0.y, a0.z, a0.w, a1.x, a1.y, a1.z, a1.w};
            float vb[8] = {b0.x, b0.y, b0.z, b0.w, b1.x, b1.y, b1.z, b1.w};
#pragma unroll
            for (int j = 0; j < 8; ++j) {
                u16 h0 = f2bf(va[j]);
                u16 h1 = f2bf(vb[j]);
                u16 p0 = f2bf(va[j] - bf2f(h0));
                u16 p1 = f2bf(vb[j] - bf2f(h1));
                int off = SW(dc + j, kp);
                *(unsigned*)(sVh + off) = (unsigned)h0 | ((unsigned)h1 << 16);
                *(unsigned*)(sVl + off) = (unsigned)p0 | ((unsigned)p1 << 16);
            }
        }
        __syncthreads();
#pragma unroll
        for (int kk = 0; kk < 2; ++kk) {
            int kf = fp2 + kk;
            bf16x8 kh[2], klv[2];
#pragma unroll
            for (int dc = 0; dc < 2; ++dc) {
                int off = SW(kf * 16 + fr, dc * 32 + fcg);
                kh[dc]  = *(const bf16x8*)(sKh + off);
                klv[dc] = *(const bf16x8*)(sKl + off);
            }
            f32x4 s = (f32x4){0.f, 0.f, 0.f, 0.f};
            s = __builtin_amdgcn_mfma_f32_16x16x32_bf16(qfh[0], kh[0], s, 0, 0, 0);
            s = __builtin_amdgcn_mfma_f32_16x16x32_bf16(qfh[1], kh[1], s, 0, 0, 0);
            s = __builtin_amdgcn_mfma_f32_16x16x32_bf16(qfl[0], kh[0], s, 0, 0, 0);
            s = __builtin_amdgcn_mfma_f32_16x16x32_bf16(qfl[1], kh[1], s, 0, 0, 0);
            s = __builtin_amdgcn_mfma_f32_16x16x32_bf16(qfh[0], klv[0], s, 0, 0, 0);
            s = __builtin_amdgcn_mfma_f32_16x16x32_bf16(qfh[1], klv[1], s, 0, 0, 0);
            int col = kf * 16 + fr;
            int key = (t << 6) + col;
#pragma unroll
            for (int r = 0; r < 4; ++r) {
                int qrow = qf16 + ((l >> 4) << 2) + r;
                Ps[qrow][col] = (key <= q0 + qrow) ? s[r] * scale : -1e9f;
            }
        }
        __syncthreads();
        {
            float4 s0 = *(const float4*)&Ps[sq][skb];
            float4 s1 = *(const float4*)&Ps[sq][skb + 4];
            float sv[8] = {s0.x, s0.y, s0.z, s0.w, s1.x, s1.y, s1.z, s1.w};
            float mx = sv[0];
#pragma unroll
            for (int j = 1; j < 8; ++j) mx = fmaxf(mx, sv[j]);
            for (int x = 1; x < 8; x <<= 1) mx = fmaxf(mx, __shfl_xor(mx, x));
            float mnew = fmaxf(m_run, mx);
            float corr = __expf(m_run - mnew);
            float lsum = 0.f;
#pragma unroll
            for (int j = 0; j < 8; ++j) {
                sv[j] = __expf(sv[j] - mnew);
                lsum += sv[j];
            }
            for (int x = 1; x < 8; x <<= 1) lsum += __shfl_xor(lsum, x);
            l_run = l_run * corr + lsum;
            m_run = mnew;
            *(float4*)&Ps[sq][skb]     = make_float4(sv[0], sv[1], sv[2], sv[3]);
            *(float4*)&Ps[sq][skb + 4] = make_float4(sv[4], sv[5], sv[6], sv[7]);
            if ((tid & 7) == 0) scal[sq] = corr;
        }
        __syncthreads();
        {
            float4 c4 = *(const float4*)&scal[qf16 + ((l >> 4) << 2)];
            float cr[4] = {c4.x, c4.y, c4.z, c4.w};
#pragma unroll
            for (int dfi = 0; dfi < 2; ++dfi)
#pragma unroll
                for (int r = 0; r < 4; ++r) o[dfi][r] *= cr[r];
            bf16x8 ph[2], pl[2];
#pragma unroll
            for (int kc = 0; kc < 2; ++kc) {
                float4 p0 = *(const float4*)&Ps[qf16 + fr][kc * 32 + fcg];
                float4 p1 = *(const float4*)&Ps[qf16 + fr][kc * 32 + fcg + 4];
                u16x8 hh, ll;
                cvt8(p0, p1, hh, ll);
                ph[kc] = *(bf16x8*)&hh;
                pl[kc] = *(bf16x8*)&ll;
            }
#pragma unroll
            for (int dfi = 0; dfi < 2; ++dfi) {
                int df = fp2 + dfi;
#pragma unroll
                for (int kc = 0; kc < 2; ++kc) {
                    int off = SW(df * 16 + fr, kc * 32 + fcg);
                    bf16x8 vh = *(const bf16x8*)(sVh + off);
                    bf16x8 vl = *(const bf16x8*)(sVl + off);
                    o[dfi] = __builtin_amdgcn_mfma_f32_16x16x32_bf16(
                        ph[kc], vh, o[dfi], 0, 0, 0);
                    o[dfi] = __builtin_amdgcn_mfma_f32_16x16x32_bf16(
                        pl[kc], vh, o[dfi], 0, 0, 0);
                    o[dfi] = __builtin_amdgcn_mfma_f32_16x16x32_bf16(
                        ph[kc], vl, o[dfi], 0, 0, 0);
                }
            }
        }
    }
    __syncthreads();
    if ((tid & 7) == 0) scal[sq] = 1.0f / l_run;
    __syncthreads();
    {
        int qrb = qf16 + ((l >> 4) << 2);
        float4 li4 = *(const float4*)&scal[qrb];
        float li[4] = {li4.x, li4.y, li4.z, li4.w};
#pragma unroll
        for (int dfi = 0; dfi < 2; ++dfi) {
            int df = fp2 + dfi;
            int col = n * HDIM + df * 16 + fr;
#pragma unroll
            for (int r = 0; r < 4; ++r) {
                int row = q0 + qrb + r;
                float val = o[dfi][r] * li[r];
                size_t oidx = (size_t)(b * SEQ + row) * HID + col;
                u16 h = f2bf(val);
                Oh[oidx] = h;
                Ol[oidx] = f2bf(val - bf2f(h));
            }
        }
    }
}

// ---------------------------------------------------------------------------
// Group attention: MHA across the 8 channels. One wave per (s, head).
// ---------------------------------------------------------------------------
__global__ __launch_bounds__(64)
void attn_group(const u16* __restrict__ Qh, const u16* __restrict__ Ql,
                const u16* __restrict__ Kh, const u16* __restrict__ Kl,
                const float* __restrict__ V, const float* __restrict__ gmask,
                u16* __restrict__ Oh, u16* __restrict__ Ol) {
    const int n = blockIdx.x % NHEAD;
    const int s = blockIdx.x / NHEAD;
    const int kv = n / REP;
    const int lane = threadIdx.x;
    __shared__ float Qs[8][65], Ks[8][65], Vs[8][65], Ps[64];
    for (int c = 0; c < 8; ++c) {
        size_t qi = (size_t)(c * SEQ + s) * HID + n * HDIM + lane;
        size_t ki = (size_t)(c * SEQ + s) * KVD + kv * HDIM + lane;
        Qs[c][lane] = bf2f(Qh[qi]) + bf2f(Ql[qi]);
        Ks[c][lane] = bf2f(Kh[ki]) + bf2f(Kl[ki]);
        Vs[c][lane] = V[ki];
    }
    __syncthreads();
    const int qb = lane >> 3, kb = lane & 7;
    float sc = 0;
    for (int d = 0; d < 64; ++d) sc += Qs[qb][d] * Ks[kb][d];
    sc = sc * 0.125f + gmask[(size_t)s * 64 + qb * 8 + kb];
    float m = sc;
    for (int x = 1; x < 8; x <<= 1) m = fmaxf(m, __shfl_xor(m, x));
    float p = __expf(sc - m);
    float l = p;
    for (int x = 1; x < 8; x <<= 1) l += __shfl_xor(l, x);
    Ps[lane] = p / l;
    __syncthreads();
    for (int q2 = 0; q2 < 8; ++q2) {
        float o = 0;
        for (int c = 0; c < 8; ++c) o += Ps[q2 * 8 + c] * Vs[c][lane];
        size_t oidx = (size_t)(q2 * SEQ + s) * HID + n * HDIM + lane;
        u16 h = f2bf(o);
        Oh[oidx] = h;
        Ol[oidx] = f2bf(o - bf2f(h));
    }
}

// ---------------------------------------------------------------------------
// MoE router (fp32)
// ---------------------------------------------------------------------------
__global__ __launch_bounds__(64)
void router_kernel(const float* __restrict__ X, const float* __restrict__ GW,
                   int* __restrict__ counts, int* __restrict__ topi,
                   float* __restrict__ topw, int* __restrict__ posb) {
    const int t = blockIdx.x;
    const int lane = threadIdx.x;
    const int e = lane >> 3, c = lane & 7;
    const float4* x4 = (const float4*)(X + (size_t)t * HID + c * 96);
    const float4* g4 = (const float4*)(GW + (size_t)e * HID + c * 96);
    float p = 0;
#pragma unroll
    for (int i = 0; i < 24; ++i) {
        float4 xv = x4[i], gv = g4[i];
        p += xv.x * gv.x + xv.y * gv.y + xv.z * gv.z + xv.w * gv.w;
    }
    p += __shfl_xor(p, 1);
    p += __shfl_xor(p, 2);
    p += __shfl_xor(p, 4);
    float lg[8];
#pragma unroll
    for (int i = 0; i < 8; ++i) lg[i] = __shfl(p, i * 8);
    float m = lg[0];
#pragma unroll
    for (int i = 1; i < 8; ++i) m = fmaxf(m, lg[i]);
    float s = 0;
#pragma unroll
    for (int i = 0; i < 8; ++i) { lg[i] = expf(lg[i] - m); s += lg[i]; }
    float inv = 1.0f / s;
    int i1 = 0; float b1 = lg[0];
#pragma unroll
    for (int i = 1; i < 8; ++i) if (lg[i] > b1) { b1 = lg[i]; i1 = i; }
    int i2 = -1; float b2 = -1.0f;
#pragma unroll
    for (int i = 0; i < 8; ++i)
        if (i != i1 && lg[i] > b2) { b2 = lg[i]; i2 = i; }
    if (lane == 0) {
        topi[t * 2] = i1; topi[t * 2 + 1] = i2;
        topw[t * 2] = b1 * inv; topw[t * 2 + 1] = b2 * inv;
        posb[t * 2] = atomicAdd(&counts[i1], 1);
        posb[t * 2 + 1] = atomicAdd(&counts[i2], 1);
    }
}

__global__ void scan_kernel(const int* __restrict__ counts, int* __restrict__ offsets) {
    int acc = 0;
    for (int e = 0; e < NEXP; ++e) { offsets[e] = acc; acc += counts[e]; }
}

__global__ __launch_bounds__(256)
void fill_slots(const int* __restrict__ topi, const float* __restrict__ topw,
                const int* __restrict__ posb, const int* __restrict__ offsets,
                int* __restrict__ slot_token, float* __restrict__ slot_w,
                int* __restrict__ token_slot) {
    int t = blockIdx.x * 256 + threadIdx.x;
    if (t >= NTOK) return;
#pragma unroll
    for (int k = 0; k < TOPK; ++k) {
        int e = topi[t * 2 + k];
        int sl = offsets[e] + posb[t * 2 + k];
        slot_token[sl] = t;
        slot_w[sl] = topw[t * 2 + k];
        token_slot[t * 2 + k] = sl;
    }
}

// ---------------------------------------------------------------------------
// MoE gate+up grouped GEMM, single-bf16 A, BK=64 (2x32 sub-slices).
// 1D grid 3072 with PANEL-pinned XCD decode: xcd = bid&7; all 32 m-blocks
// of weight panel pid=(bid>>8)*8+xcd co-reside on one XCD (panel fetched
// from HBM once, re-reads are L2 hits); experts mix across XCDs (balance).
// ---------------------------------------------------------------------------
__global__ __launch_bounds__(256)
void moe_gate_up(const u16* __restrict__ Xb, const u16* __restrict__ Wg,
                 const u16* __restrict__ Wu,
                 const int* __restrict__ slot_token,
                 const int* __restrict__ counts,
                 const int* __restrict__ offsets, u16* __restrict__ H) {
    const int bid = blockIdx.x;
    const int xcd = bid & 7;
    const int rest = bid >> 3;          // 0..383
    const int mblk = rest & 31;         // 32 m-slots
    const int pg = rest >> 5;           // 0..11
    const int pid = pg * 8 + xcd;       // 0..95 panels
    const int e = pid / 12;
    const int n0 = (pid % 12) << 7;
    const int Ce = counts[e];
    const int m0 = mblk << 7;
    if (Ce == 0 || m0 >= Ce) return;
    const int base = offsets[e];
    __shared__ __align__(16) u16 As[8192];   // [2][4096]
    __shared__ __align__(16) u16 Gs[8192];
    __shared__ __align__(16) u16 Us[8192];
    const int tid = threadIdx.x, l = tid & 63, w = tid >> 6;
    const int wm = w & 1, wn = w >> 1;
    const int sr = l >> 2, sc8 = (l & 3) << 3;
    int r0 = m0 + w * 32 + sr;
    int r1 = r0 + 16;
    int t0 = slot_token[base + min(r0, Ce - 1)];
    int t1 = slot_token[base + min(r1, Ce - 1)];
    const u16* gA0 = Xb + (size_t)t0 * HID + sc8;
    const u16* gA1 = Xb + (size_t)t1 * HID + sc8;
    const u16* Wge = Wg + (size_t)e * IEXP * HID;
    const u16* Wue = Wu + (size_t)e * IEXP * HID;
    const u16* gG0 = Wge + (size_t)(n0 + w * 32 + sr) * HID + sc8;
    const u16* gG1 = gG0 + 16 * HID;
    const u16* gU0 = Wue + (size_t)(n0 + w * 32 + sr) * HID + sc8;
    const u16* gU1 = gU0 + 16 * HID;
    u16* lA0 = As + w * 1024; u16* lA1 = lA0 + 512;
    u16* lG0 = Gs + w * 1024; u16* lG1 = lG0 + 512;
    u16* lU0 = Us + w * 1024; u16* lU1 = lU0 + 512;
    const int fr = l & 15, fc = (l >> 4) << 3;
    f32x4 accg[4][4], accu[4][4];
#pragma unroll
    for (int i = 0; i < 4; ++i)
#pragma unroll
        for (int j = 0; j < 4; ++j) {
            accg[i][j] = (f32x4){0.f, 0.f, 0.f, 0.f};
            accu[i][j] = (f32x4){0.f, 0.f, 0.f, 0.f};
        }
    for (int k0 = 0; k0 < HID; k0 += 64) {
        gload16(gA0 + k0, lA0);
        gload16(gA1 + k0, lA1);
        gload16(gG0 + k0, lG0);
        gload16(gG1 + k0, lG1);
        gload16(gU0 + k0, lU0);
        gload16(gU1 + k0, lU1);
        gload16(gA0 + k0 + 32, lA0 + 4096);
        gload16(gA1 + k0 + 32, lA1 + 4096);
        gload16(gG0 + k0 + 32, lG0 + 4096);
        gload16(gG1 + k0 + 32, lG1 + 4096);
        gload16(gU0 + k0 + 32, lU0 + 4096);
        gload16(gU1 + k0 + 32, lU1 + 4096);
        __syncthreads();
#pragma unroll
        for (int ks = 0; ks < 2; ++ks) {
            const u16* Ab = As + ks * 4096;
            const u16* Gb = Gs + ks * 4096;
            const u16* Ub = Us + ks * 4096;
            bf16x8 af[4], gf[4], uf[4];
#pragma unroll
            for (int i = 0; i < 4; ++i) {
                af[i] = *(const bf16x8*)(Ab + (wm * 64 + i * 16 + fr) * 32 + fc);
                gf[i] = *(const bf16x8*)(Gb + (wn * 64 + i * 16 + fr) * 32 + fc);
                uf[i] = *(const bf16x8*)(Ub + (wn * 64 + i * 16 + fr) * 32 + fc);
            }
#pragma unroll
            for (int mf = 0; mf < 4; ++mf)
#pragma unroll
                for (int nf = 0; nf < 4; ++nf) {
                    accg[mf][nf] = __builtin_amdgcn_mfma_f32_16x16x32_bf16(
                        af[mf], gf[nf], accg[mf][nf], 0, 0, 0);
                    accu[mf][nf] = __builtin_amdgcn_mfma_f32_16x16x32_bf16(
                        af[mf], uf[nf], accu[mf][nf], 0, 0, 0);
                }
        }
        __syncthreads();
    }
    const int er = (l >> 4) << 2, ec = l & 15;
#pragma unroll
    for (int mf = 0; mf < 4; ++mf)
#pragma unroll
        for (int i = 0; i < 4; ++i) {
            int row = m0 + wm * 64 + mf * 16 + er + i;
            if (row >= Ce) continue;
            size_t sl = (size_t)(base + row);
#pragma unroll
            for (int nf = 0; nf < 4; ++nf) {
                int col = n0 + wn * 64 + nf * 16 + ec;
                float g = accg[mf][nf][i];
                float u = accu[mf][nf][i];
                float h = g / (1.0f + __expf(-g)) * u;
                H[sl * IEXP + col] = f2bf(h);
            }
        }
}

// ---------------------------------------------------------------------------
// MoE down grouped GEMM bf16, BK=64, panel-pinned XCD decode (48 panels).
// 1D grid 1536.
// ---------------------------------------------------------------------------
__global__ __launch_bounds__(256)
void moe_down_bf16(const u16* __restrict__ Hb, const u16* __restrict__ Wd,
                   const float* __restrict__ slot_w,
                   const int* __restrict__ counts,
                   const int* __restrict__ offsets, float* __restrict__ D) {
    const int bid = blockIdx.x;
    const int xcd = bid & 7;
    const int rest = bid >> 3;          // 0..191
    const int mblk = rest & 31;
    const int pg = rest >> 5;           // 0..5
    const int pid = pg * 8 + xcd;       // 0..47 panels
    const int e = pid / 6;
    const int n0 = (pid % 6) << 7;
    const int Ce = counts[e];
    const int m0 = mblk << 7;
    if (Ce == 0 || m0 >= Ce) return;
    const int base = offsets[e];
    __shared__ __align__(16) u16 As[8192];   // [2][4096]
    __shared__ __align__(16) u16 Bs[8192];
    const int tid = threadIdx.x, l = tid & 63, w = tid >> 6;
    const int wm = w & 1, wn = w >> 1;
    const int sr = l >> 2, sc = (l & 3) << 3;
    const u16* Ae = Hb + (size_t)base * IEXP;
    int r0 = min(m0 + w * 32 + sr, Ce - 1);
    int r1 = min(m0 + w * 32 + 16 + sr, Ce - 1);
    const u16* gA0 = Ae + (size_t)r0 * IEXP + sc;
    const u16* gA1 = Ae + (size_t)r1 * IEXP + sc;
    const u16* Wde = Wd + (size_t)e * HID * IEXP;
    const u16* gB0 = Wde + (size_t)(n0 + w * 32 + sr) * IEXP + sc;
    const u16* gB1 = gB0 + 16 * IEXP;
    u16* lA0 = As + w * 1024; u16* lA1 = lA0 + 512;
    u16* lB0 = Bs + w * 1024; u16* lB1 = lB0 + 512;
    const int fr = l & 15, fc = (l >> 4) << 3;
    f32x4 acc[4][4];
#pragma unroll
    for (int i = 0; i < 4; ++i)
#pragma unroll
        for (int j = 0; j < 4; ++j) acc[i][j] = (f32x4){0.f, 0.f, 0.f, 0.f};
    for (int k0 = 0; k0 < IEXP; k0 += 64) {
        gload16(gA0 + k0, lA0);
        gload16(gA1 + k0, lA1);
        gload16(gB0 + k0, lB0);
        gload16(gB1 + k0, lB1);
        gload16(gA0 + k0 + 32, lA0 + 4096);
        gload16(gA1 + k0 + 32, lA1 + 4096);
        gload16(gB0 + k0 + 32, lB0 + 4096);
        gload16(gB1 + k0 + 32, lB1 + 4096);
        __syncthreads();
#pragma unroll
        for (int ks = 0; ks < 2; ++ks) {
            const u16* Ab = As + ks * 4096;
            const u16* Bb = Bs + ks * 4096;
            bf16x8 af[4], bfv[4];
#pragma unroll
            for (int i = 0; i < 4; ++i) {
                af[i]  = *(const bf16x8*)(Ab + (wm * 64 + i * 16 + fr) * 32 + fc);
                bfv[i] = *(const bf16x8*)(Bb + (wn * 64 + i * 16 + fr) * 32 + fc);
            }
#pragma unroll
            for (int mf = 0; mf < 4; ++mf)
#pragma unroll
                for (int nf = 0; nf < 4; ++nf)
                    acc[mf][nf] = __builtin_amdgcn_mfma_f32_16x16x32_bf16(
                        af[mf], bfv[nf], acc[mf][nf], 0, 0, 0);
        }
        __syncthreads();
    }
    const int er = (l >> 4) << 2, ec = l & 15;
#pragma unroll
    for (int mf = 0; mf < 4; ++mf)
#pragma unroll
        for (int i = 0; i < 4; ++i) {
            int row = m0 + wm * 64 + mf * 16 + er + i;
            if (row >= Ce) continue;
            size_t sl = (size_t)(base + row);
            float sw = slot_w[sl];
#pragma unroll
            for (int nf = 0; nf < 4; ++nf) {
                int col = n0 + wn * 64 + nf * 16 + ec;
                D[sl * HID + col] = acc[mf][nf][i] * sw;
            }
        }
}

__global__ __launch_bounds__(256)
void moe_add(float* __restrict__ out, const float* __restrict__ D,
             const int* __restrict__ token_slot) {
    const int t = blockIdx.y;
    const int h = blockIdx.x * 256 + threadIdx.x;
    int s0 = token_slot[t * 2], s1 = token_slot[t * 2 + 1];
    out[(size_t)t * HID + h] += D[(size_t)s0 * HID + h] + D[(size_t)s1 * HID + h];
}

// ---------------------------------------------------------------------------
extern "C" void kernel_launch(void* const* d_in, const int* in_sizes, int n_in,
                              void* d_out, int out_size, void* d_ws, size_t ws_size,
                              hipStream_t stream) {
    const float* hidden = (const float*)d_in[0];
    const float* amask  = (const float*)d_in[1];
    const float* gmask  = (const float*)d_in[2];
    const int*   posids = (const int*)d_in[3];
    const float* ln1 = (const float*)d_in[4];
    const float* ln2 = (const float*)d_in[5];
    const float* ln3 = (const float*)d_in[6];
    const float* sqw = (const float*)d_in[7];  const float* sqb = (const float*)d_in[8];
    const float* skw = (const float*)d_in[9];  const float* skb = (const float*)d_in[10];
    const float* svw = (const float*)d_in[11]; const float* svb = (const float*)d_in[12];
    const float* sow = (const float*)d_in[13];
    const float* gqw = (const float*)d_in[14]; const float* gqb = (const float*)d_in[15];
    const float* gkw = (const float*)d_in[16]; const float* gkb = (const float*)d_in[17];
    const float* gvw = (const float*)d_in[18]; const float* gvb = (const float*)d_in[19];
    const float* gow = (const float*)d_in[20];
    const float* gatew = (const float*)d_in[21];
    const float* wg = (const float*)d_in[22];
    const float* wu = (const float*)d_in[23];
    const float* wd = (const float*)d_in[24];
    float* out = (float*)d_out;
    (void)amask;

    // ---- workspace carve (byte offsets), ~121.8 MB ----
    char* base = (char*)d_ws;
    u16* xh   = (u16*)(base + 0);           //  6,291,456
    u16* xl   = (u16*)(base + 6291456);     //  -> 12,582,912
    u16* qh   = (u16*)(base + 12582912);    //  -> 18,874,368
    u16* ql   = (u16*)(base + 18874368);    //  -> 25,165,824
    u16* kh   = (u16*)(base + 25165824);    //  -> 27,262,976
    u16* kl   = (u16*)(base + 27262976);    //  -> 29,360,128
    float* vbuf = (float*)(base + 29360128);//  -> 33,554,432
    u16* oh   = (u16*)(base + 33554432);    //  -> 39,845,888
    u16* ol   = (u16*)(base + 39845888);    //  -> 46,137,344
    u16* wqkv_sh = (u16*)(base + 46137344);
    u16* wqkv_sl = (u16*)(base + 48103424);
    u16* wo_sh   = (u16*)(base + 50069504);
    u16* wo_sl   = (u16*)(base + 51249152);
    u16* wqkv_gh = (u16*)(base + 52428800);
    u16* wqkv_gl = (u16*)(base + 54394880);
    u16* wo_gh   = (u16*)(base + 56360960);
    u16* wo_gl   = (u16*)(base + 57540608); //  -> 58,720,256
    u16* wgt = (u16*)(base + 58720256);     //  -> 77,594,624
    u16* wut = (u16*)(base + 77594624);     //  -> 96,468,992
    u16* wdt = (u16*)(base + 96468992);     //  -> 115,343,360
    float* slotw = (float*)(base + 115343360);
    float* topw  = (float*)(base + 115376128);
    int* counts  = (int*)(base + 115408896);
    int* offsets = (int*)(base + 115409024);
    int* topi    = (int*)(base + 115409408);
    int* posb    = (int*)(base + 115442176);
    int* slot_token = (int*)(base + 115474944);
    int* token_slot = (int*)(base + 115507712);
    u16* xbf = (u16*)(base + 115540480);    //  -> 121,831,936
    // MoE-phase overlays (attention activations + attn weights dead by then):
    float* xb   = (float*)(base + 0);        // 12,582,912 over xh/xl
    u16*   Hbuf = (u16*)(base + 12582912);   // 25,165,824 over qh..vbuf+oh head
    float* Dbuf = (float*)(base + 37748736); // 25,165,824 over ol+attnW+wgt head

    // ---- weight prep ----
    cvt_split8<<<3072, 256, 0, stream>>>(sqw, skw, svw, sow, gqw, gkw, gvw, gow,
                                         wqkv_sh, wqkv_sl, wo_sh, wo_sl,
                                         wqkv_gh, wqkv_gl, wo_gh, wo_gl);
    transpose_cvt<<<dim3(48, 24, 8), dim3(32, 8), 0, stream>>>(wg, wgt, HID, IEXP);
    transpose_cvt<<<dim3(48, 24, 8), dim3(32, 8), 0, stream>>>(wu, wut, HID, IEXP);
    transpose_cvt<<<dim3(24, 48, 8), dim3(32, 8), 0, stream>>>(wd, wdt, IEXP, HID);

    // ---- self attention ----
    rmsnorm_split<<<NTOK, 256, 0, stream>>>(hidden, ln1, xh, xl);
    qkv_split<<<dim3(10, 32), 256, 0, stream>>>(xh, xl, wqkv_sh, wqkv_sl,
                                                sqb, skb, svb,
                                                qh, ql, kh, kl, vbuf);
    rope_split<<<NTOK, 256, 0, stream>>>(qh, ql, kh, kl, posids);
    attn_self_mfma<<<dim3(SEQ / 32, NHEAD, BATCH), 256, 0, stream>>>(
        qh, ql, kh, kl, vbuf, oh, ol);
    oproj_split<<<dim3(6, 32), 256, 0, stream>>>(oh, ol, wo_sh, wo_sl,
                                                 hidden, out, NTOK, HID, HID);

    // ---- group attention ----
    rmsnorm_split<<<NTOK, 256, 0, stream>>>(out, ln2, xh, xl);
    qkv_split<<<dim3(10, 32), 256, 0, stream>>>(xh, xl, wqkv_gh, wqkv_gl,
                                                gqb, gkb, gvb,
                                                qh, ql, kh, kl, vbuf);
    attn_group<<<SEQ * NHEAD, 64, 0, stream>>>(qh, ql, kh, kl, vbuf, gmask,
                                               oh, ol);
    oproj_split<<<dim3(6, 32), 256, 0, stream>>>(oh, ol, wo_gh, wo_gl,
                                                 out, out, NTOK, HID, HID);

    // ---- MoE (bf16 MFMA; BK=64; panel-pinned XCD swizzle) ----
    rmsnorm_kernel<<<NTOK, 256, 0, stream>>>(out, ln3, xb, xbf);
    hipMemsetAsync(counts, 0, 8 * sizeof(int), stream);
    router_kernel<<<NTOK, 64, 0, stream>>>(xb, gatew, counts, topi, topw, posb);
    scan_kernel<<<1, 1, 0, stream>>>(counts, offsets);
    fill_slots<<<16, 256, 0, stream>>>(topi, topw, posb, offsets,
                                       slot_token, slotw, token_slot);
    moe_gate_up<<<3072, 256, 0, stream>>>(
        xbf, wgt, wut, slot_token, counts, offsets, Hbuf);
    moe_down_bf16<<<1536, 256, 0, stream>>>(
        Hbuf, wdt, slotw, counts, offsets, Dbuf);
    moe_add<<<dim3(3, NTOK), 256, 0, stream>>>(out, Dbuf, token_slot);
}